// Round 7
// baseline (775.327 us; speedup 1.0000x reference)
//
#include <hip/hip_runtime.h>
#include <hip/hip_bf16.h>

#define N_NODES 100000
#define EMB 256
#define N_MP 1600000
#define N_SUP 200000

typedef __attribute__((ext_vector_type(4))) float f32x4;
typedef __attribute__((ext_vector_type(8))) short s16x8;

__device__ __forceinline__ int clampi(int v, int lo, int hi) {
    return v < lo ? lo : (v > hi ? hi : v);
}
__device__ __forceinline__ ushort f2bf(float f) {
    unsigned u = __float_as_uint(f);
    u += 0x7fffu + ((u >> 16) & 1u);   // round-to-nearest-even
    return (ushort)(u >> 16);
}
__device__ __forceinline__ float bf2f(ushort h) {
    return __uint_as_float(((unsigned)h) << 16);
}

#define GLOAD_LDS16(gsrc, ldst)                                                   \
    __builtin_amdgcn_global_load_lds(                                             \
        (const __attribute__((address_space(1))) void*)(gsrc),                    \
        (__attribute__((address_space(3))) void*)(ldst), 16, 0, 0)

// ---------------- fp32 -> bf16 convert ----------------

__global__ void f2b_kernel(const float* __restrict__ in, ushort* __restrict__ out, int n8) {
    int i = blockIdx.x * 256 + threadIdx.x;
    if (i >= n8) return;
    const float4* p = (const float4*)(in + (size_t)i * 8);
    float4 a = p[0], b = p[1];
    ushort4 lo = make_ushort4(f2bf(a.x), f2bf(a.y), f2bf(a.z), f2bf(a.w));
    ushort4 hi = make_ushort4(f2bf(b.x), f2bf(b.y), f2bf(b.z), f2bf(b.w));
    ushort4* q = (ushort4*)(out + (size_t)i * 8);
    q[0] = lo; q[1] = hi;
}

// ---------------- CSR build ----------------

__global__ void hist_kernel(const int* __restrict__ dst, int n, int* __restrict__ hist) {
    int i = blockIdx.x * 256 + threadIdx.x;
    if (i < n) atomicAdd(&hist[clampi(dst[i], 0, N_NODES - 1)], 1);
}

#define SCAN_CHUNK 1024
#define NB_SCAN ((N_NODES + SCAN_CHUNK - 1) / SCAN_CHUNK)   // 98

__global__ void scan_partial_kernel(const int* __restrict__ hist, int* __restrict__ psum, int n) {
    __shared__ int lds[4];
    int b = blockIdx.x;
    int tid = threadIdx.x, lane = tid & 63, wv = tid >> 6;
    int base = b * SCAN_CHUNK + tid * 4;
    int s = 0;
    if (base + 3 < n) {
        int4 v = *(const int4*)&hist[base];
        s = v.x + v.y + v.z + v.w;
    } else {
#pragma unroll
        for (int k = 0; k < 4; ++k) { int i = base + k; if (i < n) s += hist[i]; }
    }
#pragma unroll
    for (int off = 32; off; off >>= 1) s += __shfl_down(s, off, 64);
    if (lane == 0) lds[wv] = s;
    __syncthreads();
    if (tid == 0) psum[b] = lds[0] + lds[1] + lds[2] + lds[3];
}

__global__ void scan_blocksums_kernel(int* __restrict__ psum, int nb) {
    __shared__ int lds[128];
    int t = threadIdx.x;
    lds[t] = (t < nb) ? psum[t] : 0;
    __syncthreads();
    if (t == 0) {
        int run = 0;
        for (int i = 0; i < nb; ++i) { int v = lds[i]; lds[i] = run; run += v; }
    }
    __syncthreads();
    if (t < nb) psum[t] = lds[t];
}

__global__ void scan_final_kernel(const int* __restrict__ hist, const int* __restrict__ poff,
                                  int* __restrict__ rp, int n) {
    __shared__ int wsum[4];
    int b = blockIdx.x;
    int tid = threadIdx.x, lane = tid & 63, wv = tid >> 6;
    int base = b * SCAN_CHUNK + tid * 4;
    int v0 = 0, v1 = 0, v2 = 0, v3 = 0;
    if (base + 3 < n) {
        int4 v = *(const int4*)&hist[base];
        v0 = v.x; v1 = v.y; v2 = v.z; v3 = v.w;
    } else {
        if (base + 0 < n) v0 = hist[base + 0];
        if (base + 1 < n) v1 = hist[base + 1];
        if (base + 2 < n) v2 = hist[base + 2];
        if (base + 3 < n) v3 = hist[base + 3];
    }
    int s1 = v0 + v1, s2 = s1 + v2, s3 = s2 + v3;
    int t = s3;
#pragma unroll
    for (int off = 1; off < 64; off <<= 1) {
        int u = __shfl_up(t, off, 64);
        if (lane >= off) t += u;
    }
    if (lane == 63) wsum[wv] = t;
    __syncthreads();
    int woff = 0;
    for (int i = 0; i < wv; ++i) woff += wsum[i];
    int off0 = poff[b] + woff + (t - s3);
    if (base + 0 < n) rp[base + 1] = off0 + v0;
    if (base + 1 < n) rp[base + 2] = off0 + s1;
    if (base + 2 < n) rp[base + 3] = off0 + s2;
    if (base + 3 < n) rp[base + 4] = off0 + s3;
    if (b == 0 && tid == 0) rp[0] = 0;
}

__global__ void scatter_kernel(const int* __restrict__ src, const int* __restrict__ dst, int n,
                               const int* __restrict__ rp, int* __restrict__ fill,
                               int* __restrict__ srt) {
    int i = blockIdx.x * 256 + threadIdx.x;
    if (i < n) {
        int d = clampi(dst[i], 0, N_NODES - 1);
        int pos = rp[d] + atomicAdd(&fill[d], 1);
        if (pos >= 0 && pos < n) srt[pos] = clampi(src[i], 0, N_NODES - 1);
    }
}

// ------- mean aggregation v3: wave per node, 4 edges in flight, split accs ------
// Half-waves (32 lanes) own alternating edges; lane sl owns cols [sl*8, sl*8+8).
// Unroll 4 edges/iter: each half issues 2 independent 16B gathers back-to-back.

__global__ void agg_kernel(const ushort* __restrict__ x, const int* __restrict__ rp,
                           const int* __restrict__ srt, ushort* __restrict__ outm) {
    int w = threadIdx.x >> 6;
    int lane = threadIdx.x & 63;
    int half = lane >> 5;
    int sl = lane & 31;
    int node = blockIdx.x * 4 + w;
    if (node >= N_NODES) return;
    int beg = rp[node], end = rp[node + 1];
    int deg = end - beg;
    float acc0[8], acc1[8];
#pragma unroll
    for (int i = 0; i < 8; ++i) { acc0[i] = 0.f; acc1[i] = 0.f; }

    for (int bse = 0; bse < deg; bse += 64) {
        int rem = deg - bse;
        int cnt = rem < 64 ? rem : 64;
        int myidx = (lane < cnt) ? srt[beg + bse + lane] : 0;
        int j = 0;
        for (; j + 4 <= cnt; j += 4) {
            int s0 = __shfl(myidx, j + half, 64);
            int s1 = __shfl(myidx, j + 2 + half, 64);
            s16x8 v0 = *(const s16x8*)&x[(unsigned)s0 * EMB + sl * 8];
            s16x8 v1 = *(const s16x8*)&x[(unsigned)s1 * EMB + sl * 8];
#pragma unroll
            for (int i = 0; i < 8; ++i) acc0[i] += bf2f((ushort)v0[i]);
#pragma unroll
            for (int i = 0; i < 8; ++i) acc1[i] += bf2f((ushort)v1[i]);
        }
        for (; j < cnt; j += 2) {
            int e = j + half;
            int s = __shfl(myidx, e < cnt ? e : 0, 64);
            if (e < cnt) {
                s16x8 v = *(const s16x8*)&x[(unsigned)s * EMB + sl * 8];
#pragma unroll
                for (int i = 0; i < 8; ++i) acc0[i] += bf2f((ushort)v[i]);
            }
        }
    }
    // merge split accumulators, then combine halves
#pragma unroll
    for (int i = 0; i < 8; ++i) acc0[i] += acc1[i];
#pragma unroll
    for (int i = 0; i < 8; ++i) acc0[i] += __shfl_xor(acc0[i], 32, 64);
    float inv = 1.0f / fmaxf((float)deg, 1.0f);
    if (half == 0) {
        s16x8 o;
#pragma unroll
        for (int i = 0; i < 8; ++i) o[i] = (short)f2bf(acc0[i] * inv);
        *(s16x8*)&outm[(size_t)node * EMB + sl * 8] = o;
    }
}

// ---------------- bf16 MFMA GEMM: out = Am@Wl^T + Ax@Wr^T + b (opt relu) --------

#define BM 128
#define BN 128
#define BKG 64

__global__ __launch_bounds__(256) void gemm_kernel(
    const ushort* __restrict__ Am, const ushort* __restrict__ Ax,
    const ushort* __restrict__ Wl, const ushort* __restrict__ Wr,
    const float* __restrict__ bias, ushort* __restrict__ out, int M, int do_relu) {
    __shared__ ushort As[BM * BKG];   // 16 KiB
    __shared__ ushort Bs[BN * BKG];   // 16 KiB
    const int tid = threadIdx.x;
    const int lane = tid & 63;
    const int w = tid >> 6;
    const int m0 = blockIdx.x * BM;
    const int n0 = blockIdx.y * BN;
    const int wr = w >> 1;
    const int wc = w & 1;

    f32x4 acc[4][4];
#pragma unroll
    for (int i = 0; i < 4; ++i)
#pragma unroll
        for (int j = 0; j < 4; ++j) acc[i][j] = (f32x4){0.f, 0.f, 0.f, 0.f};

    size_t srcA[4], srcB[4];
    int ldso[4];
#pragma unroll
    for (int j = 0; j < 4; ++j) {
        int c = (w * 4 + j) * 64 + lane;
        int r = c >> 3;
        int cc = (c & 7) ^ (r & 7);
        int arow = m0 + r; if (arow > M - 1) arow = M - 1;
        srcA[j] = (size_t)arow * EMB + cc * 8;
        srcB[j] = (size_t)(n0 + r) * EMB + cc * 8;
        ldso[j] = (w * 4 + j) * 512;
    }

#pragma unroll
    for (int phase = 0; phase < 2; ++phase) {
        const ushort* A = phase ? Ax : Am;
        const ushort* W = phase ? Wr : Wl;
        for (int k0 = 0; k0 < EMB; k0 += BKG) {
#pragma unroll
            for (int j = 0; j < 4; ++j) GLOAD_LDS16(A + srcA[j] + k0, As + ldso[j]);
#pragma unroll
            for (int j = 0; j < 4; ++j) GLOAD_LDS16(W + srcB[j] + k0, Bs + ldso[j]);
            asm volatile("s_waitcnt vmcnt(0)" ::: "memory");
            __syncthreads();
#pragma unroll
            for (int ks = 0; ks < 2; ++ks) {
                const int ccr = ((ks * 4 + (lane >> 4)) ^ (lane & 7)) * 8;
                s16x8 af[4], bg[4];
#pragma unroll
                for (int mf = 0; mf < 4; ++mf) {
                    int r = wr * 64 + mf * 16 + (lane & 15);
                    af[mf] = *(const s16x8*)&As[r * BKG + ccr];
                }
#pragma unroll
                for (int nf = 0; nf < 4; ++nf) {
                    int r = wc * 64 + nf * 16 + (lane & 15);
                    bg[nf] = *(const s16x8*)&Bs[r * BKG + ccr];
                }
#pragma unroll
                for (int mf = 0; mf < 4; ++mf)
#pragma unroll
                    for (int nf = 0; nf < 4; ++nf)
                        acc[mf][nf] = __builtin_amdgcn_mfma_f32_16x16x32_bf16(
                            af[mf], bg[nf], acc[mf][nf], 0, 0, 0);
            }
            __syncthreads();
        }
    }

#pragma unroll
    for (int nf = 0; nf < 4; ++nf) {
        int col = n0 + wc * 64 + nf * 16 + (lane & 15);
        float bv = bias[col];
#pragma unroll
        for (int mf = 0; mf < 4; ++mf) {
            int rbase = m0 + wr * 64 + mf * 16 + ((lane >> 4) << 2);
#pragma unroll
            for (int q = 0; q < 4; ++q) {
                int row = rbase + q;
                if (row < M) {
                    float v = acc[mf][nf][q] + bv;
                    if (do_relu) v = fmaxf(v, 0.f);
                    out[(size_t)row * EMB + col] = f2bf(v);
                }
            }
        }
    }
}

// ------- supervision scores: wave per edge, both rows in one 16B/lane load -----

__global__ void score_kernel(const ushort* __restrict__ x, const int* __restrict__ sup,
                             float* __restrict__ out) {
    int w = threadIdx.x >> 6;
    int lane = threadIdx.x & 63;
    int half = lane >> 5;
    int sl = lane & 31;
    int e = blockIdx.x * 4 + w;
    if (e >= N_SUP) return;
    int s = clampi(sup[e], 0, N_NODES - 1);
    int d = clampi(sup[N_SUP + e], 0, N_NODES - 1);
    int row = half ? d : s;
    uint4 raw = *(const uint4*)&x[(unsigned)row * EMB + sl * 8];
    uint4 pr;
    pr.x = __shfl_xor(raw.x, 32, 64);
    pr.y = __shfl_xor(raw.y, 32, 64);
    pr.z = __shfl_xor(raw.z, 32, 64);
    pr.w = __shfl_xor(raw.w, 32, 64);
    float t = 0.f;
    unsigned a[4] = {raw.x, raw.y, raw.z, raw.w};
    unsigned b[4] = {pr.x, pr.y, pr.z, pr.w};
#pragma unroll
    for (int i = 0; i < 4; ++i) {
        t += bf2f((ushort)(a[i] & 0xffff)) * bf2f((ushort)(b[i] & 0xffff));
        t += bf2f((ushort)(a[i] >> 16)) * bf2f((ushort)(b[i] >> 16));
    }
#pragma unroll
    for (int off = 16; off > 0; off >>= 1) t += __shfl_xor(t, off, 64);
    if (lane == 0) out[e] = t;
}

// ---------------- launch ----------------

extern "C" void kernel_launch(void* const* d_in, const int* in_sizes, int n_in,
                              void* d_out, int out_size, void* d_ws, size_t ws_size,
                              hipStream_t stream) {
    const float* x0  = (const float*)d_in[0];
    const int*   mp  = (const int*)d_in[1];
    const int*   sup = (const int*)d_in[2];
    const float* Wf[6] = {(const float*)d_in[3], (const float*)d_in[5],
                          (const float*)d_in[6], (const float*)d_in[8],
                          (const float*)d_in[9], (const float*)d_in[11]};
    const float* bl1 = (const float*)d_in[4];
    const float* bl2 = (const float*)d_in[7];
    const float* bl3 = (const float*)d_in[10];
    float* scores = (float*)d_out;

    const int* mp_src = mp;
    const int* mp_dst = mp + N_MP;

    char* base = (char*)d_ws;
    size_t off = 0;
    auto alloc = [&](size_t bytes) {
        void* p = base + off;
        off = (off + bytes + 255) & ~(size_t)255;
        return p;
    };
    int* rp   = (int*)alloc((N_NODES + 1) * sizeof(int));
    int* hist = (int*)alloc(N_NODES * sizeof(int));
    int* fill = (int*)alloc(N_NODES * sizeof(int));
    int* psum = (int*)alloc(NB_SCAN * sizeof(int));
    int* srt  = (int*)alloc(N_MP * sizeof(int));
    ushort* x0b  = (ushort*)alloc((size_t)N_NODES * EMB * sizeof(ushort));
    ushort* bufA = (ushort*)alloc((size_t)N_NODES * EMB * sizeof(ushort));
    ushort* bufB = (ushort*)alloc((size_t)N_NODES * EMB * sizeof(ushort));
    ushort* bufC = (ushort*)alloc((size_t)N_NODES * EMB * sizeof(ushort));
    ushort* Wb[6];
    for (int i = 0; i < 6; ++i) Wb[i] = (ushort*)alloc((size_t)EMB * EMB * sizeof(ushort));
    (void)ws_size; (void)n_in; (void)in_sizes; (void)out_size;

    // hist+fill are adjacent in ws: one memset covers both (pad between is harmless)
    hipMemsetAsync(hist, 0, (size_t)((char*)fill - (char*)hist) + N_NODES * sizeof(int), stream);

    f2b_kernel<<<(N_NODES * EMB / 8 + 255) / 256, 256, 0, stream>>>(x0, x0b, N_NODES * EMB / 8);
    for (int i = 0; i < 6; ++i)
        f2b_kernel<<<(EMB * EMB / 8 + 255) / 256, 256, 0, stream>>>(Wf[i], Wb[i], EMB * EMB / 8);

    hist_kernel<<<(N_MP + 255) / 256, 256, 0, stream>>>(mp_dst, N_MP, hist);
    scan_partial_kernel<<<NB_SCAN, 256, 0, stream>>>(hist, psum, N_NODES);
    scan_blocksums_kernel<<<1, 128, 0, stream>>>(psum, NB_SCAN);
    scan_final_kernel<<<NB_SCAN, 256, 0, stream>>>(hist, psum, rp, N_NODES);
    scatter_kernel<<<(N_MP + 255) / 256, 256, 0, stream>>>(mp_src, mp_dst, N_MP, rp, fill, srt);

    dim3 gemm_grid((N_NODES + BM - 1) / BM, EMB / BN);
    int agg_blocks = (N_NODES + 3) / 4;

    agg_kernel<<<agg_blocks, 256, 0, stream>>>(x0b, rp, srt, bufC);
    gemm_kernel<<<gemm_grid, 256, 0, stream>>>(bufC, x0b, Wb[0], Wb[1], bl1, bufA, N_NODES, 1);

    agg_kernel<<<agg_blocks, 256, 0, stream>>>(bufA, rp, srt, bufC);
    gemm_kernel<<<gemm_grid, 256, 0, stream>>>(bufC, bufA, Wb[2], Wb[3], bl2, bufB, N_NODES, 1);

    agg_kernel<<<agg_blocks, 256, 0, stream>>>(bufB, rp, srt, bufC);
    gemm_kernel<<<gemm_grid, 256, 0, stream>>>(bufC, bufB, Wb[4], Wb[5], bl3, bufA, N_NODES, 0);

    score_kernel<<<(N_SUP + 3) / 4, 256, 0, stream>>>(bufA, sup, scores);
}

// Round 8
// 724.107 us; speedup vs baseline: 1.0707x; 1.0707x over previous
//
#include <hip/hip_runtime.h>
#include <hip/hip_bf16.h>

#define N_NODES 100000
#define EMB 256
#define N_MP 1600000
#define N_SUP 200000

typedef __attribute__((ext_vector_type(4))) float f32x4;
typedef __attribute__((ext_vector_type(8))) short s16x8;

__device__ __forceinline__ int clampi(int v, int lo, int hi) {
    return v < lo ? lo : (v > hi ? hi : v);
}
__device__ __forceinline__ ushort f2bf(float f) {
    unsigned u = __float_as_uint(f);
    u += 0x7fffu + ((u >> 16) & 1u);   // round-to-nearest-even
    return (ushort)(u >> 16);
}
__device__ __forceinline__ float bf2f(ushort h) {
    return __uint_as_float(((unsigned)h) << 16);
}

#define GLOAD_LDS16(gsrc, ldst)                                                   \
    __builtin_amdgcn_global_load_lds(                                             \
        (const __attribute__((address_space(1))) void*)(gsrc),                    \
        (__attribute__((address_space(3))) void*)(ldst), 16, 0, 0)

// ---------------- fp32 -> bf16 convert ----------------

__global__ void f2b_kernel(const float* __restrict__ in, ushort* __restrict__ out, int n8) {
    int i = blockIdx.x * 256 + threadIdx.x;
    if (i >= n8) return;
    const float4* p = (const float4*)(in + (size_t)i * 8);
    float4 a = p[0], b = p[1];
    ushort4 lo = make_ushort4(f2bf(a.x), f2bf(a.y), f2bf(a.z), f2bf(a.w));
    ushort4 hi = make_ushort4(f2bf(b.x), f2bf(b.y), f2bf(b.z), f2bf(b.w));
    ushort4* q = (ushort4*)(out + (size_t)i * 8);
    q[0] = lo; q[1] = hi;
}

// ---------------- CSR build ----------------

__global__ void hist_kernel(const int* __restrict__ dst, int n, int* __restrict__ hist) {
    int i = blockIdx.x * 256 + threadIdx.x;
    if (i < n) atomicAdd(&hist[clampi(dst[i], 0, N_NODES - 1)], 1);
}

#define SCAN_CHUNK 1024
#define NB_SCAN ((N_NODES + SCAN_CHUNK - 1) / SCAN_CHUNK)   // 98

__global__ void scan_partial_kernel(const int* __restrict__ hist, int* __restrict__ psum, int n) {
    __shared__ int lds[4];
    int b = blockIdx.x;
    int tid = threadIdx.x, lane = tid & 63, wv = tid >> 6;
    int base = b * SCAN_CHUNK + tid * 4;
    int s = 0;
    if (base + 3 < n) {
        int4 v = *(const int4*)&hist[base];
        s = v.x + v.y + v.z + v.w;
    } else {
#pragma unroll
        for (int k = 0; k < 4; ++k) { int i = base + k; if (i < n) s += hist[i]; }
    }
#pragma unroll
    for (int off = 32; off; off >>= 1) s += __shfl_down(s, off, 64);
    if (lane == 0) lds[wv] = s;
    __syncthreads();
    if (tid == 0) psum[b] = lds[0] + lds[1] + lds[2] + lds[3];
}

__global__ void scan_blocksums_kernel(int* __restrict__ psum, int nb) {
    __shared__ int lds[128];
    int t = threadIdx.x;
    lds[t] = (t < nb) ? psum[t] : 0;
    __syncthreads();
    if (t == 0) {
        int run = 0;
        for (int i = 0; i < nb; ++i) { int v = lds[i]; lds[i] = run; run += v; }
    }
    __syncthreads();
    if (t < nb) psum[t] = lds[t];
}

__global__ void scan_final_kernel(const int* __restrict__ hist, const int* __restrict__ poff,
                                  int* __restrict__ rp, int n) {
    __shared__ int wsum[4];
    int b = blockIdx.x;
    int tid = threadIdx.x, lane = tid & 63, wv = tid >> 6;
    int base = b * SCAN_CHUNK + tid * 4;
    int v0 = 0, v1 = 0, v2 = 0, v3 = 0;
    if (base + 3 < n) {
        int4 v = *(const int4*)&hist[base];
        v0 = v.x; v1 = v.y; v2 = v.z; v3 = v.w;
    } else {
        if (base + 0 < n) v0 = hist[base + 0];
        if (base + 1 < n) v1 = hist[base + 1];
        if (base + 2 < n) v2 = hist[base + 2];
        if (base + 3 < n) v3 = hist[base + 3];
    }
    int s1 = v0 + v1, s2 = s1 + v2, s3 = s2 + v3;
    int t = s3;
#pragma unroll
    for (int off = 1; off < 64; off <<= 1) {
        int u = __shfl_up(t, off, 64);
        if (lane >= off) t += u;
    }
    if (lane == 63) wsum[wv] = t;
    __syncthreads();
    int woff = 0;
    for (int i = 0; i < wv; ++i) woff += wsum[i];
    int off0 = poff[b] + woff + (t - s3);
    if (base + 0 < n) rp[base + 1] = off0 + v0;
    if (base + 1 < n) rp[base + 2] = off0 + s1;
    if (base + 2 < n) rp[base + 3] = off0 + s2;
    if (base + 3 < n) rp[base + 4] = off0 + s3;
    if (b == 0 && tid == 0) rp[0] = 0;
}

__global__ void scatter_kernel(const int* __restrict__ src, const int* __restrict__ dst, int n,
                               const int* __restrict__ rp, int* __restrict__ fill,
                               int* __restrict__ srt) {
    int i = blockIdx.x * 256 + threadIdx.x;
    if (i < n) {
        int d = clampi(dst[i], 0, N_NODES - 1);
        int pos = rp[d] + atomicAdd(&fill[d], 1);
        if (pos >= 0 && pos < n) srt[pos] = clampi(src[i], 0, N_NODES - 1);
    }
}

// ------- mean aggregation (v2, best measured): wave/node, 2 edges/iter, 16B/lane

__global__ void agg_kernel(const ushort* __restrict__ x, const int* __restrict__ rp,
                           const int* __restrict__ srt, ushort* __restrict__ outm) {
    int w = threadIdx.x >> 6;
    int lane = threadIdx.x & 63;
    int half = lane >> 5;
    int sl = lane & 31;
    int node = blockIdx.x * 4 + w;
    if (node >= N_NODES) return;
    int beg = rp[node], end = rp[node + 1];
    int deg = end - beg;
    float acc[8];
#pragma unroll
    for (int i = 0; i < 8; ++i) acc[i] = 0.f;

    for (int bse = 0; bse < deg; bse += 64) {
        int rem = deg - bse;
        int cnt = rem < 64 ? rem : 64;
        int myidx = (lane < cnt) ? srt[beg + bse + lane] : 0;
        for (int j = 0; j < cnt; j += 2) {
            int e = j + half;
            int s = __shfl(myidx, e & 63, 64);
            if (e < cnt) {
                s16x8 v = *(const s16x8*)&x[(unsigned)s * EMB + sl * 8];
#pragma unroll
                for (int i = 0; i < 8; ++i) acc[i] += bf2f((ushort)v[i]);
            }
        }
    }
#pragma unroll
    for (int i = 0; i < 8; ++i) acc[i] += __shfl_xor(acc[i], 32, 64);
    float inv = 1.0f / fmaxf((float)deg, 1.0f);
    if (half == 0) {
        s16x8 o;
#pragma unroll
        for (int i = 0; i < 8; ++i) o[i] = (short)f2bf(acc[i] * inv);
        *(s16x8*)&outm[(size_t)node * EMB + sl * 8] = o;
    }
}

// -------- bf16 MFMA GEMM v2: BM=128 x BN=256 (full width, grid.y=1) ------------
// 512 threads / 8 waves (2 row x 4 col), per-wave 64x64 output, BK=64.
// A staged ONCE per row-block (halves gload traffic vs BN=128 grid.y=2).
// Same XOR swizzle: LDS[r][cc] = G[r][cc ^ (r&7)] in 16B chunks; ds_read applies
// the same involution.

#define BM 128
#define BN 256
#define BKG 64

__global__ __launch_bounds__(512) void gemm_kernel(
    const ushort* __restrict__ Am, const ushort* __restrict__ Ax,
    const ushort* __restrict__ Wl, const ushort* __restrict__ Wr,
    const float* __restrict__ bias, ushort* __restrict__ out, int M, int do_relu) {
    __shared__ ushort As[BM * BKG];   // 16 KiB
    __shared__ ushort Bs[BN * BKG];   // 32 KiB
    const int tid = threadIdx.x;
    const int lane = tid & 63;
    const int w = tid >> 6;           // 0..7
    const int m0 = blockIdx.x * BM;
    const int wr = w >> 2;            // 0..1 (row of 64)
    const int wc = w & 3;             // 0..3 (col of 64)

    f32x4 acc[4][4];
#pragma unroll
    for (int i = 0; i < 4; ++i)
#pragma unroll
        for (int j = 0; j < 4; ++j) acc[i][j] = (f32x4){0.f, 0.f, 0.f, 0.f};

    // A staging: 1024 chunks (16B), 512 threads -> 2 each
    size_t srcA[2];
    int ldsoA[2];
#pragma unroll
    for (int j = 0; j < 2; ++j) {
        int c = j * 512 + tid;
        int r = c >> 3;
        int cc = (c & 7) ^ (r & 7);
        int arow = m0 + r; if (arow > M - 1) arow = M - 1;
        srcA[j] = (size_t)arow * EMB + cc * 8;
        ldsoA[j] = c * 8;              // ushort units (16B chunks linear)
    }
    // B staging: 2048 chunks, 4 each
    size_t srcB[4];
    int ldsoB[4];
#pragma unroll
    for (int j = 0; j < 4; ++j) {
        int c = j * 512 + tid;
        int r = c >> 3;                // 0..255
        int cc = (c & 7) ^ (r & 7);
        srcB[j] = (size_t)r * EMB + cc * 8;
        ldsoB[j] = c * 8;
    }

#pragma unroll
    for (int phase = 0; phase < 2; ++phase) {
        const ushort* A = phase ? Ax : Am;
        const ushort* W = phase ? Wr : Wl;
        for (int k0 = 0; k0 < EMB; k0 += BKG) {
#pragma unroll
            for (int j = 0; j < 2; ++j) GLOAD_LDS16(A + srcA[j] + k0, As + ldsoA[j]);
#pragma unroll
            for (int j = 0; j < 4; ++j) GLOAD_LDS16(W + srcB[j] + k0, Bs + ldsoB[j]);
            asm volatile("s_waitcnt vmcnt(0)" ::: "memory");
            __syncthreads();
#pragma unroll
            for (int ks = 0; ks < 2; ++ks) {
                const int ccr = ((ks * 4 + (lane >> 4)) ^ (lane & 7)) * 8;
                s16x8 af[4], bg[4];
#pragma unroll
                for (int mf = 0; mf < 4; ++mf) {
                    int r = wr * 64 + mf * 16 + (lane & 15);
                    af[mf] = *(const s16x8*)&As[r * BKG + ccr];
                }
#pragma unroll
                for (int nf = 0; nf < 4; ++nf) {
                    int r = wc * 64 + nf * 16 + (lane & 15);
                    bg[nf] = *(const s16x8*)&Bs[r * BKG + ccr];
                }
#pragma unroll
                for (int mf = 0; mf < 4; ++mf)
#pragma unroll
                    for (int nf = 0; nf < 4; ++nf)
                        acc[mf][nf] = __builtin_amdgcn_mfma_f32_16x16x32_bf16(
                            af[mf], bg[nf], acc[mf][nf], 0, 0, 0);
            }
            __syncthreads();
        }
    }

    // epilogue: C/D mapping col=lane&15, row=(lane>>4)*4+q
#pragma unroll
    for (int nf = 0; nf < 4; ++nf) {
        int col = wc * 64 + nf * 16 + (lane & 15);
        float bv = bias[col];
#pragma unroll
        for (int mf = 0; mf < 4; ++mf) {
            int rbase = m0 + wr * 64 + mf * 16 + ((lane >> 4) << 2);
#pragma unroll
            for (int q = 0; q < 4; ++q) {
                int row = rbase + q;
                if (row < M) {
                    float v = acc[mf][nf][q] + bv;
                    if (do_relu) v = fmaxf(v, 0.f);
                    out[(size_t)row * EMB + col] = f2bf(v);
                }
            }
        }
    }
}

// ------- supervision scores: wave per edge, both rows in one 16B/lane load -----

__global__ void score_kernel(const ushort* __restrict__ x, const int* __restrict__ sup,
                             float* __restrict__ out) {
    int w = threadIdx.x >> 6;
    int lane = threadIdx.x & 63;
    int half = lane >> 5;
    int sl = lane & 31;
    int e = blockIdx.x * 4 + w;
    if (e >= N_SUP) return;
    int s = clampi(sup[e], 0, N_NODES - 1);
    int d = clampi(sup[N_SUP + e], 0, N_NODES - 1);
    int row = half ? d : s;
    uint4 raw = *(const uint4*)&x[(unsigned)row * EMB + sl * 8];
    uint4 pr;
    pr.x = __shfl_xor(raw.x, 32, 64);
    pr.y = __shfl_xor(raw.y, 32, 64);
    pr.z = __shfl_xor(raw.z, 32, 64);
    pr.w = __shfl_xor(raw.w, 32, 64);
    float t = 0.f;
    unsigned a[4] = {raw.x, raw.y, raw.z, raw.w};
    unsigned b[4] = {pr.x, pr.y, pr.z, pr.w};
#pragma unroll
    for (int i = 0; i < 4; ++i) {
        t += bf2f((ushort)(a[i] & 0xffff)) * bf2f((ushort)(b[i] & 0xffff));
        t += bf2f((ushort)(a[i] >> 16)) * bf2f((ushort)(b[i] >> 16));
    }
#pragma unroll
    for (int off = 16; off > 0; off >>= 1) t += __shfl_xor(t, off, 64);
    if (lane == 0) out[e] = t;
}

// ---------------- launch ----------------

extern "C" void kernel_launch(void* const* d_in, const int* in_sizes, int n_in,
                              void* d_out, int out_size, void* d_ws, size_t ws_size,
                              hipStream_t stream) {
    const float* x0  = (const float*)d_in[0];
    const int*   mp  = (const int*)d_in[1];
    const int*   sup = (const int*)d_in[2];
    const float* Wf[6] = {(const float*)d_in[3], (const float*)d_in[5],
                          (const float*)d_in[6], (const float*)d_in[8],
                          (const float*)d_in[9], (const float*)d_in[11]};
    const float* bl1 = (const float*)d_in[4];
    const float* bl2 = (const float*)d_in[7];
    const float* bl3 = (const float*)d_in[10];
    float* scores = (float*)d_out;

    const int* mp_src = mp;
    const int* mp_dst = mp + N_MP;

    char* base = (char*)d_ws;
    size_t off = 0;
    auto alloc = [&](size_t bytes) {
        void* p = base + off;
        off = (off + bytes + 255) & ~(size_t)255;
        return p;
    };
    int* rp   = (int*)alloc((N_NODES + 1) * sizeof(int));
    int* hist = (int*)alloc(N_NODES * sizeof(int));
    int* fill = (int*)alloc(N_NODES * sizeof(int));
    int* psum = (int*)alloc(NB_SCAN * sizeof(int));
    int* srt  = (int*)alloc(N_MP * sizeof(int));
    ushort* x0b  = (ushort*)alloc((size_t)N_NODES * EMB * sizeof(ushort));
    ushort* bufA = (ushort*)alloc((size_t)N_NODES * EMB * sizeof(ushort));
    ushort* bufB = (ushort*)alloc((size_t)N_NODES * EMB * sizeof(ushort));
    ushort* bufC = (ushort*)alloc((size_t)N_NODES * EMB * sizeof(ushort));
    ushort* Wb[6];
    for (int i = 0; i < 6; ++i) Wb[i] = (ushort*)alloc((size_t)EMB * EMB * sizeof(ushort));
    (void)ws_size; (void)n_in; (void)in_sizes; (void)out_size;

    // hist+fill adjacent: one memset covers both
    hipMemsetAsync(hist, 0, (size_t)((char*)fill - (char*)hist) + N_NODES * sizeof(int), stream);

    f2b_kernel<<<(N_NODES * EMB / 8 + 255) / 256, 256, 0, stream>>>(x0, x0b, N_NODES * EMB / 8);
    for (int i = 0; i < 6; ++i)
        f2b_kernel<<<(EMB * EMB / 8 + 255) / 256, 256, 0, stream>>>(Wf[i], Wb[i], EMB * EMB / 8);

    hist_kernel<<<(N_MP + 255) / 256, 256, 0, stream>>>(mp_dst, N_MP, hist);
    scan_partial_kernel<<<NB_SCAN, 256, 0, stream>>>(hist, psum, N_NODES);
    scan_blocksums_kernel<<<1, 128, 0, stream>>>(psum, NB_SCAN);
    scan_final_kernel<<<NB_SCAN, 256, 0, stream>>>(hist, psum, rp, N_NODES);
    scatter_kernel<<<(N_MP + 255) / 256, 256, 0, stream>>>(mp_src, mp_dst, N_MP, rp, fill, srt);

    dim3 gemm_grid((N_NODES + BM - 1) / BM, 1);
    int agg_blocks = (N_NODES + 3) / 4;

    agg_kernel<<<agg_blocks, 256, 0, stream>>>(x0b, rp, srt, bufC);
    gemm_kernel<<<gemm_grid, 512, 0, stream>>>(bufC, x0b, Wb[0], Wb[1], bl1, bufA, N_NODES, 1);

    agg_kernel<<<agg_blocks, 256, 0, stream>>>(bufA, rp, srt, bufC);
    gemm_kernel<<<gemm_grid, 512, 0, stream>>>(bufC, bufA, Wb[2], Wb[3], bl2, bufB, N_NODES, 1);

    agg_kernel<<<agg_blocks, 256, 0, stream>>>(bufB, rp, srt, bufC);
    gemm_kernel<<<gemm_grid, 512, 0, stream>>>(bufC, bufB, Wb[4], Wb[5], bl3, bufA, N_NODES, 0);

    score_kernel<<<(N_SUP + 3) / 4, 256, 0, stream>>>(bufA, sup, scores);
}

// Round 10
// 640.594 us; speedup vs baseline: 1.2103x; 1.1304x over previous
//
#include <hip/hip_runtime.h>
#include <hip/hip_bf16.h>

#define N_NODES 100000
#define EMB 256
#define N_MP 1600000
#define N_SUP 200000

typedef __attribute__((ext_vector_type(4))) float f32x4;
typedef __attribute__((ext_vector_type(2))) float f32x2;
typedef __attribute__((ext_vector_type(8))) short s16x8;
typedef unsigned char uchar;

__device__ __forceinline__ int clampi(int v, int lo, int hi) {
    return v < lo ? lo : (v > hi ? hi : v);
}
__device__ __forceinline__ ushort f2bf(float f) {
    unsigned u = __float_as_uint(f);
    u += 0x7fffu + ((u >> 16) & 1u);   // round-to-nearest-even
    return (ushort)(u >> 16);
}
__device__ __forceinline__ float bf2f(ushort h) {
    return __uint_as_float(((unsigned)h) << 16);
}
// fp8 e4m3 HW converts; word-half selector must be an IMMEDIATE -> template
template <bool HI>
__device__ __forceinline__ f32x2 fp8_to_f32x2(unsigned w) {
    return __builtin_amdgcn_cvt_pk_f32_fp8(w, HI);
}
__device__ __forceinline__ unsigned f32x2_to_fp8(float a, float b) {
    return (unsigned)__builtin_amdgcn_cvt_pk_fp8_f32(a, b, 0, false) & 0xffffu;
}

#define GLOAD_LDS16(gsrc, ldst)                                                   \
    __builtin_amdgcn_global_load_lds(                                             \
        (const __attribute__((address_space(1))) void*)(gsrc),                    \
        (__attribute__((address_space(3))) void*)(ldst), 16, 0, 0)

// ------------- fp32 -> bf16 + fp8 convert (8 elems/thread) ----------------------

__global__ void f2b8_kernel(const float* __restrict__ in, ushort* __restrict__ outb,
                            uchar* __restrict__ out8, int n8) {
    int i = blockIdx.x * 256 + threadIdx.x;
    if (i >= n8) return;
    const float4* p = (const float4*)(in + (size_t)i * 8);
    float4 a = p[0], b = p[1];
    ushort4 lo = make_ushort4(f2bf(a.x), f2bf(a.y), f2bf(a.z), f2bf(a.w));
    ushort4 hi = make_ushort4(f2bf(b.x), f2bf(b.y), f2bf(b.z), f2bf(b.w));
    ushort4* q = (ushort4*)(outb + (size_t)i * 8);
    q[0] = lo; q[1] = hi;
    uint2 f8;
    f8.x = f32x2_to_fp8(a.x, a.y) | (f32x2_to_fp8(a.z, a.w) << 16);
    f8.y = f32x2_to_fp8(b.x, b.y) | (f32x2_to_fp8(b.z, b.w) << 16);
    *(uint2*)(out8 + (size_t)i * 8) = f8;
}

// one launch for all 6 weight matrices (bf16 only)
struct W6 { const float* p[6]; };
__global__ void wcvt_kernel(W6 ws, ushort* __restrict__ outbase) {
    int m = blockIdx.x >> 5;                      // 32 blocks per matrix
    int idx = (blockIdx.x & 31) * 256 + threadIdx.x;  // 0..8191
    const float4* p = (const float4*)(ws.p[m] + (size_t)idx * 8);
    float4 a = p[0], b = p[1];
    ushort4 lo = make_ushort4(f2bf(a.x), f2bf(a.y), f2bf(a.z), f2bf(a.w));
    ushort4 hi = make_ushort4(f2bf(b.x), f2bf(b.y), f2bf(b.z), f2bf(b.w));
    ushort4* q = (ushort4*)(outbase + (size_t)m * EMB * EMB + (size_t)idx * 8);
    q[0] = lo; q[1] = hi;
}

// ---------------- CSR build ----------------

__global__ void hist_kernel(const int* __restrict__ dst, int n, int* __restrict__ hist) {
    int i = blockIdx.x * 256 + threadIdx.x;
    if (i < n) atomicAdd(&hist[clampi(dst[i], 0, N_NODES - 1)], 1);
}

#define SCAN_CHUNK 1024
#define NB_SCAN ((N_NODES + SCAN_CHUNK - 1) / SCAN_CHUNK)   // 98

__global__ void scan_partial_kernel(const int* __restrict__ hist, int* __restrict__ psum, int n) {
    __shared__ int lds[4];
    int b = blockIdx.x;
    int tid = threadIdx.x, lane = tid & 63, wv = tid >> 6;
    int base = b * SCAN_CHUNK + tid * 4;
    int s = 0;
    if (base + 3 < n) {
        int4 v = *(const int4*)&hist[base];
        s = v.x + v.y + v.z + v.w;
    } else {
#pragma unroll
        for (int k = 0; k < 4; ++k) { int i = base + k; if (i < n) s += hist[i]; }
    }
#pragma unroll
    for (int off = 32; off; off >>= 1) s += __shfl_down(s, off, 64);
    if (lane == 0) lds[wv] = s;
    __syncthreads();
    if (tid == 0) psum[b] = lds[0] + lds[1] + lds[2] + lds[3];
}

__global__ void scan_blocksums_kernel(int* __restrict__ psum, int nb) {
    __shared__ int lds[128];
    int t = threadIdx.x;
    lds[t] = (t < nb) ? psum[t] : 0;
    __syncthreads();
    if (t == 0) {
        int run = 0;
        for (int i = 0; i < nb; ++i) { int v = lds[i]; lds[i] = run; run += v; }
    }
    __syncthreads();
    if (t < nb) psum[t] = lds[t];
}

__global__ void scan_final_kernel(const int* __restrict__ hist, const int* __restrict__ poff,
                                  int* __restrict__ rp, int n) {
    __shared__ int wsum[4];
    int b = blockIdx.x;
    int tid = threadIdx.x, lane = tid & 63, wv = tid >> 6;
    int base = b * SCAN_CHUNK + tid * 4;
    int v0 = 0, v1 = 0, v2 = 0, v3 = 0;
    if (base + 3 < n) {
        int4 v = *(const int4*)&hist[base];
        v0 = v.x; v1 = v.y; v2 = v.z; v3 = v.w;
    } else {
        if (base + 0 < n) v0 = hist[base + 0];
        if (base + 1 < n) v1 = hist[base + 1];
        if (base + 2 < n) v2 = hist[base + 2];
        if (base + 3 < n) v3 = hist[base + 3];
    }
    int s1 = v0 + v1, s2 = s1 + v2, s3 = s2 + v3;
    int t = s3;
#pragma unroll
    for (int off = 1; off < 64; off <<= 1) {
        int u = __shfl_up(t, off, 64);
        if (lane >= off) t += u;
    }
    if (lane == 63) wsum[wv] = t;
    __syncthreads();
    int woff = 0;
    for (int i = 0; i < wv; ++i) woff += wsum[i];
    int off0 = poff[b] + woff + (t - s3);
    if (base + 0 < n) rp[base + 1] = off0 + v0;
    if (base + 1 < n) rp[base + 2] = off0 + s1;
    if (base + 2 < n) rp[base + 3] = off0 + s2;
    if (base + 3 < n) rp[base + 4] = off0 + s3;
    if (b == 0 && tid == 0) rp[0] = 0;
}

__global__ void scatter_kernel(const int* __restrict__ src, const int* __restrict__ dst, int n,
                               const int* __restrict__ rp, int* __restrict__ fill,
                               int* __restrict__ srt) {
    int i = blockIdx.x * 256 + threadIdx.x;
    if (i < n) {
        int d = clampi(dst[i], 0, N_NODES - 1);
        int pos = rp[d] + atomicAdd(&fill[d], 1);
        if (pos >= 0 && pos < n) srt[pos] = clampi(src[i], 0, N_NODES - 1);
    }
}

// ------- mean aggregation v4: fp8 gather (halved bytes), fp32 accum, bf16 out ---

__global__ void agg_kernel(const uchar* __restrict__ x8, const int* __restrict__ rp,
                           const int* __restrict__ srt, ushort* __restrict__ outm) {
    int w = threadIdx.x >> 6;
    int lane = threadIdx.x & 63;
    int half = lane >> 5;
    int sl = lane & 31;
    int node = blockIdx.x * 4 + w;
    if (node >= N_NODES) return;
    int beg = rp[node], end = rp[node + 1];
    int deg = end - beg;
    float acc[8];
#pragma unroll
    for (int i = 0; i < 8; ++i) acc[i] = 0.f;

    for (int bse = 0; bse < deg; bse += 64) {
        int rem = deg - bse;
        int cnt = rem < 64 ? rem : 64;
        int myidx = (lane < cnt) ? srt[beg + bse + lane] : 0;
        for (int j = 0; j < cnt; j += 2) {
            int e = j + half;
            int s = __shfl(myidx, e & 63, 64);
            if (e < cnt) {
                uint2 v = *(const uint2*)&x8[(unsigned)s * EMB + sl * 8];
                f32x2 p0 = fp8_to_f32x2<false>(v.x);
                f32x2 p1 = fp8_to_f32x2<true>(v.x);
                f32x2 p2 = fp8_to_f32x2<false>(v.y);
                f32x2 p3 = fp8_to_f32x2<true>(v.y);
                acc[0] += p0.x; acc[1] += p0.y; acc[2] += p1.x; acc[3] += p1.y;
                acc[4] += p2.x; acc[5] += p2.y; acc[6] += p3.x; acc[7] += p3.y;
            }
        }
    }
#pragma unroll
    for (int i = 0; i < 8; ++i) acc[i] += __shfl_xor(acc[i], 32, 64);
    float inv = 1.0f / fmaxf((float)deg, 1.0f);
    if (half == 0) {
        s16x8 o;
#pragma unroll
        for (int i = 0; i < 8; ++i) o[i] = (short)f2bf(acc[i] * inv);
        *(s16x8*)&outm[(size_t)node * EMB + sl * 8] = o;
    }
}

// -------- bf16 MFMA GEMM: BM=128 x BN=256, 512 thr / 8 waves, BK=64 -------------
// optional fp8 shadow-write of the output (for the next layer's agg gather)

#define BM 128
#define BN 256
#define BKG 64

__global__ __launch_bounds__(512) void gemm_kernel(
    const ushort* __restrict__ Am, const ushort* __restrict__ Ax,
    const ushort* __restrict__ Wl, const ushort* __restrict__ Wr,
    const float* __restrict__ bias, ushort* __restrict__ out,
    uchar* __restrict__ out8, int M, int do_relu) {
    __shared__ ushort As[BM * BKG];   // 16 KiB
    __shared__ ushort Bs[BN * BKG];   // 32 KiB
    const int tid = threadIdx.x;
    const int lane = tid & 63;
    const int w = tid >> 6;           // 0..7
    const int m0 = blockIdx.x * BM;
    const int wr = w >> 2;            // 0..1
    const int wc = w & 3;             // 0..3

    f32x4 acc[4][4];
#pragma unroll
    for (int i = 0; i < 4; ++i)
#pragma unroll
        for (int j = 0; j < 4; ++j) acc[i][j] = (f32x4){0.f, 0.f, 0.f, 0.f};

    size_t srcA[2];
    int ldsoA[2];
#pragma unroll
    for (int j = 0; j < 2; ++j) {
        int c = j * 512 + tid;
        int r = c >> 3;
        int cc = (c & 7) ^ (r & 7);
        int arow = m0 + r; if (arow > M - 1) arow = M - 1;
        srcA[j] = (size_t)arow * EMB + cc * 8;
        ldsoA[j] = c * 8;
    }
    size_t srcB[4];
    int ldsoB[4];
#pragma unroll
    for (int j = 0; j < 4; ++j) {
        int c = j * 512 + tid;
        int r = c >> 3;
        int cc = (c & 7) ^ (r & 7);
        srcB[j] = (size_t)r * EMB + cc * 8;
        ldsoB[j] = c * 8;
    }

#pragma unroll
    for (int phase = 0; phase < 2; ++phase) {
        const ushort* A = phase ? Ax : Am;
        const ushort* W = phase ? Wr : Wl;
        for (int k0 = 0; k0 < EMB; k0 += BKG) {
#pragma unroll
            for (int j = 0; j < 2; ++j) GLOAD_LDS16(A + srcA[j] + k0, As + ldsoA[j]);
#pragma unroll
            for (int j = 0; j < 4; ++j) GLOAD_LDS16(W + srcB[j] + k0, Bs + ldsoB[j]);
            asm volatile("s_waitcnt vmcnt(0)" ::: "memory");
            __syncthreads();
#pragma unroll
            for (int ks = 0; ks < 2; ++ks) {
                const int ccr = ((ks * 4 + (lane >> 4)) ^ (lane & 7)) * 8;
                s16x8 af[4], bg[4];
#pragma unroll
                for (int mf = 0; mf < 4; ++mf) {
                    int r = wr * 64 + mf * 16 + (lane & 15);
                    af[mf] = *(const s16x8*)&As[r * BKG + ccr];
                }
#pragma unroll
                for (int nf = 0; nf < 4; ++nf) {
                    int r = wc * 64 + nf * 16 + (lane & 15);
                    bg[nf] = *(const s16x8*)&Bs[r * BKG + ccr];
                }
#pragma unroll
                for (int mf = 0; mf < 4; ++mf)
#pragma unroll
                    for (int nf = 0; nf < 4; ++nf)
                        acc[mf][nf] = __builtin_amdgcn_mfma_f32_16x16x32_bf16(
                            af[mf], bg[nf], acc[mf][nf], 0, 0, 0);
            }
            __syncthreads();
        }
    }

#pragma unroll
    for (int nf = 0; nf < 4; ++nf) {
        int col = wc * 64 + nf * 16 + (lane & 15);
        float bv = bias[col];
#pragma unroll
        for (int mf = 0; mf < 4; ++mf) {
            int rbase = m0 + wr * 64 + mf * 16 + ((lane >> 4) << 2);
#pragma unroll
            for (int q = 0; q < 4; ++q) {
                int row = rbase + q;
                if (row < M) {
                    float v = acc[mf][nf][q] + bv;
                    if (do_relu) v = fmaxf(v, 0.f);
                    out[(size_t)row * EMB + col] = f2bf(v);
                    if (out8) out8[(size_t)row * EMB + col] =
                        (uchar)(f32x2_to_fp8(v, 0.f) & 0xff);
                }
            }
        }
    }
}

// ------- supervision scores: wave per edge, both rows in one 16B/lane load -----

__global__ void score_kernel(const ushort* __restrict__ x, const int* __restrict__ sup,
                             float* __restrict__ out) {
    int w = threadIdx.x >> 6;
    int lane = threadIdx.x & 63;
    int half = lane >> 5;
    int sl = lane & 31;
    int e = blockIdx.x * 4 + w;
    if (e >= N_SUP) return;
    int s = clampi(sup[e], 0, N_NODES - 1);
    int d = clampi(sup[N_SUP + e], 0, N_NODES - 1);
    int row = half ? d : s;
    uint4 raw = *(const uint4*)&x[(unsigned)row * EMB + sl * 8];
    uint4 pr;
    pr.x = __shfl_xor(raw.x, 32, 64);
    pr.y = __shfl_xor(raw.y, 32, 64);
    pr.z = __shfl_xor(raw.z, 32, 64);
    pr.w = __shfl_xor(raw.w, 32, 64);
    float t = 0.f;
    unsigned a[4] = {raw.x, raw.y, raw.z, raw.w};
    unsigned b[4] = {pr.x, pr.y, pr.z, pr.w};
#pragma unroll
    for (int i = 0; i < 4; ++i) {
        t += bf2f((ushort)(a[i] & 0xffff)) * bf2f((ushort)(b[i] & 0xffff));
        t += bf2f((ushort)(a[i] >> 16)) * bf2f((ushort)(b[i] >> 16));
    }
#pragma unroll
    for (int off = 16; off > 0; off >>= 1) t += __shfl_xor(t, off, 64);
    if (lane == 0) out[e] = t;
}

// ---------------- launch ----------------

extern "C" void kernel_launch(void* const* d_in, const int* in_sizes, int n_in,
                              void* d_out, int out_size, void* d_ws, size_t ws_size,
                              hipStream_t stream) {
    const float* x0  = (const float*)d_in[0];
    const int*   mp  = (const int*)d_in[1];
    const int*   sup = (const int*)d_in[2];
    W6 wsrc;
    wsrc.p[0] = (const float*)d_in[3];   // Wl1
    wsrc.p[1] = (const float*)d_in[5];   // Wr1
    wsrc.p[2] = (const float*)d_in[6];   // Wl2
    wsrc.p[3] = (const float*)d_in[8];   // Wr2
    wsrc.p[4] = (const float*)d_in[9];   // Wl3
    wsrc.p[5] = (const float*)d_in[11];  // Wr3
    const float* bl1 = (const float*)d_in[4];
    const float* bl2 = (const float*)d_in[7];
    const float* bl3 = (const float*)d_in[10];
    float* scores = (float*)d_out;

    const int* mp_src = mp;
    const int* mp_dst = mp + N_MP;

    char* base = (char*)d_ws;
    size_t off = 0;
    auto alloc = [&](size_t bytes) {
        void* p = base + off;
        off = (off + bytes + 255) & ~(size_t)255;
        return p;
    };
    int* rp   = (int*)alloc((N_NODES + 1) * sizeof(int));
    int* hist = (int*)alloc(N_NODES * sizeof(int));
    int* fill = (int*)alloc(N_NODES * sizeof(int));
    int* psum = (int*)alloc(NB_SCAN * sizeof(int));
    int* srt  = (int*)alloc(N_MP * sizeof(int));
    ushort* x0b  = (ushort*)alloc((size_t)N_NODES * EMB * sizeof(ushort));
    ushort* bufA = (ushort*)alloc((size_t)N_NODES * EMB * sizeof(ushort));
    ushort* bufB = (ushort*)alloc((size_t)N_NODES * EMB * sizeof(ushort));
    ushort* bufC = (ushort*)alloc((size_t)N_NODES * EMB * sizeof(ushort));
    uchar*  x0f8 = (uchar*)alloc((size_t)N_NODES * EMB);
    uchar*  a8   = (uchar*)alloc((size_t)N_NODES * EMB);
    ushort* Wb   = (ushort*)alloc((size_t)6 * EMB * EMB * sizeof(ushort));
    (void)ws_size; (void)n_in; (void)in_sizes; (void)out_size;

    // hist+fill adjacent: one memset covers both
    (void)hipMemsetAsync(hist, 0,
        (size_t)((char*)fill - (char*)hist) + N_NODES * sizeof(int), stream);

    f2b8_kernel<<<(N_NODES * EMB / 8 + 255) / 256, 256, 0, stream>>>(
        x0, x0b, x0f8, N_NODES * EMB / 8);
    wcvt_kernel<<<192, 256, 0, stream>>>(wsrc, Wb);

    hist_kernel<<<(N_MP + 255) / 256, 256, 0, stream>>>(mp_dst, N_MP, hist);
    scan_partial_kernel<<<NB_SCAN, 256, 0, stream>>>(hist, psum, N_NODES);
    scan_blocksums_kernel<<<1, 128, 0, stream>>>(psum, NB_SCAN);
    scan_final_kernel<<<NB_SCAN, 256, 0, stream>>>(hist, psum, rp, N_NODES);
    scatter_kernel<<<(N_MP + 255) / 256, 256, 0, stream>>>(mp_src, mp_dst, N_MP, rp, fill, srt);

    dim3 gemm_grid((N_NODES + BM - 1) / BM, 1);
    int agg_blocks = (N_NODES + 3) / 4;

    ushort* Wl1 = Wb + 0 * EMB * EMB; ushort* Wr1 = Wb + 1 * EMB * EMB;
    ushort* Wl2 = Wb + 2 * EMB * EMB; ushort* Wr2 = Wb + 3 * EMB * EMB;
    ushort* Wl3 = Wb + 4 * EMB * EMB; ushort* Wr3 = Wb + 5 * EMB * EMB;

    agg_kernel<<<agg_blocks, 256, 0, stream>>>(x0f8, rp, srt, bufC);
    gemm_kernel<<<gemm_grid, 512, 0, stream>>>(bufC, x0b, Wl1, Wr1, bl1, bufA, a8, N_NODES, 1);

    agg_kernel<<<agg_blocks, 256, 0, stream>>>(a8, rp, srt, bufC);
    gemm_kernel<<<gemm_grid, 512, 0, stream>>>(bufC, bufA, Wl2, Wr2, bl2, bufB, a8, N_NODES, 1);

    agg_kernel<<<agg_blocks, 256, 0, stream>>>(a8, rp, srt, bufC);
    gemm_kernel<<<gemm_grid, 512, 0, stream>>>(bufC, bufB, Wl3, Wr3, bl3, bufA,
                                               (uchar*)nullptr, N_NODES, 0);

    score_kernel<<<(N_SUP + 3) / 4, 256, 0, stream>>>(bufA, sup, scores);
}

// Round 11
// 598.101 us; speedup vs baseline: 1.2963x; 1.0710x over previous
//
#include <hip/hip_runtime.h>
#include <hip/hip_bf16.h>

#define N_NODES 100000
#define EMB 256
#define N_MP 1600000
#define N_SUP 200000

typedef __attribute__((ext_vector_type(4))) float f32x4;
typedef __attribute__((ext_vector_type(2))) float f32x2;
typedef __attribute__((ext_vector_type(8))) short s16x8;
typedef unsigned char uchar;

__device__ __forceinline__ int clampi(int v, int lo, int hi) {
    return v < lo ? lo : (v > hi ? hi : v);
}
__device__ __forceinline__ ushort f2bf(float f) {
    unsigned u = __float_as_uint(f);
    u += 0x7fffu + ((u >> 16) & 1u);   // round-to-nearest-even
    return (ushort)(u >> 16);
}
__device__ __forceinline__ float bf2f(ushort h) {
    return __uint_as_float(((unsigned)h) << 16);
}
// fp8 e4m3 HW converts; word-half selector must be an IMMEDIATE -> template
template <bool HI>
__device__ __forceinline__ f32x2 fp8_to_f32x2(unsigned w) {
    return __builtin_amdgcn_cvt_pk_f32_fp8(w, HI);
}
__device__ __forceinline__ unsigned f32x2_to_fp8(float a, float b) {
    return (unsigned)__builtin_amdgcn_cvt_pk_fp8_f32(a, b, 0, false) & 0xffffu;
}

#define GLOAD_LDS16(gsrc, ldst)                                                   \
    __builtin_amdgcn_global_load_lds(                                             \
        (const __attribute__((address_space(1))) void*)(gsrc),                    \
        (__attribute__((address_space(3))) void*)(ldst), 16, 0, 0)

// ------------- fp32 -> bf16 + fp8 convert (8 elems/thread) ----------------------

__global__ void f2b8_kernel(const float* __restrict__ in, ushort* __restrict__ outb,
                            uchar* __restrict__ out8, int n8) {
    int i = blockIdx.x * 256 + threadIdx.x;
    if (i >= n8) return;
    const float4* p = (const float4*)(in + (size_t)i * 8);
    float4 a = p[0], b = p[1];
    ushort4 lo = make_ushort4(f2bf(a.x), f2bf(a.y), f2bf(a.z), f2bf(a.w));
    ushort4 hi = make_ushort4(f2bf(b.x), f2bf(b.y), f2bf(b.z), f2bf(b.w));
    ushort4* q = (ushort4*)(outb + (size_t)i * 8);
    q[0] = lo; q[1] = hi;
    uint2 f8;
    f8.x = f32x2_to_fp8(a.x, a.y) | (f32x2_to_fp8(a.z, a.w) << 16);
    f8.y = f32x2_to_fp8(b.x, b.y) | (f32x2_to_fp8(b.z, b.w) << 16);
    *(uint2*)(out8 + (size_t)i * 8) = f8;
}

// one launch for all 6 weight matrices (bf16 only)
struct W6 { const float* p[6]; };
__global__ void wcvt_kernel(W6 ws, ushort* __restrict__ outbase) {
    int m = blockIdx.x >> 5;                      // 32 blocks per matrix
    int idx = (blockIdx.x & 31) * 256 + threadIdx.x;  // 0..8191
    const float4* p = (const float4*)(ws.p[m] + (size_t)idx * 8);
    float4 a = p[0], b = p[1];
    ushort4 lo = make_ushort4(f2bf(a.x), f2bf(a.y), f2bf(a.z), f2bf(a.w));
    ushort4 hi = make_ushort4(f2bf(b.x), f2bf(b.y), f2bf(b.z), f2bf(b.w));
    ushort4* q = (ushort4*)(outbase + (size_t)m * EMB * EMB + (size_t)idx * 8);
    q[0] = lo; q[1] = hi;
}

// ---------------- CSR build: hist + scan ----------------

__global__ void hist_kernel(const int* __restrict__ dst, int n, int* __restrict__ hist) {
    int i = blockIdx.x * 256 + threadIdx.x;
    if (i < n) atomicAdd(&hist[clampi(dst[i], 0, N_NODES - 1)], 1);
}

#define SCAN_CHUNK 1024
#define NB_SCAN ((N_NODES + SCAN_CHUNK - 1) / SCAN_CHUNK)   // 98

__global__ void scan_partial_kernel(const int* __restrict__ hist, int* __restrict__ psum, int n) {
    __shared__ int lds[4];
    int b = blockIdx.x;
    int tid = threadIdx.x, lane = tid & 63, wv = tid >> 6;
    int base = b * SCAN_CHUNK + tid * 4;
    int s = 0;
    if (base + 3 < n) {
        int4 v = *(const int4*)&hist[base];
        s = v.x + v.y + v.z + v.w;
    } else {
#pragma unroll
        for (int k = 0; k < 4; ++k) { int i = base + k; if (i < n) s += hist[i]; }
    }
#pragma unroll
    for (int off = 32; off; off >>= 1) s += __shfl_down(s, off, 64);
    if (lane == 0) lds[wv] = s;
    __syncthreads();
    if (tid == 0) psum[b] = lds[0] + lds[1] + lds[2] + lds[3];
}

__global__ void scan_blocksums_kernel(int* __restrict__ psum, int nb) {
    __shared__ int lds[128];
    int t = threadIdx.x;
    lds[t] = (t < nb) ? psum[t] : 0;
    __syncthreads();
    if (t == 0) {
        int run = 0;
        for (int i = 0; i < nb; ++i) { int v = lds[i]; lds[i] = run; run += v; }
    }
    __syncthreads();
    if (t < nb) psum[t] = lds[t];
}

__global__ void scan_final_kernel(const int* __restrict__ hist, const int* __restrict__ poff,
                                  int* __restrict__ rp, int n) {
    __shared__ int wsum[4];
    int b = blockIdx.x;
    int tid = threadIdx.x, lane = tid & 63, wv = tid >> 6;
    int base = b * SCAN_CHUNK + tid * 4;
    int v0 = 0, v1 = 0, v2 = 0, v3 = 0;
    if (base + 3 < n) {
        int4 v = *(const int4*)&hist[base];
        v0 = v.x; v1 = v.y; v2 = v.z; v3 = v.w;
    } else {
        if (base + 0 < n) v0 = hist[base + 0];
        if (base + 1 < n) v1 = hist[base + 1];
        if (base + 2 < n) v2 = hist[base + 2];
        if (base + 3 < n) v3 = hist[base + 3];
    }
    int s1 = v0 + v1, s2 = s1 + v2, s3 = s2 + v3;
    int t = s3;
#pragma unroll
    for (int off = 1; off < 64; off <<= 1) {
        int u = __shfl_up(t, off, 64);
        if (lane >= off) t += u;
    }
    if (lane == 63) wsum[wv] = t;
    __syncthreads();
    int woff = 0;
    for (int i = 0; i < wv; ++i) woff += wsum[i];
    int off0 = poff[b] + woff + (t - s3);
    if (base + 0 < n) rp[base + 1] = off0 + v0;
    if (base + 1 < n) rp[base + 2] = off0 + s1;
    if (base + 2 < n) rp[base + 3] = off0 + s2;
    if (base + 3 < n) rp[base + 4] = off0 + s3;
    if (b == 0 && tid == 0) rp[0] = 0;
}

// ---------------- two-pass binned scatter (write-amplification fix) ----------
// bucket b = dst >> 9 (512 nodes each); NBUCK = ceil(N/512) = 196.
// Pass A: per-block LDS histogram -> one reservation atomic per (bucket,block)
//         -> contiguous ~21-entry runs per bucket. packed = (dlocal<<20)|src.
// Pass B: one block per bucket; scatter within the bucket's CSR window (one L2).

#define BSH 9
#define NBUCK ((N_NODES + 511) / 512)   // 196
#define EPB_A 4096                       // edges per bin block (1024 thr x 4)

__global__ void binit_kernel(const int* __restrict__ rp, int* __restrict__ gbfill) {
    int t = threadIdx.x;
    if (t < NBUCK) gbfill[t] = rp[t << BSH];
    else if (t < 256) gbfill[t] = 0;
}

__global__ __launch_bounds__(1024) void bin_kernel(
    const int* __restrict__ src, const int* __restrict__ dst, int n,
    int* __restrict__ gbfill, unsigned* __restrict__ packed) {
    __shared__ int cnt[256];
    __shared__ int base[256];
    int tid = threadIdx.x;
    if (tid < 256) cnt[tid] = 0;
    __syncthreads();
    int e0 = blockIdx.x * EPB_A + tid;
    int bk[4], rank[4], sv[4];
    bool valid[4];
#pragma unroll
    for (int k = 0; k < 4; ++k) {
        int e = e0 + k * 1024;
        valid[k] = e < n;
        if (valid[k]) {
            int d = clampi(dst[e], 0, N_NODES - 1);
            sv[k] = clampi(src[e], 0, N_NODES - 1);
            bk[k] = d >> BSH;
            int dl = d & 511;
            sv[k] |= (dl << 20);
            rank[k] = atomicAdd(&cnt[bk[k]], 1);
        }
    }
    __syncthreads();
    if (tid < 256) {
        int c = cnt[tid];
        base[tid] = c > 0 ? atomicAdd(&gbfill[tid], c) : 0;
    }
    __syncthreads();
#pragma unroll
    for (int k = 0; k < 4; ++k) {
        if (valid[k]) packed[base[bk[k]] + rank[k]] = (unsigned)sv[k];
    }
}

__global__ __launch_bounds__(1024) void debin_kernel(
    const unsigned* __restrict__ packed, const int* __restrict__ rp,
    int* __restrict__ srt) {
    __shared__ int fill[512];
    __shared__ int rpl[512];
    int b = blockIdx.x;
    int tid = threadIdx.x;
    int node0 = b << BSH;
    int nn = N_NODES - node0; if (nn > 512) nn = 512;
    if (tid < 512) {
        fill[tid] = 0;
        rpl[tid] = (tid < nn) ? rp[node0 + tid] : 0;
    }
    __syncthreads();
    int bstart = rp[node0];
    int bend = rp[node0 + nn];
    for (int e = bstart + tid; e < bend; e += 1024) {
        unsigned p = packed[e];
        int dl = p >> 20;
        int rank = atomicAdd(&fill[dl], 1);
        srt[rpl[dl] + rank] = (int)(p & 0xFFFFFu);
    }
}

// ------- mean aggregation v4: fp8 gather (halved bytes), fp32 accum, bf16 out ---

__global__ void agg_kernel(const uchar* __restrict__ x8, const int* __restrict__ rp,
                           const int* __restrict__ srt, ushort* __restrict__ outm) {
    int w = threadIdx.x >> 6;
    int lane = threadIdx.x & 63;
    int half = lane >> 5;
    int sl = lane & 31;
    int node = blockIdx.x * 4 + w;
    if (node >= N_NODES) return;
    int beg = rp[node], end = rp[node + 1];
    int deg = end - beg;
    float acc[8];
#pragma unroll
    for (int i = 0; i < 8; ++i) acc[i] = 0.f;

    for (int bse = 0; bse < deg; bse += 64) {
        int rem = deg - bse;
        int cnt = rem < 64 ? rem : 64;
        int myidx = (lane < cnt) ? srt[beg + bse + lane] : 0;
        for (int j = 0; j < cnt; j += 2) {
            int e = j + half;
            int s = __shfl(myidx, e & 63, 64);
            if (e < cnt) {
                uint2 v = *(const uint2*)&x8[(unsigned)s * EMB + sl * 8];
                f32x2 p0 = fp8_to_f32x2<false>(v.x);
                f32x2 p1 = fp8_to_f32x2<true>(v.x);
                f32x2 p2 = fp8_to_f32x2<false>(v.y);
                f32x2 p3 = fp8_to_f32x2<true>(v.y);
                acc[0] += p0.x; acc[1] += p0.y; acc[2] += p1.x; acc[3] += p1.y;
                acc[4] += p2.x; acc[5] += p2.y; acc[6] += p3.x; acc[7] += p3.y;
            }
        }
    }
#pragma unroll
    for (int i = 0; i < 8; ++i) acc[i] += __shfl_xor(acc[i], 32, 64);
    float inv = 1.0f / fmaxf((float)deg, 1.0f);
    if (half == 0) {
        s16x8 o;
#pragma unroll
        for (int i = 0; i < 8; ++i) o[i] = (short)f2bf(acc[i] * inv);
        *(s16x8*)&outm[(size_t)node * EMB + sl * 8] = o;
    }
}

// -------- bf16 MFMA GEMM: BM=128 x BN=256, 512 thr / 8 waves, BK=64 -------------
// optional fp8 shadow-write of the output (for the next layer's agg gather)

#define BM 128
#define BN 256
#define BKG 64

__global__ __launch_bounds__(512) void gemm_kernel(
    const ushort* __restrict__ Am, const ushort* __restrict__ Ax,
    const ushort* __restrict__ Wl, const ushort* __restrict__ Wr,
    const float* __restrict__ bias, ushort* __restrict__ out,
    uchar* __restrict__ out8, int M, int do_relu) {
    __shared__ ushort As[BM * BKG];   // 16 KiB
    __shared__ ushort Bs[BN * BKG];   // 32 KiB
    const int tid = threadIdx.x;
    const int lane = tid & 63;
    const int w = tid >> 6;           // 0..7
    const int m0 = blockIdx.x * BM;
    const int wr = w >> 2;            // 0..1
    const int wc = w & 3;             // 0..3

    f32x4 acc[4][4];
#pragma unroll
    for (int i = 0; i < 4; ++i)
#pragma unroll
        for (int j = 0; j < 4; ++j) acc[i][j] = (f32x4){0.f, 0.f, 0.f, 0.f};

    size_t srcA[2];
    int ldsoA[2];
#pragma unroll
    for (int j = 0; j < 2; ++j) {
        int c = j * 512 + tid;
        int r = c >> 3;
        int cc = (c & 7) ^ (r & 7);
        int arow = m0 + r; if (arow > M - 1) arow = M - 1;
        srcA[j] = (size_t)arow * EMB + cc * 8;
        ldsoA[j] = c * 8;
    }
    size_t srcB[4];
    int ldsoB[4];
#pragma unroll
    for (int j = 0; j < 4; ++j) {
        int c = j * 512 + tid;
        int r = c >> 3;
        int cc = (c & 7) ^ (r & 7);
        srcB[j] = (size_t)r * EMB + cc * 8;
        ldsoB[j] = c * 8;
    }

#pragma unroll
    for (int phase = 0; phase < 2; ++phase) {
        const ushort* A = phase ? Ax : Am;
        const ushort* W = phase ? Wr : Wl;
        for (int k0 = 0; k0 < EMB; k0 += BKG) {
#pragma unroll
            for (int j = 0; j < 2; ++j) GLOAD_LDS16(A + srcA[j] + k0, As + ldsoA[j]);
#pragma unroll
            for (int j = 0; j < 4; ++j) GLOAD_LDS16(W + srcB[j] + k0, Bs + ldsoB[j]);
            asm volatile("s_waitcnt vmcnt(0)" ::: "memory");
            __syncthreads();
#pragma unroll
            for (int ks = 0; ks < 2; ++ks) {
                const int ccr = ((ks * 4 + (lane >> 4)) ^ (lane & 7)) * 8;
                s16x8 af[4], bg[4];
#pragma unroll
                for (int mf = 0; mf < 4; ++mf) {
                    int r = wr * 64 + mf * 16 + (lane & 15);
                    af[mf] = *(const s16x8*)&As[r * BKG + ccr];
                }
#pragma unroll
                for (int nf = 0; nf < 4; ++nf) {
                    int r = wc * 64 + nf * 16 + (lane & 15);
                    bg[nf] = *(const s16x8*)&Bs[r * BKG + ccr];
                }
#pragma unroll
                for (int mf = 0; mf < 4; ++mf)
#pragma unroll
                    for (int nf = 0; nf < 4; ++nf)
                        acc[mf][nf] = __builtin_amdgcn_mfma_f32_16x16x32_bf16(
                            af[mf], bg[nf], acc[mf][nf], 0, 0, 0);
            }
            __syncthreads();
        }
    }

#pragma unroll
    for (int nf = 0; nf < 4; ++nf) {
        int col = wc * 64 + nf * 16 + (lane & 15);
        float bv = bias[col];
#pragma unroll
        for (int mf = 0; mf < 4; ++mf) {
            int rbase = m0 + wr * 64 + mf * 16 + ((lane >> 4) << 2);
#pragma unroll
            for (int q = 0; q < 4; ++q) {
                int row = rbase + q;
                if (row < M) {
                    float v = acc[mf][nf][q] + bv;
                    if (do_relu) v = fmaxf(v, 0.f);
                    out[(size_t)row * EMB + col] = f2bf(v);
                    if (out8) out8[(size_t)row * EMB + col] =
                        (uchar)(f32x2_to_fp8(v, 0.f) & 0xff);
                }
            }
        }
    }
}

// ------- supervision scores: wave per edge, both rows in one 16B/lane load -----

__global__ void score_kernel(const ushort* __restrict__ x, const int* __restrict__ sup,
                             float* __restrict__ out) {
    int w = threadIdx.x >> 6;
    int lane = threadIdx.x & 63;
    int half = lane >> 5;
    int sl = lane & 31;
    int e = blockIdx.x * 4 + w;
    if (e >= N_SUP) return;
    int s = clampi(sup[e], 0, N_NODES - 1);
    int d = clampi(sup[N_SUP + e], 0, N_NODES - 1);
    int row = half ? d : s;
    uint4 raw = *(const uint4*)&x[(unsigned)row * EMB + sl * 8];
    uint4 pr;
    pr.x = __shfl_xor(raw.x, 32, 64);
    pr.y = __shfl_xor(raw.y, 32, 64);
    pr.z = __shfl_xor(raw.z, 32, 64);
    pr.w = __shfl_xor(raw.w, 32, 64);
    float t = 0.f;
    unsigned a[4] = {raw.x, raw.y, raw.z, raw.w};
    unsigned b[4] = {pr.x, pr.y, pr.z, pr.w};
#pragma unroll
    for (int i = 0; i < 4; ++i) {
        t += bf2f((ushort)(a[i] & 0xffff)) * bf2f((ushort)(b[i] & 0xffff));
        t += bf2f((ushort)(a[i] >> 16)) * bf2f((ushort)(b[i] >> 16));
    }
#pragma unroll
    for (int off = 16; off > 0; off >>= 1) t += __shfl_xor(t, off, 64);
    if (lane == 0) out[e] = t;
}

// ---------------- launch ----------------

extern "C" void kernel_launch(void* const* d_in, const int* in_sizes, int n_in,
                              void* d_out, int out_size, void* d_ws, size_t ws_size,
                              hipStream_t stream) {
    const float* x0  = (const float*)d_in[0];
    const int*   mp  = (const int*)d_in[1];
    const int*   sup = (const int*)d_in[2];
    W6 wsrc;
    wsrc.p[0] = (const float*)d_in[3];   // Wl1
    wsrc.p[1] = (const float*)d_in[5];   // Wr1
    wsrc.p[2] = (const float*)d_in[6];   // Wl2
    wsrc.p[3] = (const float*)d_in[8];   // Wr2
    wsrc.p[4] = (const float*)d_in[9];   // Wl3
    wsrc.p[5] = (const float*)d_in[11];  // Wr3
    const float* bl1 = (const float*)d_in[4];
    const float* bl2 = (const float*)d_in[7];
    const float* bl3 = (const float*)d_in[10];
    float* scores = (float*)d_out;

    const int* mp_src = mp;
    const int* mp_dst = mp + N_MP;

    char* base = (char*)d_ws;
    size_t off = 0;
    auto alloc = [&](size_t bytes) {
        void* p = base + off;
        off = (off + bytes + 255) & ~(size_t)255;
        return p;
    };
    int* rp     = (int*)alloc((N_NODES + 1) * sizeof(int));
    int* hist   = (int*)alloc(N_NODES * sizeof(int));
    int* gbfill = (int*)alloc(256 * sizeof(int));
    int* psum   = (int*)alloc(NB_SCAN * sizeof(int));
    int* srt    = (int*)alloc(N_MP * sizeof(int));
    unsigned* packed = (unsigned*)alloc(N_MP * sizeof(unsigned));
    ushort* x0b  = (ushort*)alloc((size_t)N_NODES * EMB * sizeof(ushort));
    ushort* bufA = (ushort*)alloc((size_t)N_NODES * EMB * sizeof(ushort));
    ushort* bufB = (ushort*)alloc((size_t)N_NODES * EMB * sizeof(ushort));
    ushort* bufC = (ushort*)alloc((size_t)N_NODES * EMB * sizeof(ushort));
    uchar*  x0f8 = (uchar*)alloc((size_t)N_NODES * EMB);
    uchar*  a8   = (uchar*)alloc((size_t)N_NODES * EMB);
    ushort* Wb   = (ushort*)alloc((size_t)6 * EMB * EMB * sizeof(ushort));
    (void)ws_size; (void)n_in; (void)in_sizes; (void)out_size;

    (void)hipMemsetAsync(hist, 0, N_NODES * sizeof(int), stream);

    f2b8_kernel<<<(N_NODES * EMB / 8 + 255) / 256, 256, 0, stream>>>(
        x0, x0b, x0f8, N_NODES * EMB / 8);
    wcvt_kernel<<<192, 256, 0, stream>>>(wsrc, Wb);

    hist_kernel<<<(N_MP + 255) / 256, 256, 0, stream>>>(mp_dst, N_MP, hist);
    scan_partial_kernel<<<NB_SCAN, 256, 0, stream>>>(hist, psum, N_NODES);
    scan_blocksums_kernel<<<1, 128, 0, stream>>>(psum, NB_SCAN);
    scan_final_kernel<<<NB_SCAN, 256, 0, stream>>>(hist, psum, rp, N_NODES);

    binit_kernel<<<1, 256, 0, stream>>>(rp, gbfill);
    bin_kernel<<<(N_MP + EPB_A - 1) / EPB_A, 1024, 0, stream>>>(
        mp_src, mp_dst, N_MP, gbfill, packed);
    debin_kernel<<<NBUCK, 1024, 0, stream>>>(packed, rp, srt);

    dim3 gemm_grid((N_NODES + BM - 1) / BM, 1);
    int agg_blocks = (N_NODES + 3) / 4;

    ushort* Wl1 = Wb + 0 * EMB * EMB; ushort* Wr1 = Wb + 1 * EMB * EMB;
    ushort* Wl2 = Wb + 2 * EMB * EMB; ushort* Wr2 = Wb + 3 * EMB * EMB;
    ushort* Wl3 = Wb + 4 * EMB * EMB; ushort* Wr3 = Wb + 5 * EMB * EMB;

    agg_kernel<<<agg_blocks, 256, 0, stream>>>(x0f8, rp, srt, bufC);
    gemm_kernel<<<gemm_grid, 512, 0, stream>>>(bufC, x0b, Wl1, Wr1, bl1, bufA, a8, N_NODES, 1);

    agg_kernel<<<agg_blocks, 256, 0, stream>>>(a8, rp, srt, bufC);
    gemm_kernel<<<gemm_grid, 512, 0, stream>>>(bufC, bufA, Wl2, Wr2, bl2, bufB, a8, N_NODES, 1);

    agg_kernel<<<agg_blocks, 256, 0, stream>>>(a8, rp, srt, bufC);
    gemm_kernel<<<gemm_grid, 512, 0, stream>>>(bufC, bufB, Wl3, Wr3, bl3, bufA,
                                               (uchar*)nullptr, N_NODES, 0);

    score_kernel<<<(N_SUP + 3) / 4, 256, 0, stream>>>(bufA, sup, scores);
}

// Round 12
// 590.079 us; speedup vs baseline: 1.3139x; 1.0136x over previous
//
#include <hip/hip_runtime.h>
#include <hip/hip_bf16.h>

#define N_NODES 100000
#define EMB 256
#define N_MP 1600000
#define N_SUP 200000

typedef __attribute__((ext_vector_type(4))) float f32x4;
typedef __attribute__((ext_vector_type(2))) float f32x2;
typedef __attribute__((ext_vector_type(8))) short s16x8;
typedef unsigned char uchar;

__device__ __forceinline__ int clampi(int v, int lo, int hi) {
    return v < lo ? lo : (v > hi ? hi : v);
}
__device__ __forceinline__ ushort f2bf(float f) {
    unsigned u = __float_as_uint(f);
    u += 0x7fffu + ((u >> 16) & 1u);   // round-to-nearest-even
    return (ushort)(u >> 16);
}
__device__ __forceinline__ float bf2f(ushort h) {
    return __uint_as_float(((unsigned)h) << 16);
}
// fp8 e4m3 HW converts; word-half selector must be an IMMEDIATE -> template
template <bool HI>
__device__ __forceinline__ f32x2 fp8_to_f32x2(unsigned w) {
    return __builtin_amdgcn_cvt_pk_f32_fp8(w, HI);
}
__device__ __forceinline__ unsigned f32x2_to_fp8(float a, float b) {
    return (unsigned)__builtin_amdgcn_cvt_pk_fp8_f32(a, b, 0, false) & 0xffffu;
}

#define GLOAD_LDS16(gsrc, ldst)                                                   \
    __builtin_amdgcn_global_load_lds(                                             \
        (const __attribute__((address_space(1))) void*)(gsrc),                    \
        (__attribute__((address_space(3))) void*)(ldst), 16, 0, 0)

// ------------- fp32 -> bf16 + fp8 convert (8 elems/thread) ----------------------

__global__ void f2b8_kernel(const float* __restrict__ in, ushort* __restrict__ outb,
                            uchar* __restrict__ out8, int n8) {
    int i = blockIdx.x * 256 + threadIdx.x;
    if (i >= n8) return;
    const float4* p = (const float4*)(in + (size_t)i * 8);
    float4 a = p[0], b = p[1];
    ushort4 lo = make_ushort4(f2bf(a.x), f2bf(a.y), f2bf(a.z), f2bf(a.w));
    ushort4 hi = make_ushort4(f2bf(b.x), f2bf(b.y), f2bf(b.z), f2bf(b.w));
    ushort4* q = (ushort4*)(outb + (size_t)i * 8);
    q[0] = lo; q[1] = hi;
    uint2 f8;
    f8.x = f32x2_to_fp8(a.x, a.y) | (f32x2_to_fp8(a.z, a.w) << 16);
    f8.y = f32x2_to_fp8(b.x, b.y) | (f32x2_to_fp8(b.z, b.w) << 16);
    *(uint2*)(out8 + (size_t)i * 8) = f8;
}

// one launch for all 6 weight matrices (bf16 only)
struct W6 { const float* p[6]; };
__global__ void wcvt_kernel(W6 ws, ushort* __restrict__ outbase) {
    int m = blockIdx.x >> 5;                      // 32 blocks per matrix
    int idx = (blockIdx.x & 31) * 256 + threadIdx.x;  // 0..8191
    const float4* p = (const float4*)(ws.p[m] + (size_t)idx * 8);
    float4 a = p[0], b = p[1];
    ushort4 lo = make_ushort4(f2bf(a.x), f2bf(a.y), f2bf(a.z), f2bf(a.w));
    ushort4 hi = make_ushort4(f2bf(b.x), f2bf(b.y), f2bf(b.z), f2bf(b.w));
    ushort4* q = (ushort4*)(outbase + (size_t)m * EMB * EMB + (size_t)idx * 8);
    q[0] = lo; q[1] = hi;
}

// ---------------- CSR build: hist + scan ----------------

__global__ void hist_kernel(const int* __restrict__ dst, int n, int* __restrict__ hist) {
    int i = blockIdx.x * 256 + threadIdx.x;
    if (i < n) atomicAdd(&hist[clampi(dst[i], 0, N_NODES - 1)], 1);
}

#define SCAN_CHUNK 1024
#define NB_SCAN ((N_NODES + SCAN_CHUNK - 1) / SCAN_CHUNK)   // 98

__global__ void scan_partial_kernel(const int* __restrict__ hist, int* __restrict__ psum, int n) {
    __shared__ int lds[4];
    int b = blockIdx.x;
    int tid = threadIdx.x, lane = tid & 63, wv = tid >> 6;
    int base = b * SCAN_CHUNK + tid * 4;
    int s = 0;
    if (base + 3 < n) {
        int4 v = *(const int4*)&hist[base];
        s = v.x + v.y + v.z + v.w;
    } else {
#pragma unroll
        for (int k = 0; k < 4; ++k) { int i = base + k; if (i < n) s += hist[i]; }
    }
#pragma unroll
    for (int off = 32; off; off >>= 1) s += __shfl_down(s, off, 64);
    if (lane == 0) lds[wv] = s;
    __syncthreads();
    if (tid == 0) psum[b] = lds[0] + lds[1] + lds[2] + lds[3];
}

__global__ void scan_blocksums_kernel(int* __restrict__ psum, int nb) {
    __shared__ int lds[128];
    int t = threadIdx.x;
    lds[t] = (t < nb) ? psum[t] : 0;
    __syncthreads();
    if (t == 0) {
        int run = 0;
        for (int i = 0; i < nb; ++i) { int v = lds[i]; lds[i] = run; run += v; }
    }
    __syncthreads();
    if (t < nb) psum[t] = lds[t];
}

__global__ void scan_final_kernel(const int* __restrict__ hist, const int* __restrict__ poff,
                                  int* __restrict__ rp, int n) {
    __shared__ int wsum[4];
    int b = blockIdx.x;
    int tid = threadIdx.x, lane = tid & 63, wv = tid >> 6;
    int base = b * SCAN_CHUNK + tid * 4;
    int v0 = 0, v1 = 0, v2 = 0, v3 = 0;
    if (base + 3 < n) {
        int4 v = *(const int4*)&hist[base];
        v0 = v.x; v1 = v.y; v2 = v.z; v3 = v.w;
    } else {
        if (base + 0 < n) v0 = hist[base + 0];
        if (base + 1 < n) v1 = hist[base + 1];
        if (base + 2 < n) v2 = hist[base + 2];
        if (base + 3 < n) v3 = hist[base + 3];
    }
    int s1 = v0 + v1, s2 = s1 + v2, s3 = s2 + v3;
    int t = s3;
#pragma unroll
    for (int off = 1; off < 64; off <<= 1) {
        int u = __shfl_up(t, off, 64);
        if (lane >= off) t += u;
    }
    if (lane == 63) wsum[wv] = t;
    __syncthreads();
    int woff = 0;
    for (int i = 0; i < wv; ++i) woff += wsum[i];
    int off0 = poff[b] + woff + (t - s3);
    if (base + 0 < n) rp[base + 1] = off0 + v0;
    if (base + 1 < n) rp[base + 2] = off0 + s1;
    if (base + 2 < n) rp[base + 3] = off0 + s2;
    if (base + 3 < n) rp[base + 4] = off0 + s3;
    if (b == 0 && tid == 0) rp[0] = 0;
}

// ---------------- two-pass binned scatter ----------

#define BSH 9
#define NBUCK ((N_NODES + 511) / 512)   // 196
#define EPB_A 4096                       // edges per bin block (1024 thr x 4)

__global__ void binit_kernel(const int* __restrict__ rp, int* __restrict__ gbfill) {
    int t = threadIdx.x;
    if (t < NBUCK) gbfill[t] = rp[t << BSH];
    else if (t < 256) gbfill[t] = 0;
}

__global__ __launch_bounds__(1024) void bin_kernel(
    const int* __restrict__ src, const int* __restrict__ dst, int n,
    int* __restrict__ gbfill, unsigned* __restrict__ packed) {
    __shared__ int cnt[256];
    __shared__ int base[256];
    int tid = threadIdx.x;
    if (tid < 256) cnt[tid] = 0;
    __syncthreads();
    int e0 = blockIdx.x * EPB_A + tid;
    int bk[4], rank[4], sv[4];
    bool valid[4];
#pragma unroll
    for (int k = 0; k < 4; ++k) {
        int e = e0 + k * 1024;
        valid[k] = e < n;
        if (valid[k]) {
            int d = clampi(dst[e], 0, N_NODES - 1);
            sv[k] = clampi(src[e], 0, N_NODES - 1);
            bk[k] = d >> BSH;
            int dl = d & 511;
            sv[k] |= (dl << 20);
            rank[k] = atomicAdd(&cnt[bk[k]], 1);
        }
    }
    __syncthreads();
    if (tid < 256) {
        int c = cnt[tid];
        base[tid] = c > 0 ? atomicAdd(&gbfill[tid], c) : 0;
    }
    __syncthreads();
#pragma unroll
    for (int k = 0; k < 4; ++k) {
        if (valid[k]) packed[base[bk[k]] + rank[k]] = (unsigned)sv[k];
    }
}

__global__ __launch_bounds__(1024) void debin_kernel(
    const unsigned* __restrict__ packed, const int* __restrict__ rp,
    int* __restrict__ srt) {
    __shared__ int fill[512];
    __shared__ int rpl[512];
    int b = blockIdx.x;
    int tid = threadIdx.x;
    int node0 = b << BSH;
    int nn = N_NODES - node0; if (nn > 512) nn = 512;
    if (tid < 512) {
        fill[tid] = 0;
        rpl[tid] = (tid < nn) ? rp[node0 + tid] : 0;
    }
    __syncthreads();
    int bstart = rp[node0];
    int bend = rp[node0 + nn];
    for (int e = bstart + tid; e < bend; e += 1024) {
        unsigned p = packed[e];
        int dl = p >> 20;
        int rank = atomicAdd(&fill[dl], 1);
        srt[rpl[dl] + rank] = (int)(p & 0xFFFFFu);
    }
}

// ------- mean aggregation: fp8 gather, fp32 accum, bf16 out ---------------------

__global__ void agg_kernel(const uchar* __restrict__ x8, const int* __restrict__ rp,
                           const int* __restrict__ srt, ushort* __restrict__ outm) {
    int w = threadIdx.x >> 6;
    int lane = threadIdx.x & 63;
    int half = lane >> 5;
    int sl = lane & 31;
    int node = blockIdx.x * 4 + w;
    if (node >= N_NODES) return;
    int beg = rp[node], end = rp[node + 1];
    int deg = end - beg;
    float acc[8];
#pragma unroll
    for (int i = 0; i < 8; ++i) acc[i] = 0.f;

    for (int bse = 0; bse < deg; bse += 64) {
        int rem = deg - bse;
        int cnt = rem < 64 ? rem : 64;
        int myidx = (lane < cnt) ? srt[beg + bse + lane] : 0;
        for (int j = 0; j < cnt; j += 2) {
            int e = j + half;
            int s = __shfl(myidx, e & 63, 64);
            if (e < cnt) {
                uint2 v = *(const uint2*)&x8[(unsigned)s * EMB + sl * 8];
                f32x2 p0 = fp8_to_f32x2<false>(v.x);
                f32x2 p1 = fp8_to_f32x2<true>(v.x);
                f32x2 p2 = fp8_to_f32x2<false>(v.y);
                f32x2 p3 = fp8_to_f32x2<true>(v.y);
                acc[0] += p0.x; acc[1] += p0.y; acc[2] += p1.x; acc[3] += p1.y;
                acc[4] += p2.x; acc[5] += p2.y; acc[6] += p3.x; acc[7] += p3.y;
            }
        }
    }
#pragma unroll
    for (int i = 0; i < 8; ++i) acc[i] += __shfl_xor(acc[i], 32, 64);
    float inv = 1.0f / fmaxf((float)deg, 1.0f);
    if (half == 0) {
        s16x8 o;
#pragma unroll
        for (int i = 0; i < 8; ++i) o[i] = (short)f2bf(acc[i] * inv);
        *(s16x8*)&outm[(size_t)node * EMB + sl * 8] = o;
    }
}

// -------- bf16 MFMA GEMM: BM=128 x BN=256, 512 thr / 8 waves, BK=64 -------------
// LDS-repacked epilogue: acc -> LDS (bf16) -> linear wide global stores.
// LDS union: staging (As 16K + Bs 32K = 48K) reused as C-slab (64x256 bf16 = 32K)
// in two row-half passes -> keeps 48K total, 3 blocks/CU.

#define BM 128
#define BN 256
#define BKG 64

__global__ __launch_bounds__(512) void gemm_kernel(
    const ushort* __restrict__ Am, const ushort* __restrict__ Ax,
    const ushort* __restrict__ Wl, const ushort* __restrict__ Wr,
    const float* __restrict__ bias, ushort* __restrict__ out,
    uchar* __restrict__ out8, int M, int do_relu) {
    __shared__ ushort smem[BM * BKG + BN * BKG];   // 48 KiB
    ushort* As = smem;                 // [BM*BKG]
    ushort* Bs = smem + BM * BKG;      // [BN*BKG]
    ushort* Cs = smem;                 // reused: [64*BN] = 32 KiB
    const int tid = threadIdx.x;
    const int lane = tid & 63;
    const int w = tid >> 6;           // 0..7
    const int m0 = blockIdx.x * BM;
    const int wr = w >> 2;            // 0..1
    const int wc = w & 3;             // 0..3

    f32x4 acc[4][4];
#pragma unroll
    for (int i = 0; i < 4; ++i)
#pragma unroll
        for (int j = 0; j < 4; ++j) acc[i][j] = (f32x4){0.f, 0.f, 0.f, 0.f};

    size_t srcA[2];
    int ldsoA[2];
#pragma unroll
    for (int j = 0; j < 2; ++j) {
        int c = j * 512 + tid;
        int r = c >> 3;
        int cc = (c & 7) ^ (r & 7);
        int arow = m0 + r; if (arow > M - 1) arow = M - 1;
        srcA[j] = (size_t)arow * EMB + cc * 8;
        ldsoA[j] = c * 8;
    }
    size_t srcB[4];
    int ldsoB[4];
#pragma unroll
    for (int j = 0; j < 4; ++j) {
        int c = j * 512 + tid;
        int r = c >> 3;
        int cc = (c & 7) ^ (r & 7);
        srcB[j] = (size_t)r * EMB + cc * 8;
        ldsoB[j] = c * 8;
    }

#pragma unroll
    for (int phase = 0; phase < 2; ++phase) {
        const ushort* A = phase ? Ax : Am;
        const ushort* W = phase ? Wr : Wl;
        for (int k0 = 0; k0 < EMB; k0 += BKG) {
#pragma unroll
            for (int j = 0; j < 2; ++j) GLOAD_LDS16(A + srcA[j] + k0, As + ldsoA[j]);
#pragma unroll
            for (int j = 0; j < 4; ++j) GLOAD_LDS16(W + srcB[j] + k0, Bs + ldsoB[j]);
            asm volatile("s_waitcnt vmcnt(0)" ::: "memory");
            __syncthreads();
#pragma unroll
            for (int ks = 0; ks < 2; ++ks) {
                const int ccr = ((ks * 4 + (lane >> 4)) ^ (lane & 7)) * 8;
                s16x8 af[4], bg[4];
#pragma unroll
                for (int mf = 0; mf < 4; ++mf) {
                    int r = wr * 64 + mf * 16 + (lane & 15);
                    af[mf] = *(const s16x8*)&As[r * BKG + ccr];
                }
#pragma unroll
                for (int nf = 0; nf < 4; ++nf) {
                    int r = wc * 64 + nf * 16 + (lane & 15);
                    bg[nf] = *(const s16x8*)&Bs[r * BKG + ccr];
                }
#pragma unroll
                for (int mf = 0; mf < 4; ++mf)
#pragma unroll
                    for (int nf = 0; nf < 4; ++nf)
                        acc[mf][nf] = __builtin_amdgcn_mfma_f32_16x16x32_bf16(
                            af[mf], bg[nf], acc[mf][nf], 0, 0, 0);
            }
            __syncthreads();
        }
    }

    // ---- epilogue: two row-half passes through LDS, then linear stores ----
#pragma unroll
    for (int p = 0; p < 2; ++p) {
        if (wr == p) {
#pragma unroll
            for (int nf = 0; nf < 4; ++nf) {
                int col = wc * 64 + nf * 16 + (lane & 15);
                float bv = bias[col];
#pragma unroll
                for (int mf = 0; mf < 4; ++mf) {
                    int rl = mf * 16 + ((lane >> 4) << 2);   // 0..63 local row
#pragma unroll
                    for (int q = 0; q < 4; ++q) {
                        float v = acc[mf][nf][q] + bv;
                        if (do_relu) v = fmaxf(v, 0.f);
                        Cs[(rl + q) * BN + col] = f2bf(v);
                    }
                }
            }
        }
        __syncthreads();
        // copy out 64 rows (= 2048 uint4); 512 threads x 4
#pragma unroll
        for (int i = 0; i < 4; ++i) {
            int idx = i * 512 + tid;          // uint4 index; 32 per row
            int row = m0 + p * 64 + (idx >> 5);
            if (row < M) {
                uint4 v = ((const uint4*)Cs)[idx];
                *(uint4*)&out[(size_t)row * EMB + (idx & 31) * 8] = v;
                if (out8) {
                    const ushort* pu = (const ushort*)&v;
                    unsigned lo = f32x2_to_fp8(bf2f(pu[0]), bf2f(pu[1])) |
                                  (f32x2_to_fp8(bf2f(pu[2]), bf2f(pu[3])) << 16);
                    unsigned hi = f32x2_to_fp8(bf2f(pu[4]), bf2f(pu[5])) |
                                  (f32x2_to_fp8(bf2f(pu[6]), bf2f(pu[7])) << 16);
                    *(uint2*)&out8[(size_t)row * EMB + (idx & 31) * 8] =
                        make_uint2(lo, hi);
                }
            }
        }
        __syncthreads();
    }
}

// ------- supervision scores: wave per edge, both rows in one 16B/lane load -----

__global__ void score_kernel(const ushort* __restrict__ x, const int* __restrict__ sup,
                             float* __restrict__ out) {
    int w = threadIdx.x >> 6;
    int lane = threadIdx.x & 63;
    int half = lane >> 5;
    int sl = lane & 31;
    int e = blockIdx.x * 4 + w;
    if (e >= N_SUP) return;
    int s = clampi(sup[e], 0, N_NODES - 1);
    int d = clampi(sup[N_SUP + e], 0, N_NODES - 1);
    int row = half ? d : s;
    uint4 raw = *(const uint4*)&x[(unsigned)row * EMB + sl * 8];
    uint4 pr;
    pr.x = __shfl_xor(raw.x, 32, 64);
    pr.y = __shfl_xor(raw.y, 32, 64);
    pr.z = __shfl_xor(raw.z, 32, 64);
    pr.w = __shfl_xor(raw.w, 32, 64);
    float t = 0.f;
    unsigned a[4] = {raw.x, raw.y, raw.z, raw.w};
    unsigned b[4] = {pr.x, pr.y, pr.z, pr.w};
#pragma unroll
    for (int i = 0; i < 4; ++i) {
        t += bf2f((ushort)(a[i] & 0xffff)) * bf2f((ushort)(b[i] & 0xffff));
        t += bf2f((ushort)(a[i] >> 16)) * bf2f((ushort)(b[i] >> 16));
    }
#pragma unroll
    for (int off = 16; off > 0; off >>= 1) t += __shfl_xor(t, off, 64);
    if (lane == 0) out[e] = t;
}

// ---------------- launch ----------------

extern "C" void kernel_launch(void* const* d_in, const int* in_sizes, int n_in,
                              void* d_out, int out_size, void* d_ws, size_t ws_size,
                              hipStream_t stream) {
    const float* x0  = (const float*)d_in[0];
    const int*   mp  = (const int*)d_in[1];
    const int*   sup = (const int*)d_in[2];
    W6 wsrc;
    wsrc.p[0] = (const float*)d_in[3];   // Wl1
    wsrc.p[1] = (const float*)d_in[5];   // Wr1
    wsrc.p[2] = (const float*)d_in[6];   // Wl2
    wsrc.p[3] = (const float*)d_in[8];   // Wr2
    wsrc.p[4] = (const float*)d_in[9];   // Wl3
    wsrc.p[5] = (const float*)d_in[11];  // Wr3
    const float* bl1 = (const float*)d_in[4];
    const float* bl2 = (const float*)d_in[7];
    const float* bl3 = (const float*)d_in[10];
    float* scores = (float*)d_out;

    const int* mp_src = mp;
    const int* mp_dst = mp + N_MP;

    char* base = (char*)d_ws;
    size_t off = 0;
    auto alloc = [&](size_t bytes) {
        void* p = base + off;
        off = (off + bytes + 255) & ~(size_t)255;
        return p;
    };
    int* rp     = (int*)alloc((N_NODES + 1) * sizeof(int));
    int* hist   = (int*)alloc(N_NODES * sizeof(int));
    int* gbfill = (int*)alloc(256 * sizeof(int));
    int* psum   = (int*)alloc(NB_SCAN * sizeof(int));
    int* srt    = (int*)alloc(N_MP * sizeof(int));
    unsigned* packed = (unsigned*)alloc(N_MP * sizeof(unsigned));
    ushort* x0b  = (ushort*)alloc((size_t)N_NODES * EMB * sizeof(ushort));
    ushort* bufA = (ushort*)alloc((size_t)N_NODES * EMB * sizeof(ushort));
    ushort* bufB = (ushort*)alloc((size_t)N_NODES * EMB * sizeof(ushort));
    ushort* bufC = (ushort*)alloc((size_t)N_NODES * EMB * sizeof(ushort));
    uchar*  x0f8 = (uchar*)alloc((size_t)N_NODES * EMB);
    uchar*  a8   = (uchar*)alloc((size_t)N_NODES * EMB);
    ushort* Wb   = (ushort*)alloc((size_t)6 * EMB * EMB * sizeof(ushort));
    (void)ws_size; (void)n_in; (void)in_sizes; (void)out_size;

    (void)hipMemsetAsync(hist, 0, N_NODES * sizeof(int), stream);

    f2b8_kernel<<<(N_NODES * EMB / 8 + 255) / 256, 256, 0, stream>>>(
        x0, x0b, x0f8, N_NODES * EMB / 8);
    wcvt_kernel<<<192, 256, 0, stream>>>(wsrc, Wb);

    hist_kernel<<<(N_MP + 255) / 256, 256, 0, stream>>>(mp_dst, N_MP, hist);
    scan_partial_kernel<<<NB_SCAN, 256, 0, stream>>>(hist, psum, N_NODES);
    scan_blocksums_kernel<<<1, 128, 0, stream>>>(psum, NB_SCAN);
    scan_final_kernel<<<NB_SCAN, 256, 0, stream>>>(hist, psum, rp, N_NODES);

    binit_kernel<<<1, 256, 0, stream>>>(rp, gbfill);
    bin_kernel<<<(N_MP + EPB_A - 1) / EPB_A, 1024, 0, stream>>>(
        mp_src, mp_dst, N_MP, gbfill, packed);
    debin_kernel<<<NBUCK, 1024, 0, stream>>>(packed, rp, srt);

    dim3 gemm_grid((N_NODES + BM - 1) / BM, 1);
    int agg_blocks = (N_NODES + 3) / 4;

    ushort* Wl1 = Wb + 0 * EMB * EMB; ushort* Wr1 = Wb + 1 * EMB * EMB;
    ushort* Wl2 = Wb + 2 * EMB * EMB; ushort* Wr2 = Wb + 3 * EMB * EMB;
    ushort* Wl3 = Wb + 4 * EMB * EMB; ushort* Wr3 = Wb + 5 * EMB * EMB;

    agg_kernel<<<agg_blocks, 256, 0, stream>>>(x0f8, rp, srt, bufC);
    gemm_kernel<<<gemm_grid, 512, 0, stream>>>(bufC, x0b, Wl1, Wr1, bl1, bufA, a8, N_NODES, 1);

    agg_kernel<<<agg_blocks, 256, 0, stream>>>(a8, rp, srt, bufC);
    gemm_kernel<<<gemm_grid, 512, 0, stream>>>(bufC, bufA, Wl2, Wr2, bl2, bufB, a8, N_NODES, 1);

    agg_kernel<<<agg_blocks, 256, 0, stream>>>(a8, rp, srt, bufC);
    gemm_kernel<<<gemm_grid, 512, 0, stream>>>(bufC, bufB, Wl3, Wr3, bl3, bufA,
                                               (uchar*)nullptr, N_NODES, 0);

    score_kernel<<<(N_SUP + 3) / 4, 256, 0, stream>>>(bufA, sup, scores);
}

// Round 13
// 564.039 us; speedup vs baseline: 1.3746x; 1.0462x over previous
//
#include <hip/hip_runtime.h>
#include <hip/hip_bf16.h>

#define N_NODES 100000
#define EMB 256
#define N_MP 1600000
#define N_SUP 200000

typedef __attribute__((ext_vector_type(4))) float f32x4;
typedef __attribute__((ext_vector_type(2))) float f32x2;
typedef __attribute__((ext_vector_type(8))) short s16x8;
typedef unsigned char uchar;

__device__ __forceinline__ int clampi(int v, int lo, int hi) {
    return v < lo ? lo : (v > hi ? hi : v);
}
__device__ __forceinline__ ushort f2bf(float f) {
    unsigned u = __float_as_uint(f);
    u += 0x7fffu + ((u >> 16) & 1u);   // round-to-nearest-even
    return (ushort)(u >> 16);
}
__device__ __forceinline__ float bf2f(ushort h) {
    return __uint_as_float(((unsigned)h) << 16);
}
// fp8 e4m3 HW converts; word-half selector must be an IMMEDIATE -> template
template <bool HI>
__device__ __forceinline__ f32x2 fp8_to_f32x2(unsigned w) {
    return __builtin_amdgcn_cvt_pk_f32_fp8(w, HI);
}
__device__ __forceinline__ unsigned f32x2_to_fp8(float a, float b) {
    return (unsigned)__builtin_amdgcn_cvt_pk_fp8_f32(a, b, 0, false) & 0xffffu;
}

#define GLOAD_LDS16(gsrc, ldst)                                                   \
    __builtin_amdgcn_global_load_lds(                                             \
        (const __attribute__((address_space(1))) void*)(gsrc),                    \
        (__attribute__((address_space(3))) void*)(ldst), 16, 0, 0)

// ------------- fp32 -> bf16 + fp8 convert (8 elems/thread) ----------------------

__global__ void f2b8_kernel(const float* __restrict__ in, ushort* __restrict__ outb,
                            uchar* __restrict__ out8, int n8) {
    int i = blockIdx.x * 256 + threadIdx.x;
    if (i >= n8) return;
    const float4* p = (const float4*)(in + (size_t)i * 8);
    float4 a = p[0], b = p[1];
    ushort4 lo = make_ushort4(f2bf(a.x), f2bf(a.y), f2bf(a.z), f2bf(a.w));
    ushort4 hi = make_ushort4(f2bf(b.x), f2bf(b.y), f2bf(b.z), f2bf(b.w));
    ushort4* q = (ushort4*)(outb + (size_t)i * 8);
    q[0] = lo; q[1] = hi;
    uint2 f8;
    f8.x = f32x2_to_fp8(a.x, a.y) | (f32x2_to_fp8(a.z, a.w) << 16);
    f8.y = f32x2_to_fp8(b.x, b.y) | (f32x2_to_fp8(b.z, b.w) << 16);
    *(uint2*)(out8 + (size_t)i * 8) = f8;
}

// one launch for all 6 weight matrices (bf16 only)
struct W6 { const float* p[6]; };
__global__ void wcvt_kernel(W6 ws, ushort* __restrict__ outbase) {
    int m = blockIdx.x >> 5;                      // 32 blocks per matrix
    int idx = (blockIdx.x & 31) * 256 + threadIdx.x;  // 0..8191
    const float4* p = (const float4*)(ws.p[m] + (size_t)idx * 8);
    float4 a = p[0], b = p[1];
    ushort4 lo = make_ushort4(f2bf(a.x), f2bf(a.y), f2bf(a.z), f2bf(a.w));
    ushort4 hi = make_ushort4(f2bf(b.x), f2bf(b.y), f2bf(b.z), f2bf(b.w));
    ushort4* q = (ushort4*)(outbase + (size_t)m * EMB * EMB + (size_t)idx * 8);
    q[0] = lo; q[1] = hi;
}

// ---------------- CSR build: hist + scan ----------------

__global__ void hist_kernel(const int* __restrict__ dst, int n, int* __restrict__ hist) {
    int i = blockIdx.x * 256 + threadIdx.x;
    if (i < n) atomicAdd(&hist[clampi(dst[i], 0, N_NODES - 1)], 1);
}

#define SCAN_CHUNK 1024
#define NB_SCAN ((N_NODES + SCAN_CHUNK - 1) / SCAN_CHUNK)   // 98

__global__ void scan_partial_kernel(const int* __restrict__ hist, int* __restrict__ psum, int n) {
    __shared__ int lds[4];
    int b = blockIdx.x;
    int tid = threadIdx.x, lane = tid & 63, wv = tid >> 6;
    int base = b * SCAN_CHUNK + tid * 4;
    int s = 0;
    if (base + 3 < n) {
        int4 v = *(const int4*)&hist[base];
        s = v.x + v.y + v.z + v.w;
    } else {
#pragma unroll
        for (int k = 0; k < 4; ++k) { int i = base + k; if (i < n) s += hist[i]; }
    }
#pragma unroll
    for (int off = 32; off; off >>= 1) s += __shfl_down(s, off, 64);
    if (lane == 0) lds[wv] = s;
    __syncthreads();
    if (tid == 0) psum[b] = lds[0] + lds[1] + lds[2] + lds[3];
}

__global__ void scan_blocksums_kernel(int* __restrict__ psum, int nb) {
    __shared__ int lds[128];
    int t = threadIdx.x;
    lds[t] = (t < nb) ? psum[t] : 0;
    __syncthreads();
    if (t == 0) {
        int run = 0;
        for (int i = 0; i < nb; ++i) { int v = lds[i]; lds[i] = run; run += v; }
    }
    __syncthreads();
    if (t < nb) psum[t] = lds[t];
}

__global__ void scan_final_kernel(const int* __restrict__ hist, const int* __restrict__ poff,
                                  int* __restrict__ rp, int n) {
    __shared__ int wsum[4];
    int b = blockIdx.x;
    int tid = threadIdx.x, lane = tid & 63, wv = tid >> 6;
    int base = b * SCAN_CHUNK + tid * 4;
    int v0 = 0, v1 = 0, v2 = 0, v3 = 0;
    if (base + 3 < n) {
        int4 v = *(const int4*)&hist[base];
        v0 = v.x; v1 = v.y; v2 = v.z; v3 = v.w;
    } else {
        if (base + 0 < n) v0 = hist[base + 0];
        if (base + 1 < n) v1 = hist[base + 1];
        if (base + 2 < n) v2 = hist[base + 2];
        if (base + 3 < n) v3 = hist[base + 3];
    }
    int s1 = v0 + v1, s2 = s1 + v2, s3 = s2 + v3;
    int t = s3;
#pragma unroll
    for (int off = 1; off < 64; off <<= 1) {
        int u = __shfl_up(t, off, 64);
        if (lane >= off) t += u;
    }
    if (lane == 63) wsum[wv] = t;
    __syncthreads();
    int woff = 0;
    for (int i = 0; i < wv; ++i) woff += wsum[i];
    int off0 = poff[b] + woff + (t - s3);
    if (base + 0 < n) rp[base + 1] = off0 + v0;
    if (base + 1 < n) rp[base + 2] = off0 + s1;
    if (base + 2 < n) rp[base + 3] = off0 + s2;
    if (base + 3 < n) rp[base + 4] = off0 + s3;
    if (b == 0 && tid == 0) rp[0] = 0;
}

// ---------------- two-pass binned scatter ----------

#define BSH 9
#define NBUCK ((N_NODES + 511) / 512)   // 196
#define EPB_A 4096                       // edges per bin block (1024 thr x 4)

__global__ void binit_kernel(const int* __restrict__ rp, int* __restrict__ gbfill) {
    int t = threadIdx.x;
    if (t < NBUCK) gbfill[t] = rp[t << BSH];
    else if (t < 256) gbfill[t] = 0;
}

__global__ __launch_bounds__(1024) void bin_kernel(
    const int* __restrict__ src, const int* __restrict__ dst, int n,
    int* __restrict__ gbfill, unsigned* __restrict__ packed) {
    __shared__ int cnt[256];
    __shared__ int base[256];
    int tid = threadIdx.x;
    if (tid < 256) cnt[tid] = 0;
    __syncthreads();
    int e0 = blockIdx.x * EPB_A + tid;
    int bk[4], rank[4], sv[4];
    bool valid[4];
#pragma unroll
    for (int k = 0; k < 4; ++k) {
        int e = e0 + k * 1024;
        valid[k] = e < n;
        if (valid[k]) {
            int d = clampi(dst[e], 0, N_NODES - 1);
            sv[k] = clampi(src[e], 0, N_NODES - 1);
            bk[k] = d >> BSH;
            int dl = d & 511;
            sv[k] |= (dl << 20);
            rank[k] = atomicAdd(&cnt[bk[k]], 1);
        }
    }
    __syncthreads();
    if (tid < 256) {
        int c = cnt[tid];
        base[tid] = c > 0 ? atomicAdd(&gbfill[tid], c) : 0;
    }
    __syncthreads();
#pragma unroll
    for (int k = 0; k < 4; ++k) {
        if (valid[k]) packed[base[bk[k]] + rank[k]] = (unsigned)sv[k];
    }
}

__global__ __launch_bounds__(1024) void debin_kernel(
    const unsigned* __restrict__ packed, const int* __restrict__ rp,
    int* __restrict__ srt) {
    __shared__ int fill[512];
    __shared__ int rpl[512];
    int b = blockIdx.x;
    int tid = threadIdx.x;
    int node0 = b << BSH;
    int nn = N_NODES - node0; if (nn > 512) nn = 512;
    if (tid < 512) {
        fill[tid] = 0;
        rpl[tid] = (tid < nn) ? rp[node0 + tid] : 0;
    }
    __syncthreads();
    int bstart = rp[node0];
    int bend = rp[node0 + nn];
    for (int e = bstart + tid; e < bend; e += 1024) {
        unsigned p = packed[e];
        int dl = p >> 20;
        int rank = atomicAdd(&fill[dl], 1);
        srt[rpl[dl] + rank] = (int)(p & 0xFFFFFu);
    }
}

// ------- mean aggregation v5: quarter-wave rows, 16B/lane, 4 edges/load-instr ---
// Wave of 64 = 4 quarters x 16 lanes. Quarter qw owns edge j+qw; lane sl owns
// fp8 cols [sl*16, sl*16+16). Quarters folded via shfl_xor(32), shfl_xor(16).

__global__ void agg_kernel(const uchar* __restrict__ x8, const int* __restrict__ rp,
                           const int* __restrict__ srt, ushort* __restrict__ outm) {
    int w = threadIdx.x >> 6;
    int lane = threadIdx.x & 63;
    int qw = lane >> 4;
    int sl = lane & 15;
    int node = blockIdx.x * 4 + w;
    if (node >= N_NODES) return;
    int beg = rp[node], end = rp[node + 1];
    int deg = end - beg;
    float acc[16];
#pragma unroll
    for (int i = 0; i < 16; ++i) acc[i] = 0.f;

    for (int bse = 0; bse < deg; bse += 64) {
        int rem = deg - bse;
        int cnt = rem < 64 ? rem : 64;
        int myidx = (lane < cnt) ? srt[beg + bse + lane] : 0;
        for (int j = 0; j < cnt; j += 4) {
            int e = j + qw;
            int s = __shfl(myidx, e < cnt ? e : 0, 64);
            if (e < cnt) {
                uint4 v = *(const uint4*)&x8[(unsigned)s * EMB + sl * 16];
                f32x2 p;
                p = fp8_to_f32x2<false>(v.x); acc[0] += p.x; acc[1] += p.y;
                p = fp8_to_f32x2<true >(v.x); acc[2] += p.x; acc[3] += p.y;
                p = fp8_to_f32x2<false>(v.y); acc[4] += p.x; acc[5] += p.y;
                p = fp8_to_f32x2<true >(v.y); acc[6] += p.x; acc[7] += p.y;
                p = fp8_to_f32x2<false>(v.z); acc[8] += p.x; acc[9] += p.y;
                p = fp8_to_f32x2<true >(v.z); acc[10] += p.x; acc[11] += p.y;
                p = fp8_to_f32x2<false>(v.w); acc[12] += p.x; acc[13] += p.y;
                p = fp8_to_f32x2<true >(v.w); acc[14] += p.x; acc[15] += p.y;
            }
        }
    }
    // fold quarters: qw0<-qw2 etc, then qw0<-qw1
#pragma unroll
    for (int i = 0; i < 16; ++i) acc[i] += __shfl_xor(acc[i], 32, 64);
#pragma unroll
    for (int i = 0; i < 16; ++i) acc[i] += __shfl_xor(acc[i], 16, 64);
    float inv = 1.0f / fmaxf((float)deg, 1.0f);
    if (qw == 0) {
        s16x8 o0, o1;
#pragma unroll
        for (int i = 0; i < 8; ++i) o0[i] = (short)f2bf(acc[i] * inv);
#pragma unroll
        for (int i = 0; i < 8; ++i) o1[i] = (short)f2bf(acc[8 + i] * inv);
        *(s16x8*)&outm[(size_t)node * EMB + sl * 16] = o0;
        *(s16x8*)&outm[(size_t)node * EMB + sl * 16 + 8] = o1;
    }
}

// -------- bf16 MFMA GEMM: BM=128 x BN=256, 512 thr / 8 waves, BK=64 -------------
// LDS-repacked epilogue: acc -> LDS (bf16) -> linear wide global stores.

#define BM 128
#define BN 256
#define BKG 64

__global__ __launch_bounds__(512) void gemm_kernel(
    const ushort* __restrict__ Am, const ushort* __restrict__ Ax,
    const ushort* __restrict__ Wl, const ushort* __restrict__ Wr,
    const float* __restrict__ bias, ushort* __restrict__ out,
    uchar* __restrict__ out8, int M, int do_relu) {
    __shared__ ushort smem[BM * BKG + BN * BKG];   // 48 KiB
    ushort* As = smem;                 // [BM*BKG]
    ushort* Bs = smem + BM * BKG;      // [BN*BKG]
    ushort* Cs = smem;                 // reused: [64*BN] = 32 KiB
    const int tid = threadIdx.x;
    const int lane = tid & 63;
    const int w = tid >> 6;           // 0..7
    const int m0 = blockIdx.x * BM;
    const int wr = w >> 2;            // 0..1
    const int wc = w & 3;             // 0..3

    f32x4 acc[4][4];
#pragma unroll
    for (int i = 0; i < 4; ++i)
#pragma unroll
        for (int j = 0; j < 4; ++j) acc[i][j] = (f32x4){0.f, 0.f, 0.f, 0.f};

    size_t srcA[2];
    int ldsoA[2];
#pragma unroll
    for (int j = 0; j < 2; ++j) {
        int c = j * 512 + tid;
        int r = c >> 3;
        int cc = (c & 7) ^ (r & 7);
        int arow = m0 + r; if (arow > M - 1) arow = M - 1;
        srcA[j] = (size_t)arow * EMB + cc * 8;
        ldsoA[j] = c * 8;
    }
    size_t srcB[4];
    int ldsoB[4];
#pragma unroll
    for (int j = 0; j < 4; ++j) {
        int c = j * 512 + tid;
        int r = c >> 3;
        int cc = (c & 7) ^ (r & 7);
        srcB[j] = (size_t)r * EMB + cc * 8;
        ldsoB[j] = c * 8;
    }

#pragma unroll
    for (int phase = 0; phase < 2; ++phase) {
        const ushort* A = phase ? Ax : Am;
        const ushort* W = phase ? Wr : Wl;
        for (int k0 = 0; k0 < EMB; k0 += BKG) {
#pragma unroll
            for (int j = 0; j < 2; ++j) GLOAD_LDS16(A + srcA[j] + k0, As + ldsoA[j]);
#pragma unroll
            for (int j = 0; j < 4; ++j) GLOAD_LDS16(W + srcB[j] + k0, Bs + ldsoB[j]);
            asm volatile("s_waitcnt vmcnt(0)" ::: "memory");
            __syncthreads();
#pragma unroll
            for (int ks = 0; ks < 2; ++ks) {
                const int ccr = ((ks * 4 + (lane >> 4)) ^ (lane & 7)) * 8;
                s16x8 af[4], bg[4];
#pragma unroll
                for (int mf = 0; mf < 4; ++mf) {
                    int r = wr * 64 + mf * 16 + (lane & 15);
                    af[mf] = *(const s16x8*)&As[r * BKG + ccr];
                }
#pragma unroll
                for (int nf = 0; nf < 4; ++nf) {
                    int r = wc * 64 + nf * 16 + (lane & 15);
                    bg[nf] = *(const s16x8*)&Bs[r * BKG + ccr];
                }
#pragma unroll
                for (int mf = 0; mf < 4; ++mf)
#pragma unroll
                    for (int nf = 0; nf < 4; ++nf)
                        acc[mf][nf] = __builtin_amdgcn_mfma_f32_16x16x32_bf16(
                            af[mf], bg[nf], acc[mf][nf], 0, 0, 0);
            }
            __syncthreads();
        }
    }

    // ---- epilogue: two row-half passes through LDS, then linear stores ----
#pragma unroll
    for (int p = 0; p < 2; ++p) {
        if (wr == p) {
#pragma unroll
            for (int nf = 0; nf < 4; ++nf) {
                int col = wc * 64 + nf * 16 + (lane & 15);
                float bv = bias[col];
#pragma unroll
                for (int mf = 0; mf < 4; ++mf) {
                    int rl = mf * 16 + ((lane >> 4) << 2);   // 0..63 local row
#pragma unroll
                    for (int q = 0; q < 4; ++q) {
                        float v = acc[mf][nf][q] + bv;
                        if (do_relu) v = fmaxf(v, 0.f);
                        Cs[(rl + q) * BN + col] = f2bf(v);
                    }
                }
            }
        }
        __syncthreads();
        // copy out 64 rows (= 2048 uint4); 512 threads x 4
#pragma unroll
        for (int i = 0; i < 4; ++i) {
            int idx = i * 512 + tid;          // uint4 index; 32 per row
            int row = m0 + p * 64 + (idx >> 5);
            if (row < M) {
                uint4 v = ((const uint4*)Cs)[idx];
                *(uint4*)&out[(size_t)row * EMB + (idx & 31) * 8] = v;
                if (out8) {
                    const ushort* pu = (const ushort*)&v;
                    unsigned lo = f32x2_to_fp8(bf2f(pu[0]), bf2f(pu[1])) |
                                  (f32x2_to_fp8(bf2f(pu[2]), bf2f(pu[3])) << 16);
                    unsigned hi = f32x2_to_fp8(bf2f(pu[4]), bf2f(pu[5])) |
                                  (f32x2_to_fp8(bf2f(pu[6]), bf2f(pu[7])) << 16);
                    *(uint2*)&out8[(size_t)row * EMB + (idx & 31) * 8] =
                        make_uint2(lo, hi);
                }
            }
        }
        __syncthreads();
    }
}

// ------- supervision scores: wave per edge, both rows in one 16B/lane load -----

__global__ void score_kernel(const ushort* __restrict__ x, const int* __restrict__ sup,
                             float* __restrict__ out) {
    int w = threadIdx.x >> 6;
    int lane = threadIdx.x & 63;
    int half = lane >> 5;
    int sl = lane & 31;
    int e = blockIdx.x * 4 + w;
    if (e >= N_SUP) return;
    int s = clampi(sup[e], 0, N_NODES - 1);
    int d = clampi(sup[N_SUP + e], 0, N_NODES - 1);
    int row = half ? d : s;
    uint4 raw = *(const uint4*)&x[(unsigned)row * EMB + sl * 8];
    uint4 pr;
    pr.x = __shfl_xor(raw.x, 32, 64);
    pr.y = __shfl_xor(raw.y, 32, 64);
    pr.z = __shfl_xor(raw.z, 32, 64);
    pr.w = __shfl_xor(raw.w, 32, 64);
    float t = 0.f;
    unsigned a[4] = {raw.x, raw.y, raw.z, raw.w};
    unsigned b[4] = {pr.x, pr.y, pr.z, pr.w};
#pragma unroll
    for (int i = 0; i < 4; ++i) {
        t += bf2f((ushort)(a[i] & 0xffff)) * bf2f((ushort)(b[i] & 0xffff));
        t += bf2f((ushort)(a[i] >> 16)) * bf2f((ushort)(b[i] >> 16));
    }
#pragma unroll
    for (int off = 16; off > 0; off >>= 1) t += __shfl_xor(t, off, 64);
    if (lane == 0) out[e] = t;
}

// ---------------- launch ----------------

extern "C" void kernel_launch(void* const* d_in, const int* in_sizes, int n_in,
                              void* d_out, int out_size, void* d_ws, size_t ws_size,
                              hipStream_t stream) {
    const float* x0  = (const float*)d_in[0];
    const int*   mp  = (const int*)d_in[1];
    const int*   sup = (const int*)d_in[2];
    W6 wsrc;
    wsrc.p[0] = (const float*)d_in[3];   // Wl1
    wsrc.p[1] = (const float*)d_in[5];   // Wr1
    wsrc.p[2] = (const float*)d_in[6];   // Wl2
    wsrc.p[3] = (const float*)d_in[8];   // Wr2
    wsrc.p[4] = (const float*)d_in[9];   // Wl3
    wsrc.p[5] = (const float*)d_in[11];  // Wr3
    const float* bl1 = (const float*)d_in[4];
    const float* bl2 = (const float*)d_in[7];
    const float* bl3 = (const float*)d_in[10];
    float* scores = (float*)d_out;

    const int* mp_src = mp;
    const int* mp_dst = mp + N_MP;

    char* base = (char*)d_ws;
    size_t off = 0;
    auto alloc = [&](size_t bytes) {
        void* p = base + off;
        off = (off + bytes + 255) & ~(size_t)255;
        return p;
    };
    int* rp     = (int*)alloc((N_NODES + 1) * sizeof(int));
    int* hist   = (int*)alloc(N_NODES * sizeof(int));
    int* gbfill = (int*)alloc(256 * sizeof(int));
    int* psum   = (int*)alloc(NB_SCAN * sizeof(int));
    int* srt    = (int*)alloc(N_MP * sizeof(int));
    unsigned* packed = (unsigned*)alloc(N_MP * sizeof(unsigned));
    ushort* x0b  = (ushort*)alloc((size_t)N_NODES * EMB * sizeof(ushort));
    ushort* bufA = (ushort*)alloc((size_t)N_NODES * EMB * sizeof(ushort));
    ushort* bufB = (ushort*)alloc((size_t)N_NODES * EMB * sizeof(ushort));
    ushort* bufC = (ushort*)alloc((size_t)N_NODES * EMB * sizeof(ushort));
    uchar*  x0f8 = (uchar*)alloc((size_t)N_NODES * EMB);
    uchar*  a8   = (uchar*)alloc((size_t)N_NODES * EMB);
    ushort* Wb   = (ushort*)alloc((size_t)6 * EMB * EMB * sizeof(ushort));
    (void)ws_size; (void)n_in; (void)in_sizes; (void)out_size;

    (void)hipMemsetAsync(hist, 0, N_NODES * sizeof(int), stream);

    f2b8_kernel<<<(N_NODES * EMB / 8 + 255) / 256, 256, 0, stream>>>(
        x0, x0b, x0f8, N_NODES * EMB / 8);
    wcvt_kernel<<<192, 256, 0, stream>>>(wsrc, Wb);

    hist_kernel<<<(N_MP + 255) / 256, 256, 0, stream>>>(mp_dst, N_MP, hist);
    scan_partial_kernel<<<NB_SCAN, 256, 0, stream>>>(hist, psum, N_NODES);
    scan_blocksums_kernel<<<1, 128, 0, stream>>>(psum, NB_SCAN);
    scan_final_kernel<<<NB_SCAN, 256, 0, stream>>>(hist, psum, rp, N_NODES);

    binit_kernel<<<1, 256, 0, stream>>>(rp, gbfill);
    bin_kernel<<<(N_MP + EPB_A - 1) / EPB_A, 1024, 0, stream>>>(
        mp_src, mp_dst, N_MP, gbfill, packed);
    debin_kernel<<<NBUCK, 1024, 0, stream>>>(packed, rp, srt);

    dim3 gemm_grid((N_NODES + BM - 1) / BM, 1);
    int agg_blocks = (N_NODES + 3) / 4;

    ushort* Wl1 = Wb + 0 * EMB * EMB; ushort* Wr1 = Wb + 1 * EMB * EMB;
    ushort* Wl2 = Wb + 2 * EMB * EMB; ushort* Wr2 = Wb + 3 * EMB * EMB;
    ushort* Wl3 = Wb + 4 * EMB * EMB; ushort* Wr3 = Wb + 5 * EMB * EMB;

    agg_kernel<<<agg_blocks, 256, 0, stream>>>(x0f8, rp, srt, bufC);
    gemm_kernel<<<gemm_grid, 512, 0, stream>>>(bufC, x0b, Wl1, Wr1, bl1, bufA, a8, N_NODES, 1);

    agg_kernel<<<agg_blocks, 256, 0, stream>>>(a8, rp, srt, bufC);
    gemm_kernel<<<gemm_grid, 512, 0, stream>>>(bufC, bufA, Wl2, Wr2, bl2, bufB, a8, N_NODES, 1);

    agg_kernel<<<agg_blocks, 256, 0, stream>>>(a8, rp, srt, bufC);
    gemm_kernel<<<gemm_grid, 512, 0, stream>>>(bufC, bufB, Wl3, Wr3, bl3, bufA,
                                               (uchar*)nullptr, N_NODES, 0);

    score_kernel<<<(N_SUP + 3) / 4, 256, 0, stream>>>(bufA, sup, scores);
}

// Round 14
// 523.850 us; speedup vs baseline: 1.4801x; 1.0767x over previous
//
#include <hip/hip_runtime.h>
#include <hip/hip_bf16.h>

#define N_NODES 100000
#define EMB 256
#define N_MP 1600000
#define N_SUP 200000

typedef __attribute__((ext_vector_type(4))) float f32x4;
typedef __attribute__((ext_vector_type(2))) float f32x2;
typedef __attribute__((ext_vector_type(8))) short s16x8;
typedef unsigned char uchar;

__device__ __forceinline__ int clampi(int v, int lo, int hi) {
    return v < lo ? lo : (v > hi ? hi : v);
}
__device__ __forceinline__ ushort f2bf(float f) {
    unsigned u = __float_as_uint(f);
    u += 0x7fffu + ((u >> 16) & 1u);   // round-to-nearest-even
    return (ushort)(u >> 16);
}
__device__ __forceinline__ float bf2f(ushort h) {
    return __uint_as_float(((unsigned)h) << 16);
}
// fp8 e4m3 HW converts; word-half selector must be an IMMEDIATE -> template
template <bool HI>
__device__ __forceinline__ f32x2 fp8_to_f32x2(unsigned w) {
    return __builtin_amdgcn_cvt_pk_f32_fp8(w, HI);
}
__device__ __forceinline__ unsigned f32x2_to_fp8(float a, float b) {
    return (unsigned)__builtin_amdgcn_cvt_pk_fp8_f32(a, b, 0, false) & 0xffffu;
}

#define GLOAD_LDS16(gsrc, ldst)                                                   \
    __builtin_amdgcn_global_load_lds(                                             \
        (const __attribute__((address_space(1))) void*)(gsrc),                    \
        (__attribute__((address_space(3))) void*)(ldst), 16, 0, 0)

// ------------- fp32 -> bf16 + fp8 convert (8 elems/thread) ----------------------

__global__ void f2b8_kernel(const float* __restrict__ in, ushort* __restrict__ outb,
                            uchar* __restrict__ out8, int n8) {
    int i = blockIdx.x * 256 + threadIdx.x;
    if (i >= n8) return;
    const float4* p = (const float4*)(in + (size_t)i * 8);
    float4 a = p[0], b = p[1];
    ushort4 lo = make_ushort4(f2bf(a.x), f2bf(a.y), f2bf(a.z), f2bf(a.w));
    ushort4 hi = make_ushort4(f2bf(b.x), f2bf(b.y), f2bf(b.z), f2bf(b.w));
    ushort4* q = (ushort4*)(outb + (size_t)i * 8);
    q[0] = lo; q[1] = hi;
    uint2 f8;
    f8.x = f32x2_to_fp8(a.x, a.y) | (f32x2_to_fp8(a.z, a.w) << 16);
    f8.y = f32x2_to_fp8(b.x, b.y) | (f32x2_to_fp8(b.z, b.w) << 16);
    *(uint2*)(out8 + (size_t)i * 8) = f8;
}

// one launch for all 6 weight matrices (bf16 only)
struct W6 { const float* p[6]; };
__global__ void wcvt_kernel(W6 ws, ushort* __restrict__ outbase) {
    int m = blockIdx.x >> 5;                      // 32 blocks per matrix
    int idx = (blockIdx.x & 31) * 256 + threadIdx.x;  // 0..8191
    const float4* p = (const float4*)(ws.p[m] + (size_t)idx * 8);
    float4 a = p[0], b = p[1];
    ushort4 lo = make_ushort4(f2bf(a.x), f2bf(a.y), f2bf(a.z), f2bf(a.w));
    ushort4 hi = make_ushort4(f2bf(b.x), f2bf(b.y), f2bf(b.z), f2bf(b.w));
    ushort4* q = (ushort4*)(outbase + (size_t)m * EMB * EMB + (size_t)idx * 8);
    q[0] = lo; q[1] = hi;
}

// ---------------- CSR build: hist + scan ----------------

__global__ void hist_kernel(const int* __restrict__ dst, int n, int* __restrict__ hist) {
    int i = blockIdx.x * 256 + threadIdx.x;
    if (i < n) atomicAdd(&hist[clampi(dst[i], 0, N_NODES - 1)], 1);
}

#define SCAN_CHUNK 1024
#define NB_SCAN ((N_NODES + SCAN_CHUNK - 1) / SCAN_CHUNK)   // 98

__global__ void scan_partial_kernel(const int* __restrict__ hist, int* __restrict__ psum, int n) {
    __shared__ int lds[4];
    int b = blockIdx.x;
    int tid = threadIdx.x, lane = tid & 63, wv = tid >> 6;
    int base = b * SCAN_CHUNK + tid * 4;
    int s = 0;
    if (base + 3 < n) {
        int4 v = *(const int4*)&hist[base];
        s = v.x + v.y + v.z + v.w;
    } else {
#pragma unroll
        for (int k = 0; k < 4; ++k) { int i = base + k; if (i < n) s += hist[i]; }
    }
#pragma unroll
    for (int off = 32; off; off >>= 1) s += __shfl_down(s, off, 64);
    if (lane == 0) lds[wv] = s;
    __syncthreads();
    if (tid == 0) psum[b] = lds[0] + lds[1] + lds[2] + lds[3];
}

__global__ void scan_blocksums_kernel(int* __restrict__ psum, int nb) {
    __shared__ int lds[128];
    int t = threadIdx.x;
    lds[t] = (t < nb) ? psum[t] : 0;
    __syncthreads();
    if (t == 0) {
        int run = 0;
        for (int i = 0; i < nb; ++i) { int v = lds[i]; lds[i] = run; run += v; }
    }
    __syncthreads();
    if (t < nb) psum[t] = lds[t];
}

__global__ void scan_final_kernel(const int* __restrict__ hist, const int* __restrict__ poff,
                                  int* __restrict__ rp, int n) {
    __shared__ int wsum[4];
    int b = blockIdx.x;
    int tid = threadIdx.x, lane = tid & 63, wv = tid >> 6;
    int base = b * SCAN_CHUNK + tid * 4;
    int v0 = 0, v1 = 0, v2 = 0, v3 = 0;
    if (base + 3 < n) {
        int4 v = *(const int4*)&hist[base];
        v0 = v.x; v1 = v.y; v2 = v.z; v3 = v.w;
    } else {
        if (base + 0 < n) v0 = hist[base + 0];
        if (base + 1 < n) v1 = hist[base + 1];
        if (base + 2 < n) v2 = hist[base + 2];
        if (base + 3 < n) v3 = hist[base + 3];
    }
    int s1 = v0 + v1, s2 = s1 + v2, s3 = s2 + v3;
    int t = s3;
#pragma unroll
    for (int off = 1; off < 64; off <<= 1) {
        int u = __shfl_up(t, off, 64);
        if (lane >= off) t += u;
    }
    if (lane == 63) wsum[wv] = t;
    __syncthreads();
    int woff = 0;
    for (int i = 0; i < wv; ++i) woff += wsum[i];
    int off0 = poff[b] + woff + (t - s3);
    if (base + 0 < n) rp[base + 1] = off0 + v0;
    if (base + 1 < n) rp[base + 2] = off0 + s1;
    if (base + 2 < n) rp[base + 3] = off0 + s2;
    if (base + 3 < n) rp[base + 4] = off0 + s3;
    if (b == 0 && tid == 0) rp[0] = 0;
}

// ---------------- two-pass binned scatter ----------

#define BSH 9
#define NBUCK ((N_NODES + 511) / 512)   // 196
#define EPB_A 4096                       // edges per bin block (1024 thr x 4)

__global__ void binit_kernel(const int* __restrict__ rp, int* __restrict__ gbfill) {
    int t = threadIdx.x;
    if (t < NBUCK) gbfill[t] = rp[t << BSH];
    else if (t < 256) gbfill[t] = 0;
}

__global__ __launch_bounds__(1024) void bin_kernel(
    const int* __restrict__ src, const int* __restrict__ dst, int n,
    int* __restrict__ gbfill, unsigned* __restrict__ packed) {
    __shared__ int cnt[256];
    __shared__ int base[256];
    int tid = threadIdx.x;
    if (tid < 256) cnt[tid] = 0;
    __syncthreads();
    int e0 = blockIdx.x * EPB_A + tid;
    int bk[4], rank[4], sv[4];
    bool valid[4];
#pragma unroll
    for (int k = 0; k < 4; ++k) {
        int e = e0 + k * 1024;
        valid[k] = e < n;
        if (valid[k]) {
            int d = clampi(dst[e], 0, N_NODES - 1);
            sv[k] = clampi(src[e], 0, N_NODES - 1);
            bk[k] = d >> BSH;
            int dl = d & 511;
            sv[k] |= (dl << 20);
            rank[k] = atomicAdd(&cnt[bk[k]], 1);
        }
    }
    __syncthreads();
    if (tid < 256) {
        int c = cnt[tid];
        base[tid] = c > 0 ? atomicAdd(&gbfill[tid], c) : 0;
    }
    __syncthreads();
#pragma unroll
    for (int k = 0; k < 4; ++k) {
        if (valid[k]) packed[base[bk[k]] + rank[k]] = (unsigned)sv[k];
    }
}

__global__ __launch_bounds__(1024) void debin_kernel(
    const unsigned* __restrict__ packed, const int* __restrict__ rp,
    int* __restrict__ srt) {
    __shared__ int fill[512];
    __shared__ int rpl[512];
    int b = blockIdx.x;
    int tid = threadIdx.x;
    int node0 = b << BSH;
    int nn = N_NODES - node0; if (nn > 512) nn = 512;
    if (tid < 512) {
        fill[tid] = 0;
        rpl[tid] = (tid < nn) ? rp[node0 + tid] : 0;
    }
    __syncthreads();
    int bstart = rp[node0];
    int bend = rp[node0 + nn];
    for (int e = bstart + tid; e < bend; e += 1024) {
        unsigned p = packed[e];
        int dl = p >> 20;
        int rank = atomicAdd(&fill[dl], 1);
        srt[rpl[dl] + rank] = (int)(p & 0xFFFFFu);
    }
}

// ------- mean aggregation v5: quarter-wave rows, 16B/lane, 4 edges/load-instr ---

__global__ void agg_kernel(const uchar* __restrict__ x8, const int* __restrict__ rp,
                           const int* __restrict__ srt, ushort* __restrict__ outm) {
    int w = threadIdx.x >> 6;
    int lane = threadIdx.x & 63;
    int qw = lane >> 4;
    int sl = lane & 15;
    int node = blockIdx.x * 4 + w;
    if (node >= N_NODES) return;
    int beg = rp[node], end = rp[node + 1];
    int deg = end - beg;
    float acc[16];
#pragma unroll
    for (int i = 0; i < 16; ++i) acc[i] = 0.f;

    for (int bse = 0; bse < deg; bse += 64) {
        int rem = deg - bse;
        int cnt = rem < 64 ? rem : 64;
        int myidx = (lane < cnt) ? srt[beg + bse + lane] : 0;
        for (int j = 0; j < cnt; j += 4) {
            int e = j + qw;
            int s = __shfl(myidx, e < cnt ? e : 0, 64);
            if (e < cnt) {
                uint4 v = *(const uint4*)&x8[(unsigned)s * EMB + sl * 16];
                f32x2 p;
                p = fp8_to_f32x2<false>(v.x); acc[0] += p.x; acc[1] += p.y;
                p = fp8_to_f32x2<true >(v.x); acc[2] += p.x; acc[3] += p.y;
                p = fp8_to_f32x2<false>(v.y); acc[4] += p.x; acc[5] += p.y;
                p = fp8_to_f32x2<true >(v.y); acc[6] += p.x; acc[7] += p.y;
                p = fp8_to_f32x2<false>(v.z); acc[8] += p.x; acc[9] += p.y;
                p = fp8_to_f32x2<true >(v.z); acc[10] += p.x; acc[11] += p.y;
                p = fp8_to_f32x2<false>(v.w); acc[12] += p.x; acc[13] += p.y;
                p = fp8_to_f32x2<true >(v.w); acc[14] += p.x; acc[15] += p.y;
            }
        }
    }
#pragma unroll
    for (int i = 0; i < 16; ++i) acc[i] += __shfl_xor(acc[i], 32, 64);
#pragma unroll
    for (int i = 0; i < 16; ++i) acc[i] += __shfl_xor(acc[i], 16, 64);
    float inv = 1.0f / fmaxf((float)deg, 1.0f);
    if (qw == 0) {
        s16x8 o0, o1;
#pragma unroll
        for (int i = 0; i < 8; ++i) o0[i] = (short)f2bf(acc[i] * inv);
#pragma unroll
        for (int i = 0; i < 8; ++i) o1[i] = (short)f2bf(acc[8 + i] * inv);
        *(s16x8*)&outm[(size_t)node * EMB + sl * 16] = o0;
        *(s16x8*)&outm[(size_t)node * EMB + sl * 16 + 8] = o1;
    }
}

// -------- bf16 MFMA GEMM v3: BM=128 x BN=256, BK=32, DOUBLE-BUFFERED pipeline ---
// T3 minimum-2-phase skeleton: issue next step's stage BEFORE compute; one
// __syncthreads per K-step (its implicit vmcnt(0) is the pipeline wait, placed
// after compute so loads overlap MFMAs). LDS: 2 x (A 8K + B 16K) = 48K;
// C-slab (32K) reuses the same smem. 3 blocks/CU.
// Swizzle (4 chunks/row): LDS[r][c] = G[r][c ^ (r&3)], read chunk = (lane>>4)^(r&3).

#define BM 128
#define BN 256
#define BKG 32
#define NSTEPS 16                          // 2 phases x (EMB/BKG)
#define ABSZ (BM * BKG)                    // 4096 ushorts
#define BUFSZ (BM * BKG + BN * BKG)        // 12288 ushorts

__global__ __launch_bounds__(512) void gemm_kernel(
    const ushort* __restrict__ Am, const ushort* __restrict__ Ax,
    const ushort* __restrict__ Wl, const ushort* __restrict__ Wr,
    const float* __restrict__ bias, ushort* __restrict__ out,
    uchar* __restrict__ out8, int M, int do_relu) {
    __shared__ ushort smem[2 * BUFSZ];   // 48 KiB
    const int tid = threadIdx.x;
    const int lane = tid & 63;
    const int w = tid >> 6;           // 0..7
    const int m0 = blockIdx.x * BM;
    const int wr = w >> 2;            // 0..1
    const int wc = w & 3;             // 0..3

    f32x4 acc[4][4];
#pragma unroll
    for (int i = 0; i < 4; ++i)
#pragma unroll
        for (int j = 0; j < 4; ++j) acc[i][j] = (f32x4){0.f, 0.f, 0.f, 0.f};

    // per-thread staging: 1 A chunk + 2 B chunks (16B each) per K-step
    int ca = tid;                           // 0..511
    int ra = ca >> 2;
    int cca = (ca & 3) ^ (ra & 3);
    int arow = m0 + ra; if (arow > M - 1) arow = M - 1;
    size_t srcA = (size_t)arow * EMB + cca * 8;
    int ldsoA = ca * 8;
    int cb0 = tid, cb1 = tid + 512;
    int rb0 = cb0 >> 2, rb1 = cb1 >> 2;
    size_t srcB0 = (size_t)rb0 * EMB + ((cb0 & 3) ^ (rb0 & 3)) * 8;
    size_t srcB1 = (size_t)rb1 * EMB + ((cb1 & 3) ^ (rb1 & 3)) * 8;
    int ldsoB0 = cb0 * 8, ldsoB1 = cb1 * 8;

    // fragment read addressing (constant across steps)
    int raf[4], rbf[4];
#pragma unroll
    for (int mf = 0; mf < 4; ++mf) {
        int r = wr * 64 + mf * 16 + (lane & 15);
        raf[mf] = r * BKG + (((lane >> 4) ^ (r & 3)) * 8);
    }
#pragma unroll
    for (int nf = 0; nf < 4; ++nf) {
        int r = wc * 64 + nf * 16 + (lane & 15);
        rbf[nf] = r * BKG + (((lane >> 4) ^ (r & 3)) * 8);
    }

    // prologue: stage step 0 into buffer 0
    GLOAD_LDS16(Am + srcA, smem + ldsoA);
    GLOAD_LDS16(Wl + srcB0, smem + ABSZ + ldsoB0);
    GLOAD_LDS16(Wl + srcB1, smem + ABSZ + ldsoB1);
    __syncthreads();

    int cur = 0;
    for (int s = 0; s < NSTEPS; ++s) {
        int nxt = s + 1;
        if (nxt < NSTEPS) {
            const ushort* A = (nxt >= 8) ? Ax : Am;
            const ushort* W = (nxt >= 8) ? Wr : Wl;
            int k0 = (nxt & 7) * BKG;
            ushort* d = smem + (cur ^ 1) * BUFSZ;
            GLOAD_LDS16(A + srcA + k0, d + ldsoA);
            GLOAD_LDS16(W + srcB0 + k0, d + ABSZ + ldsoB0);
            GLOAD_LDS16(W + srcB1 + k0, d + ABSZ + ldsoB1);
        }
        const ushort* As = smem + cur * BUFSZ;
        const ushort* Bs = As + ABSZ;
        s16x8 af[4], bg[4];
#pragma unroll
        for (int mf = 0; mf < 4; ++mf) af[mf] = *(const s16x8*)&As[raf[mf]];
#pragma unroll
        for (int nf = 0; nf < 4; ++nf) bg[nf] = *(const s16x8*)&Bs[rbf[nf]];
#pragma unroll
        for (int mf = 0; mf < 4; ++mf)
#pragma unroll
            for (int nf = 0; nf < 4; ++nf)
                acc[mf][nf] = __builtin_amdgcn_mfma_f32_16x16x32_bf16(
                    af[mf], bg[nf], acc[mf][nf], 0, 0, 0);
        __syncthreads();   // implicit vmcnt(0): next buffer ready; cur free
        cur ^= 1;
    }

    // ---- epilogue: two row-half passes through LDS, then linear stores ----
    ushort* Cs = smem;   // 32K of the 48K
#pragma unroll
    for (int p = 0; p < 2; ++p) {
        if (wr == p) {
#pragma unroll
            for (int nf = 0; nf < 4; ++nf) {
                int col = wc * 64 + nf * 16 + (lane & 15);
                float bv = bias[col];
#pragma unroll
                for (int mf = 0; mf < 4; ++mf) {
                    int rl = mf * 16 + ((lane >> 4) << 2);   // 0..63 local row
#pragma unroll
                    for (int q = 0; q < 4; ++q) {
                        float v = acc[mf][nf][q] + bv;
                        if (do_relu) v = fmaxf(v, 0.f);
                        Cs[(rl + q) * BN + col] = f2bf(v);
                    }
                }
            }
        }
        __syncthreads();
        // copy out 64 rows (= 2048 uint4); 512 threads x 4
#pragma unroll
        for (int i = 0; i < 4; ++i) {
            int idx = i * 512 + tid;          // uint4 index; 32 per row
            int row = m0 + p * 64 + (idx >> 5);
            if (row < M) {
                uint4 v = ((const uint4*)Cs)[idx];
                *(uint4*)&out[(size_t)row * EMB + (idx & 31) * 8] = v;
                if (out8) {
                    const ushort* pu = (const ushort*)&v;
                    unsigned lo = f32x2_to_fp8(bf2f(pu[0]), bf2f(pu[1])) |
                                  (f32x2_to_fp8(bf2f(pu[2]), bf2f(pu[3])) << 16);
                    unsigned hi = f32x2_to_fp8(bf2f(pu[4]), bf2f(pu[5])) |
                                  (f32x2_to_fp8(bf2f(pu[6]), bf2f(pu[7])) << 16);
                    *(uint2*)&out8[(size_t)row * EMB + (idx & 31) * 8] =
                        make_uint2(lo, hi);
                }
            }
        }
        __syncthreads();
    }
}

// ------- supervision scores: wave per edge, both rows in one 16B/lane load -----

__global__ void score_kernel(const ushort* __restrict__ x, const int* __restrict__ sup,
                             float* __restrict__ out) {
    int w = threadIdx.x >> 6;
    int lane = threadIdx.x & 63;
    int half = lane >> 5;
    int sl = lane & 31;
    int e = blockIdx.x * 4 + w;
    if (e >= N_SUP) return;
    int s = clampi(sup[e], 0, N_NODES - 1);
    int d = clampi(sup[N_SUP + e], 0, N_NODES - 1);
    int row = half ? d : s;
    uint4 raw = *(const uint4*)&x[(unsigned)row * EMB + sl * 8];
    uint4 pr;
    pr.x = __shfl_xor(raw.x, 32, 64);
    pr.y = __shfl_xor(raw.y, 32, 64);
    pr.z = __shfl_xor(raw.z, 32, 64);
    pr.w = __shfl_xor(raw.w, 32, 64);
    float t = 0.f;
    unsigned a[4] = {raw.x, raw.y, raw.z, raw.w};
    unsigned b[4] = {pr.x, pr.y, pr.z, pr.w};
#pragma unroll
    for (int i = 0; i < 4; ++i) {
        t += bf2f((ushort)(a[i] & 0xffff)) * bf2f((ushort)(b[i] & 0xffff));
        t += bf2f((ushort)(a[i] >> 16)) * bf2f((ushort)(b[i] >> 16));
    }
#pragma unroll
    for (int off = 16; off > 0; off >>= 1) t += __shfl_xor(t, off, 64);
    if (lane == 0) out[e] = t;
}

// ---------------- launch ----------------

extern "C" void kernel_launch(void* const* d_in, const int* in_sizes, int n_in,
                              void* d_out, int out_size, void* d_ws, size_t ws_size,
                              hipStream_t stream) {
    const float* x0  = (const float*)d_in[0];
    const int*   mp  = (const int*)d_in[1];
    const int*   sup = (const int*)d_in[2];
    W6 wsrc;
    wsrc.p[0] = (const float*)d_in[3];   // Wl1
    wsrc.p[1] = (const float*)d_in[5];   // Wr1
    wsrc.p[2] = (const float*)d_in[6];   // Wl2
    wsrc.p[3] = (const float*)d_in[8];   // Wr2
    wsrc.p[4] = (const float*)d_in[9];   // Wl3
    wsrc.p[5] = (const float*)d_in[11];  // Wr3
    const float* bl1 = (const float*)d_in[4];
    const float* bl2 = (const float*)d_in[7];
    const float* bl3 = (const float*)d_in[10];
    float* scores = (float*)d_out;

    const int* mp_src = mp;
    const int* mp_dst = mp + N_MP;

    char* base = (char*)d_ws;
    size_t off = 0;
    auto alloc = [&](size_t bytes) {
        void* p = base + off;
        off = (off + bytes + 255) & ~(size_t)255;
        return p;
    };
    int* rp     = (int*)alloc((N_NODES + 1) * sizeof(int));
    int* hist   = (int*)alloc(N_NODES * sizeof(int));
    int* gbfill = (int*)alloc(256 * sizeof(int));
    int* psum   = (int*)alloc(NB_SCAN * sizeof(int));
    int* srt    = (int*)alloc(N_MP * sizeof(int));
    unsigned* packed = (unsigned*)alloc(N_MP * sizeof(unsigned));
    ushort* x0b  = (ushort*)alloc((size_t)N_NODES * EMB * sizeof(ushort));
    ushort* bufA = (ushort*)alloc((size_t)N_NODES * EMB * sizeof(ushort));
    ushort* bufB = (ushort*)alloc((size_t)N_NODES * EMB * sizeof(ushort));
    ushort* bufC = (ushort*)alloc((size_t)N_NODES * EMB * sizeof(ushort));
    uchar*  x0f8 = (uchar*)alloc((size_t)N_NODES * EMB);
    uchar*  a8   = (uchar*)alloc((size_t)N_NODES * EMB);
    ushort* Wb   = (ushort*)alloc((size_t)6 * EMB * EMB * sizeof(ushort));
    (void)ws_size; (void)n_in; (void)in_sizes; (void)out_size;

    (void)hipMemsetAsync(hist, 0, N_NODES * sizeof(int), stream);

    f2b8_kernel<<<(N_NODES * EMB / 8 + 255) / 256, 256, 0, stream>>>(
        x0, x0b, x0f8, N_NODES * EMB / 8);
    wcvt_kernel<<<192, 256, 0, stream>>>(wsrc, Wb);

    hist_kernel<<<(N_MP + 255) / 256, 256, 0, stream>>>(mp_dst, N_MP, hist);
    scan_partial_kernel<<<NB_SCAN, 256, 0, stream>>>(hist, psum, N_NODES);
    scan_blocksums_kernel<<<1, 128, 0, stream>>>(psum, NB_SCAN);
    scan_final_kernel<<<NB_SCAN, 256, 0, stream>>>(hist, psum, rp, N_NODES);

    binit_kernel<<<1, 256, 0, stream>>>(rp, gbfill);
    bin_kernel<<<(N_MP + EPB_A - 1) / EPB_A, 1024, 0, stream>>>(
        mp_src, mp_dst, N_MP, gbfill, packed);
    debin_kernel<<<NBUCK, 1024, 0, stream>>>(packed, rp, srt);

    dim3 gemm_grid((N_NODES + BM - 1) / BM, 1);
    int agg_blocks = (N_NODES + 3) / 4;

    ushort* Wl1 = Wb + 0 * EMB * EMB; ushort* Wr1 = Wb + 1 * EMB * EMB;
    ushort* Wl2 = Wb + 2 * EMB * EMB; ushort* Wr2 = Wb + 3 * EMB * EMB;
    ushort* Wl3 = Wb + 4 * EMB * EMB; ushort* Wr3 = Wb + 5 * EMB * EMB;

    agg_kernel<<<agg_blocks, 256, 0, stream>>>(x0f8, rp, srt, bufC);
    gemm_kernel<<<gemm_grid, 512, 0, stream>>>(bufC, x0b, Wl1, Wr1, bl1, bufA, a8, N_NODES, 1);

    agg_kernel<<<agg_blocks, 256, 0, stream>>>(a8, rp, srt, bufC);
    gemm_kernel<<<gemm_grid, 512, 0, stream>>>(bufC, bufA, Wl2, Wr2, bl2, bufB, a8, N_NODES, 1);

    agg_kernel<<<agg_blocks, 256, 0, stream>>>(a8, rp, srt, bufC);
    gemm_kernel<<<gemm_grid, 512, 0, stream>>>(bufC, bufB, Wl3, Wr3, bl3, bufA,
                                               (uchar*)nullptr, N_NODES, 0);

    score_kernel<<<(N_SUP + 3) / 4, 256, 0, stream>>>(bufA, sup, scores);
}

// Round 16
// 434.651 us; speedup vs baseline: 1.7838x; 1.2052x over previous
//
#include <hip/hip_runtime.h>
#include <hip/hip_bf16.h>

#define N_NODES 100000
#define EMB 256
#define N_MP 1600000
#define N_SUP 200000

typedef __attribute__((ext_vector_type(4))) float f32x4;
typedef __attribute__((ext_vector_type(2))) float f32x2;
typedef __attribute__((ext_vector_type(8))) short s16x8;
typedef unsigned char uchar;

__device__ __forceinline__ int clampi(int v, int lo, int hi) {
    return v < lo ? lo : (v > hi ? hi : v);
}
__device__ __forceinline__ ushort f2bf(float f) {
    unsigned u = __float_as_uint(f);
    u += 0x7fffu + ((u >> 16) & 1u);   // round-to-nearest-even
    return (ushort)(u >> 16);
}
__device__ __forceinline__ float bf2f(ushort h) {
    return __uint_as_float(((unsigned)h) << 16);
}
// fp8 e4m3 HW converts; word-half selector must be an IMMEDIATE -> template
template <bool HI>
__device__ __forceinline__ f32x2 fp8_to_f32x2(unsigned w) {
    return __builtin_amdgcn_cvt_pk_f32_fp8(w, HI);
}
__device__ __forceinline__ unsigned f32x2_to_fp8(float a, float b) {
    return (unsigned)__builtin_amdgcn_cvt_pk_fp8_f32(a, b, 0, false) & 0xffffu;
}

#define GLOAD_LDS16(gsrc, ldst)                                                   \
    __builtin_amdgcn_global_load_lds(                                             \
        (const __attribute__((address_space(1))) void*)(gsrc),                    \
        (__attribute__((address_space(3))) void*)(ldst), 16, 0, 0)

// ------------- fp32 -> bf16 + fp8 convert (8 elems/thread) ----------------------

__global__ void f2b8_kernel(const float* __restrict__ in, ushort* __restrict__ outb,
                            uchar* __restrict__ out8, int n8) {
    int i = blockIdx.x * 256 + threadIdx.x;
    if (i >= n8) return;
    const float4* p = (const float4*)(in + (size_t)i * 8);
    float4 a = p[0], b = p[1];
    ushort4 lo = make_ushort4(f2bf(a.x), f2bf(a.y), f2bf(a.z), f2bf(a.w));
    ushort4 hi = make_ushort4(f2bf(b.x), f2bf(b.y), f2bf(b.z), f2bf(b.w));
    ushort4* q = (ushort4*)(outb + (size_t)i * 8);
    q[0] = lo; q[1] = hi;
    uint2 f8;
    f8.x = f32x2_to_fp8(a.x, a.y) | (f32x2_to_fp8(a.z, a.w) << 16);
    f8.y = f32x2_to_fp8(b.x, b.y) | (f32x2_to_fp8(b.z, b.w) << 16);
    *(uint2*)(out8 + (size_t)i * 8) = f8;
}

// one launch for all 6 weight matrices (bf16 only)
struct W6 { const float* p[6]; };
__global__ void wcvt_kernel(W6 ws, ushort* __restrict__ outbase) {
    int m = blockIdx.x >> 5;                      // 32 blocks per matrix
    int idx = (blockIdx.x & 31) * 256 + threadIdx.x;  // 0..8191
    const float4* p = (const float4*)(ws.p[m] + (size_t)idx * 8);
    float4 a = p[0], b = p[1];
    ushort4 lo = make_ushort4(f2bf(a.x), f2bf(a.y), f2bf(a.z), f2bf(a.w));
    ushort4 hi = make_ushort4(f2bf(b.x), f2bf(b.y), f2bf(b.z), f2bf(b.w));
    ushort4* q = (ushort4*)(outbase + (size_t)m * EMB * EMB + (size_t)idx * 8);
    q[0] = lo; q[1] = hi;
}

// ---------------- merged CSR build: bin -> bucket scan -> debin(+rp) ------------
// bucket b = dst >> 9 (512 nodes); packed region per bucket = [b*SCAP, (b+1)*SCAP)

#define BSH 9
#define NBUCK ((N_NODES + 511) / 512)   // 196
#define EPB_A 4096                       // edges per bin block (1024 thr x 4)
#define SCAP 16384                       // per-bucket packed capacity (mean 8192)

__global__ void binit_kernel(int* __restrict__ gbfill) {
    int t = threadIdx.x;
    if (t < NBUCK) gbfill[t] = t * SCAP;
}

__global__ __launch_bounds__(1024) void bin_kernel(
    const int* __restrict__ src, const int* __restrict__ dst, int n,
    int* __restrict__ gbfill, unsigned* __restrict__ packed) {
    __shared__ int cnt[256];
    __shared__ int base[256];
    int tid = threadIdx.x;
    if (tid < 256) cnt[tid] = 0;
    __syncthreads();
    int e0 = blockIdx.x * EPB_A + tid;
    int bk[4], rank[4], sv[4];
    bool valid[4];
#pragma unroll
    for (int k = 0; k < 4; ++k) {
        int e = e0 + k * 1024;
        valid[k] = e < n;
        if (valid[k]) {
            int d = clampi(dst[e], 0, N_NODES - 1);
            sv[k] = clampi(src[e], 0, N_NODES - 1);
            bk[k] = d >> BSH;
            int dl = d & 511;
            sv[k] |= (dl << 20);
            rank[k] = atomicAdd(&cnt[bk[k]], 1);
        }
    }
    __syncthreads();
    if (tid < 256) {
        int c = cnt[tid];
        base[tid] = c > 0 ? atomicAdd(&gbfill[tid], c) : 0;
    }
    __syncthreads();
#pragma unroll
    for (int k = 0; k < 4; ++k) {
        if (valid[k]) {
            int pos = base[bk[k]] + rank[k];
            if (pos < (bk[k] + 1) * SCAP) packed[pos] = (unsigned)sv[k];
        }
    }
}

// exclusive scan over 196 bucket counts -> bbase; rp[N_NODES] = total
__global__ void bscan_kernel(const int* __restrict__ gbfill, int* __restrict__ bbase,
                             int* __restrict__ rp) {
    __shared__ int c[256];
    int t = threadIdx.x;
    c[t] = (t < NBUCK) ? (gbfill[t] - t * SCAP) : 0;
    __syncthreads();
    if (t == 0) {
        int run = 0;
        for (int i = 0; i < NBUCK; ++i) { int v = c[i]; c[i] = run; run += v; }
        rp[N_NODES] = run;
    }
    __syncthreads();
    if (t < NBUCK) bbase[t] = c[t];
}

// per bucket: LDS histogram over 512 nodes, wave-scan -> local offsets,
// write rp slice + scatter srt within the bucket's CSR window.
__global__ __launch_bounds__(1024) void debin_kernel(
    const unsigned* __restrict__ packed, const int* __restrict__ gbfill,
    const int* __restrict__ bbase, int* __restrict__ srt, int* __restrict__ rp) {
    __shared__ int cnt[512];
    __shared__ int loc[512];
    __shared__ int wsum[8];
    int b = blockIdx.x;
    int tid = threadIdx.x;
    int lane = tid & 63, wv = tid >> 6;
    int node0 = b << BSH;
    int nn = N_NODES - node0; if (nn > 512) nn = 512;
    if (tid < 512) cnt[tid] = 0;
    __syncthreads();
    int pbase = b * SCAP;
    int bcnt = gbfill[b] - pbase;
    if (bcnt > SCAP) bcnt = SCAP;
    for (int e = tid; e < bcnt; e += 1024)
        atomicAdd(&cnt[packed[pbase + e] >> 20], 1);
    __syncthreads();
    int v = (tid < 512) ? cnt[tid] : 0;
    int t = v;
#pragma unroll
    for (int off = 1; off < 64; off <<= 1) {
        int u = __shfl_up(t, off, 64);
        if (lane >= off) t += u;
    }
    if (tid < 512 && lane == 63) wsum[wv] = t;
    __syncthreads();
    if (tid < 512) {
        int woff = 0;
        for (int i = 0; i < wv; ++i) woff += wsum[i];
        loc[tid] = woff + t - v;          // exclusive local offset
        if (tid < nn) rp[node0 + tid] = bbase[b] + loc[tid];
    }
    __syncthreads();
    if (tid < 512) cnt[tid] = 0;
    __syncthreads();
    int sb = bbase[b];
    for (int e = tid; e < bcnt; e += 1024) {
        unsigned p = packed[pbase + e];
        int dl = p >> 20;
        int rank = atomicAdd(&cnt[dl], 1);
        srt[sb + loc[dl] + rank] = (int)(p & 0xFFFFFu);
    }
}

// ------- mean aggregation v5: quarter-wave rows, 16B/lane, 4 edges/load-instr ---

__global__ void agg_kernel(const uchar* __restrict__ x8, const int* __restrict__ rp,
                           const int* __restrict__ srt, ushort* __restrict__ outm) {
    int w = threadIdx.x >> 6;
    int lane = threadIdx.x & 63;
    int qw = lane >> 4;
    int sl = lane & 15;
    int node = blockIdx.x * 4 + w;
    if (node >= N_NODES) return;
    int beg = rp[node], end = rp[node + 1];
    int deg = end - beg;
    float acc[16];
#pragma unroll
    for (int i = 0; i < 16; ++i) acc[i] = 0.f;

    for (int bse = 0; bse < deg; bse += 64) {
        int rem = deg - bse;
        int cnt = rem < 64 ? rem : 64;
        int myidx = (lane < cnt) ? srt[beg + bse + lane] : 0;
        for (int j = 0; j < cnt; j += 4) {
            int e = j + qw;
            int s = __shfl(myidx, e < cnt ? e : 0, 64);
            if (e < cnt) {
                uint4 v = *(const uint4*)&x8[(unsigned)s * EMB + sl * 16];
                f32x2 p;
                p = fp8_to_f32x2<false>(v.x); acc[0] += p.x; acc[1] += p.y;
                p = fp8_to_f32x2<true >(v.x); acc[2] += p.x; acc[3] += p.y;
                p = fp8_to_f32x2<false>(v.y); acc[4] += p.x; acc[5] += p.y;
                p = fp8_to_f32x2<true >(v.y); acc[6] += p.x; acc[7] += p.y;
                p = fp8_to_f32x2<false>(v.z); acc[8] += p.x; acc[9] += p.y;
                p = fp8_to_f32x2<true >(v.z); acc[10] += p.x; acc[11] += p.y;
                p = fp8_to_f32x2<false>(v.w); acc[12] += p.x; acc[13] += p.y;
                p = fp8_to_f32x2<true >(v.w); acc[14] += p.x; acc[15] += p.y;
            }
        }
    }
#pragma unroll
    for (int i = 0; i < 16; ++i) acc[i] += __shfl_xor(acc[i], 32, 64);
#pragma unroll
    for (int i = 0; i < 16; ++i) acc[i] += __shfl_xor(acc[i], 16, 64);
    float inv = 1.0f / fmaxf((float)deg, 1.0f);
    if (qw == 0) {
        s16x8 o0, o1;
#pragma unroll
        for (int i = 0; i < 8; ++i) o0[i] = (short)f2bf(acc[i] * inv);
#pragma unroll
        for (int i = 0; i < 8; ++i) o1[i] = (short)f2bf(acc[8 + i] * inv);
        *(s16x8*)&outm[(size_t)node * EMB + sl * 16] = o0;
        *(s16x8*)&outm[(size_t)node * EMB + sl * 16 + 8] = o1;
    }
}

// -------- bf16 MFMA GEMM v4: BM=128 x BN=256, BK=32, 3-buffer counted vmcnt -----
// T3+T4: loads for steps s+1, s+2 stay in flight; per step wait vmcnt(3) (never
// 0 until the last step), raw s_barrier, sched_barrier(0) pin, then issue s+2's
// stage and compute step s. LDS 3 x 24 KiB = 72 KiB -> 2 blocks/CU.

#define BM 128
#define BN 256
#define BKG 32
#define NSTEPS 16                          // 2 phases x (EMB/BKG)
#define ABSZ (BM * BKG)                    // 4096 ushorts
#define BUFSZ (BM * BKG + BN * BKG)        // 12288 ushorts (24 KiB)

__global__ __launch_bounds__(512) void gemm_kernel(
    const ushort* __restrict__ Am, const ushort* __restrict__ Ax,
    const ushort* __restrict__ Wl, const ushort* __restrict__ Wr,
    const float* __restrict__ bias, ushort* __restrict__ out,
    uchar* __restrict__ out8, int M, int do_relu) {
    __shared__ ushort smem[3 * BUFSZ];   // 72 KiB
    const int tid = threadIdx.x;
    const int lane = tid & 63;
    const int w = tid >> 6;           // 0..7
    const int m0 = blockIdx.x * BM;
    const int wr = w >> 2;            // 0..1
    const int wc = w & 3;             // 0..3

    f32x4 acc[4][4];
#pragma unroll
    for (int i = 0; i < 4; ++i)
#pragma unroll
        for (int j = 0; j < 4; ++j) acc[i][j] = (f32x4){0.f, 0.f, 0.f, 0.f};

    // per-thread staging: 1 A chunk + 2 B chunks (16B each) per K-step
    int ca = tid;
    int ra = ca >> 2;
    int cca = (ca & 3) ^ (ra & 3);
    int arow = m0 + ra; if (arow > M - 1) arow = M - 1;
    size_t srcA = (size_t)arow * EMB + cca * 8;
    int ldsoA = ca * 8;
    int cb0 = tid, cb1 = tid + 512;
    int rb0 = cb0 >> 2, rb1 = cb1 >> 2;
    size_t srcB0 = (size_t)rb0 * EMB + ((cb0 & 3) ^ (rb0 & 3)) * 8;
    size_t srcB1 = (size_t)rb1 * EMB + ((cb1 & 3) ^ (rb1 & 3)) * 8;
    int ldsoB0 = cb0 * 8, ldsoB1 = cb1 * 8;

    // fragment read addressing (constant across steps)
    int raf[4], rbf[4];
#pragma unroll
    for (int mf = 0; mf < 4; ++mf) {
        int r = wr * 64 + mf * 16 + (lane & 15);
        raf[mf] = r * BKG + (((lane >> 4) ^ (r & 3)) * 8);
    }
#pragma unroll
    for (int nf = 0; nf < 4; ++nf) {
        int r = wc * 64 + nf * 16 + (lane & 15);
        rbf[nf] = r * BKG + (((lane >> 4) ^ (r & 3)) * 8);
    }

    // prologue: stage steps 0 (buf0) and 1 (buf1); 6 loads in flight
    GLOAD_LDS16(Am + srcA, smem + ldsoA);
    GLOAD_LDS16(Wl + srcB0, smem + ABSZ + ldsoB0);
    GLOAD_LDS16(Wl + srcB1, smem + ABSZ + ldsoB1);
    GLOAD_LDS16(Am + srcA + BKG, smem + BUFSZ + ldsoA);
    GLOAD_LDS16(Wl + srcB0 + BKG, smem + BUFSZ + ABSZ + ldsoB0);
    GLOAD_LDS16(Wl + srcB1 + BKG, smem + BUFSZ + ABSZ + ldsoB1);

    for (int s = 0; s < NSTEPS; ++s) {
        if (s < NSTEPS - 1) {
            asm volatile("s_waitcnt vmcnt(3)" ::: "memory");   // step s's loads done
        } else {
            asm volatile("s_waitcnt vmcnt(0)" ::: "memory");
        }
        __builtin_amdgcn_s_barrier();
        __builtin_amdgcn_sched_barrier(0);
        int nx = s + 2;
        if (nx < NSTEPS) {
            const ushort* A = (nx >= 8) ? Ax : Am;
            const ushort* W = (nx >= 8) ? Wr : Wl;
            int k0 = (nx & 7) * BKG;
            ushort* d = smem + (nx % 3) * BUFSZ;
            GLOAD_LDS16(A + srcA + k0, d + ldsoA);
            GLOAD_LDS16(W + srcB0 + k0, d + ABSZ + ldsoB0);
            GLOAD_LDS16(W + srcB1 + k0, d + ABSZ + ldsoB1);
        }
        const ushort* As = smem + (s % 3) * BUFSZ;
        const ushort* Bs = As + ABSZ;
        s16x8 af[4], bg[4];
#pragma unroll
        for (int mf = 0; mf < 4; ++mf) af[mf] = *(const s16x8*)&As[raf[mf]];
#pragma unroll
        for (int nf = 0; nf < 4; ++nf) bg[nf] = *(const s16x8*)&Bs[rbf[nf]];
#pragma unroll
        for (int mf = 0; mf < 4; ++mf)
#pragma unroll
            for (int nf = 0; nf < 4; ++nf)
                acc[mf][nf] = __builtin_amdgcn_mfma_f32_16x16x32_bf16(
                    af[mf], bg[nf], acc[mf][nf], 0, 0, 0);
    }
    __syncthreads();   // all waves done reading smem before C-slab reuse

    // ---- epilogue: two row-half passes through LDS, then linear stores ----
    ushort* Cs = smem;   // 32K of the 72K
#pragma unroll
    for (int p = 0; p < 2; ++p) {
        if (wr == p) {
#pragma unroll
            for (int nf = 0; nf < 4; ++nf) {
                int col = wc * 64 + nf * 16 + (lane & 15);
                float bv = bias[col];
#pragma unroll
                for (int mf = 0; mf < 4; ++mf) {
                    int rl = mf * 16 + ((lane >> 4) << 2);   // 0..63 local row
#pragma unroll
                    for (int q = 0; q < 4; ++q) {
                        float v = acc[mf][nf][q] + bv;
                        if (do_relu) v = fmaxf(v, 0.f);
                        Cs[(rl + q) * BN + col] = f2bf(v);
                    }
                }
            }
        }
        __syncthreads();
        // copy out 64 rows (= 2048 uint4); 512 threads x 4
#pragma unroll
        for (int i = 0; i < 4; ++i) {
            int idx = i * 512 + tid;          // uint4 index; 32 per row
            int row = m0 + p * 64 + (idx >> 5);
            if (row < M) {
                uint4 v = ((const uint4*)Cs)[idx];
                *(uint4*)&out[(size_t)row * EMB + (idx & 31) * 8] = v;
                if (out8) {
                    const ushort* pu = (const ushort*)&v;
                    unsigned lo = f32x2_to_fp8(bf2f(pu[0]), bf2f(pu[1])) |
                                  (f32x2_to_fp8(bf2f(pu[2]), bf2f(pu[3])) << 16);
                    unsigned hi = f32x2_to_fp8(bf2f(pu[4]), bf2f(pu[5])) |
                                  (f32x2_to_fp8(bf2f(pu[6]), bf2f(pu[7])) << 16);
                    *(uint2*)&out8[(size_t)row * EMB + (idx & 31) * 8] =
                        make_uint2(lo, hi);
                }
            }
        }
        __syncthreads();
    }
}

// ------- supervision scores: wave per edge, both rows in one 16B/lane load -----

__global__ void score_kernel(const ushort* __restrict__ x, const int* __restrict__ sup,
                             float* __restrict__ out) {
    int w = threadIdx.x >> 6;
    int lane = threadIdx.x & 63;
    int half = lane >> 5;
    int sl = lane & 31;
    int e = blockIdx.x * 4 + w;
    if (e >= N_SUP) return;
    int s = clampi(sup[e], 0, N_NODES - 1);
    int d = clampi(sup[N_SUP + e], 0, N_NODES - 1);
    int row = half ? d : s;
    uint4 raw = *(const uint4*)&x[(unsigned)row * EMB + sl * 8];
    uint4 pr;
    pr.x = __shfl_xor(raw.x, 32, 64);
    pr.y = __shfl_xor(raw.y, 32, 64);
    pr.z = __shfl_xor(raw.z, 32, 64);
    pr.w = __shfl_xor(raw.w, 32, 64);
    float t = 0.f;
    unsigned a[4] = {raw.x, raw.y, raw.z, raw.w};
    unsigned b[4] = {pr.x, pr.y, pr.z, pr.w};
#pragma unroll
    for (int i = 0; i < 4; ++i) {
        t += bf2f((ushort)(a[i] & 0xffff)) * bf2f((ushort)(b[i] & 0xffff));
        t += bf2f((ushort)(a[i] >> 16)) * bf2f((ushort)(b[i] >> 16));
    }
#pragma unroll
    for (int off = 16; off > 0; off >>= 1) t += __shfl_xor(t, off, 64);
    if (lane == 0) out[e] = t;
}

// ---------------- launch ----------------

extern "C" void kernel_launch(void* const* d_in, const int* in_sizes, int n_in,
                              void* d_out, int out_size, void* d_ws, size_t ws_size,
                              hipStream_t stream) {
    const float* x0  = (const float*)d_in[0];
    const int*   mp  = (const int*)d_in[1];
    const int*   sup = (const int*)d_in[2];
    W6 wsrc;
    wsrc.p[0] = (const float*)d_in[3];   // Wl1
    wsrc.p[1] = (const float*)d_in[5];   // Wr1
    wsrc.p[2] = (const float*)d_in[6];   // Wl2
    wsrc.p[3] = (const float*)d_in[8];   // Wr2
    wsrc.p[4] = (const float*)d_in[9];   // Wl3
    wsrc.p[5] = (const float*)d_in[11];  // Wr3
    const float* bl1 = (const float*)d_in[4];
    const float* bl2 = (const float*)d_in[7];
    const float* bl3 = (const float*)d_in[10];
    float* scores = (float*)d_out;

    const int* mp_src = mp;
    const int* mp_dst = mp + N_MP;

    char* base = (char*)d_ws;
    size_t off = 0;
    auto alloc = [&](size_t bytes) {
        void* p = base + off;
        off = (off + bytes + 255) & ~(size_t)255;
        return p;
    };
    int* rp     = (int*)alloc((N_NODES + 1) * sizeof(int));
    int* gbfill = (int*)alloc(256 * sizeof(int));
    int* bbase  = (int*)alloc(256 * sizeof(int));
    int* srt    = (int*)alloc(N_MP * sizeof(int));
    unsigned* packed = (unsigned*)alloc((size_t)NBUCK * SCAP * sizeof(unsigned));
    ushort* x0b  = (ushort*)alloc((size_t)N_NODES * EMB * sizeof(ushort));
    ushort* bufA = (ushort*)alloc((size_t)N_NODES * EMB * sizeof(ushort));
    ushort* bufB = (ushort*)alloc((size_t)N_NODES * EMB * sizeof(ushort));
    ushort* bufC = (ushort*)alloc((size_t)N_NODES * EMB * sizeof(ushort));
    uchar*  x0f8 = (uchar*)alloc((size_t)N_NODES * EMB);
    uchar*  a8   = (uchar*)alloc((size_t)N_NODES * EMB);
    ushort* Wb   = (ushort*)alloc((size_t)6 * EMB * EMB * sizeof(ushort));
    (void)ws_size; (void)n_in; (void)in_sizes; (void)out_size;

    f2b8_kernel<<<(N_NODES * EMB / 8 + 255) / 256, 256, 0, stream>>>(
        x0, x0b, x0f8, N_NODES * EMB / 8);
    wcvt_kernel<<<192, 256, 0, stream>>>(wsrc, Wb);

    binit_kernel<<<1, 256, 0, stream>>>(gbfill);
    bin_kernel<<<(N_MP + EPB_A - 1) / EPB_A, 1024, 0, stream>>>(
        mp_src, mp_dst, N_MP, gbfill, packed);
    bscan_kernel<<<1, 256, 0, stream>>>(gbfill, bbase, rp);
    debin_kernel<<<NBUCK, 1024, 0, stream>>>(packed, gbfill, bbase, srt, rp);

    dim3 gemm_grid((N_NODES + BM - 1) / BM, 1);
    int agg_blocks = (N_NODES + 3) / 4;

    ushort* Wl1 = Wb + 0 * EMB * EMB; ushort* Wr1 = Wb + 1 * EMB * EMB;
    ushort* Wl2 = Wb + 2 * EMB * EMB; ushort* Wr2 = Wb + 3 * EMB * EMB;
    ushort* Wl3 = Wb + 4 * EMB * EMB; ushort* Wr3 = Wb + 5 * EMB * EMB;

    agg_kernel<<<agg_blocks, 256, 0, stream>>>(x0f8, rp, srt, bufC);
    gemm_kernel<<<gemm_grid, 512, 0, stream>>>(bufC, x0b, Wl1, Wr1, bl1, bufA, a8, N_NODES, 1);

    agg_kernel<<<agg_blocks, 256, 0, stream>>>(a8, rp, srt, bufC);
    gemm_kernel<<<gemm_grid, 512, 0, stream>>>(bufC, bufA, Wl2, Wr2, bl2, bufB, a8, N_NODES, 1);

    agg_kernel<<<agg_blocks, 256, 0, stream>>>(a8, rp, srt, bufC);
    gemm_kernel<<<gemm_grid, 512, 0, stream>>>(bufC, bufB, Wl3, Wr3, bl3, bufA,
                                               (uchar*)nullptr, N_NODES, 0);

    score_kernel<<<(N_SUP + 3) / 4, 256, 0, stream>>>(bufA, sup, scores);
}

// Round 17
// 412.082 us; speedup vs baseline: 1.8815x; 1.0548x over previous
//
#include <hip/hip_runtime.h>
#include <hip/hip_bf16.h>

#define N_NODES 100000
#define EMB 256
#define N_MP 1600000
#define N_SUP 200000

typedef __attribute__((ext_vector_type(4))) float f32x4;
typedef __attribute__((ext_vector_type(2))) float f32x2;
typedef __attribute__((ext_vector_type(8))) short s16x8;
typedef unsigned char uchar;

__device__ __forceinline__ int clampi(int v, int lo, int hi) {
    return v < lo ? lo : (v > hi ? hi : v);
}
__device__ __forceinline__ ushort f2bf(float f) {
    unsigned u = __float_as_uint(f);
    u += 0x7fffu + ((u >> 16) & 1u);   // round-to-nearest-even
    return (ushort)(u >> 16);
}
__device__ __forceinline__ float bf2f(ushort h) {
    return __uint_as_float(((unsigned)h) << 16);
}
// fp8 e4m3 HW converts; word-half selector must be an IMMEDIATE -> template
template <bool HI>
__device__ __forceinline__ f32x2 fp8_to_f32x2(unsigned w) {
    return __builtin_amdgcn_cvt_pk_f32_fp8(w, HI);
}
__device__ __forceinline__ unsigned f32x2_to_fp8(float a, float b) {
    return (unsigned)__builtin_amdgcn_cvt_pk_fp8_f32(a, b, 0, false) & 0xffffu;
}

#define GLOAD_LDS16(gsrc, ldst)                                                   \
    __builtin_amdgcn_global_load_lds(                                             \
        (const __attribute__((address_space(1))) void*)(gsrc),                    \
        (__attribute__((address_space(3))) void*)(ldst), 16, 0, 0)

// ------------- fp32 -> bf16 + fp8 convert (8 elems/thread) ----------------------

__global__ void f2b8_kernel(const float* __restrict__ in, ushort* __restrict__ outb,
                            uchar* __restrict__ out8, int n8) {
    int i = blockIdx.x * 256 + threadIdx.x;
    if (i >= n8) return;
    const float4* p = (const float4*)(in + (size_t)i * 8);
    float4 a = p[0], b = p[1];
    ushort4 lo = make_ushort4(f2bf(a.x), f2bf(a.y), f2bf(a.z), f2bf(a.w));
    ushort4 hi = make_ushort4(f2bf(b.x), f2bf(b.y), f2bf(b.z), f2bf(b.w));
    ushort4* q = (ushort4*)(outb + (size_t)i * 8);
    q[0] = lo; q[1] = hi;
    uint2 f8;
    f8.x = f32x2_to_fp8(a.x, a.y) | (f32x2_to_fp8(a.z, a.w) << 16);
    f8.y = f32x2_to_fp8(b.x, b.y) | (f32x2_to_fp8(b.z, b.w) << 16);
    *(uint2*)(out8 + (size_t)i * 8) = f8;
}

// one launch for all 6 weight matrices; fp8 shadow for the 3 Wl matrices
struct W6 { const float* p[6]; };
__global__ void wcvt_kernel(W6 ws, ushort* __restrict__ outb, uchar* __restrict__ out8) {
    int m = blockIdx.x >> 5;                      // 32 blocks per matrix
    int idx = (blockIdx.x & 31) * 256 + threadIdx.x;  // 0..8191
    const float4* p = (const float4*)(ws.p[m] + (size_t)idx * 8);
    float4 a = p[0], b = p[1];
    ushort4 lo = make_ushort4(f2bf(a.x), f2bf(a.y), f2bf(a.z), f2bf(a.w));
    ushort4 hi = make_ushort4(f2bf(b.x), f2bf(b.y), f2bf(b.z), f2bf(b.w));
    ushort4* q = (ushort4*)(outb + (size_t)m * EMB * EMB + (size_t)idx * 8);
    q[0] = lo; q[1] = hi;
    if (!(m & 1)) {   // Wl1/Wl2/Wl3 -> fp8 slot m/2
        uint2 f8;
        f8.x = f32x2_to_fp8(a.x, a.y) | (f32x2_to_fp8(a.z, a.w) << 16);
        f8.y = f32x2_to_fp8(b.x, b.y) | (f32x2_to_fp8(b.z, b.w) << 16);
        *(uint2*)(out8 + (size_t)(m >> 1) * EMB * EMB + (size_t)idx * 8) = f8;
    }
}

// ---------------- merged CSR build: bin -> bucket scan -> debin(+rp) ------------

#define BSH 9
#define NBUCK ((N_NODES + 511) / 512)   // 196
#define EPB_A 4096
#define SCAP 16384

__global__ void binit_kernel(int* __restrict__ gbfill) {
    int t = threadIdx.x;
    if (t < NBUCK) gbfill[t] = t * SCAP;
}

__global__ __launch_bounds__(1024) void bin_kernel(
    const int* __restrict__ src, const int* __restrict__ dst, int n,
    int* __restrict__ gbfill, unsigned* __restrict__ packed) {
    __shared__ int cnt[256];
    __shared__ int base[256];
    int tid = threadIdx.x;
    if (tid < 256) cnt[tid] = 0;
    __syncthreads();
    int e0 = blockIdx.x * EPB_A + tid;
    int bk[4], rank[4], sv[4];
    bool valid[4];
#pragma unroll
    for (int k = 0; k < 4; ++k) {
        int e = e0 + k * 1024;
        valid[k] = e < n;
        if (valid[k]) {
            int d = clampi(dst[e], 0, N_NODES - 1);
            sv[k] = clampi(src[e], 0, N_NODES - 1);
            bk[k] = d >> BSH;
            int dl = d & 511;
            sv[k] |= (dl << 20);
            rank[k] = atomicAdd(&cnt[bk[k]], 1);
        }
    }
    __syncthreads();
    if (tid < 256) {
        int c = cnt[tid];
        base[tid] = c > 0 ? atomicAdd(&gbfill[tid], c) : 0;
    }
    __syncthreads();
#pragma unroll
    for (int k = 0; k < 4; ++k) {
        if (valid[k]) {
            int pos = base[bk[k]] + rank[k];
            if (pos < (bk[k] + 1) * SCAP) packed[pos] = (unsigned)sv[k];
        }
    }
}

__global__ void bscan_kernel(const int* __restrict__ gbfill, int* __restrict__ bbase,
                             int* __restrict__ rp) {
    __shared__ int c[256];
    int t = threadIdx.x;
    c[t] = (t < NBUCK) ? (gbfill[t] - t * SCAP) : 0;
    __syncthreads();
    if (t == 0) {
        int run = 0;
        for (int i = 0; i < NBUCK; ++i) { int v = c[i]; c[i] = run; run += v; }
        rp[N_NODES] = run;
    }
    __syncthreads();
    if (t < NBUCK) bbase[t] = c[t];
}

__global__ __launch_bounds__(1024) void debin_kernel(
    const unsigned* __restrict__ packed, const int* __restrict__ gbfill,
    const int* __restrict__ bbase, int* __restrict__ srt, int* __restrict__ rp) {
    __shared__ int cnt[512];
    __shared__ int loc[512];
    __shared__ int wsum[8];
    int b = blockIdx.x;
    int tid = threadIdx.x;
    int lane = tid & 63, wv = tid >> 6;
    int node0 = b << BSH;
    int nn = N_NODES - node0; if (nn > 512) nn = 512;
    if (tid < 512) cnt[tid] = 0;
    __syncthreads();
    int pbase = b * SCAP;
    int bcnt = gbfill[b] - pbase;
    if (bcnt > SCAP) bcnt = SCAP;
    for (int e = tid; e < bcnt; e += 1024)
        atomicAdd(&cnt[packed[pbase + e] >> 20], 1);
    __syncthreads();
    int v = (tid < 512) ? cnt[tid] : 0;
    int t = v;
#pragma unroll
    for (int off = 1; off < 64; off <<= 1) {
        int u = __shfl_up(t, off, 64);
        if (lane >= off) t += u;
    }
    if (tid < 512 && lane == 63) wsum[wv] = t;
    __syncthreads();
    if (tid < 512) {
        int woff = 0;
        for (int i = 0; i < wv; ++i) woff += wsum[i];
        loc[tid] = woff + t - v;
        if (tid < nn) rp[node0 + tid] = bbase[b] + loc[tid];
    }
    __syncthreads();
    if (tid < 512) cnt[tid] = 0;
    __syncthreads();
    int sb = bbase[b];
    for (int e = tid; e < bcnt; e += 1024) {
        unsigned p = packed[pbase + e];
        int dl = p >> 20;
        int rank = atomicAdd(&cnt[dl], 1);
        srt[sb + loc[dl] + rank] = (int)(p & 0xFFFFFu);
    }
}

// ------- mean aggregation v6: fp8 gather, fp32 accum, **fp8 out** ---------------

__global__ void agg_kernel(const uchar* __restrict__ x8, const int* __restrict__ rp,
                           const int* __restrict__ srt, uchar* __restrict__ outm8) {
    int w = threadIdx.x >> 6;
    int lane = threadIdx.x & 63;
    int qw = lane >> 4;
    int sl = lane & 15;
    int node = blockIdx.x * 4 + w;
    if (node >= N_NODES) return;
    int beg = rp[node], end = rp[node + 1];
    int deg = end - beg;
    float acc[16];
#pragma unroll
    for (int i = 0; i < 16; ++i) acc[i] = 0.f;

    for (int bse = 0; bse < deg; bse += 64) {
        int rem = deg - bse;
        int cnt = rem < 64 ? rem : 64;
        int myidx = (lane < cnt) ? srt[beg + bse + lane] : 0;
        for (int j = 0; j < cnt; j += 4) {
            int e = j + qw;
            int s = __shfl(myidx, e < cnt ? e : 0, 64);
            if (e < cnt) {
                uint4 v = *(const uint4*)&x8[(unsigned)s * EMB + sl * 16];
                f32x2 p;
                p = fp8_to_f32x2<false>(v.x); acc[0] += p.x; acc[1] += p.y;
                p = fp8_to_f32x2<true >(v.x); acc[2] += p.x; acc[3] += p.y;
                p = fp8_to_f32x2<false>(v.y); acc[4] += p.x; acc[5] += p.y;
                p = fp8_to_f32x2<true >(v.y); acc[6] += p.x; acc[7] += p.y;
                p = fp8_to_f32x2<false>(v.z); acc[8] += p.x; acc[9] += p.y;
                p = fp8_to_f32x2<true >(v.z); acc[10] += p.x; acc[11] += p.y;
                p = fp8_to_f32x2<false>(v.w); acc[12] += p.x; acc[13] += p.y;
                p = fp8_to_f32x2<true >(v.w); acc[14] += p.x; acc[15] += p.y;
            }
        }
    }
#pragma unroll
    for (int i = 0; i < 16; ++i) acc[i] += __shfl_xor(acc[i], 32, 64);
#pragma unroll
    for (int i = 0; i < 16; ++i) acc[i] += __shfl_xor(acc[i], 16, 64);
    float inv = 1.0f / fmaxf((float)deg, 1.0f);
    if (qw == 0) {
        uint4 o;
        o.x = f32x2_to_fp8(acc[0] * inv, acc[1] * inv) |
              (f32x2_to_fp8(acc[2] * inv, acc[3] * inv) << 16);
        o.y = f32x2_to_fp8(acc[4] * inv, acc[5] * inv) |
              (f32x2_to_fp8(acc[6] * inv, acc[7] * inv) << 16);
        o.z = f32x2_to_fp8(acc[8] * inv, acc[9] * inv) |
              (f32x2_to_fp8(acc[10] * inv, acc[11] * inv) << 16);
        o.w = f32x2_to_fp8(acc[12] * inv, acc[13] * inv) |
              (f32x2_to_fp8(acc[14] * inv, acc[15] * inv) << 16);
        *(uint4*)&outm8[(size_t)node * EMB + sl * 16] = o;
    }
}

// -------- GEMM v5: phase 0 = fp8 (Am8 x Wl8, K=64/step, 4 steps), ---------------
//          phase 1 = bf16 (Ax x Wr, K=32/step, 8 steps); same acc.
// Both phases: 64-B row window per step -> identical chunk geometry:
// A 512 chunks + B 1024 chunks = 3 loads/thread/step (uniform vmcnt counting).
// 3-buffer rotation, counted vmcnt(3). LDS 3 x 24 KiB = 72 KiB -> 2 blocks/CU.

#define BM 128
#define BN 256
#define NSTEPS 12                          // 4 fp8 + 8 bf16
#define BUFSZ 12288                        // ushorts = 24 KiB
#define AREG 8192                          // bytes: A region size per buffer

__global__ __launch_bounds__(512) void gemm_kernel(
    const uchar* __restrict__ Am8, const ushort* __restrict__ Ax,
    const uchar* __restrict__ Wl8, const ushort* __restrict__ Wr,
    const float* __restrict__ bias, ushort* __restrict__ out,
    uchar* __restrict__ out8, int M, int do_relu) {
    __shared__ ushort smem[3 * BUFSZ];   // 72 KiB
    const int tid = threadIdx.x;
    const int lane = tid & 63;
    const int w = tid >> 6;
    const int m0 = blockIdx.x * BM;
    const int wr = w >> 2;
    const int wc = w & 3;
    const int g = lane >> 4;            // K-group 0..3

    f32x4 acc[4][4];
#pragma unroll
    for (int i = 0; i < 4; ++i)
#pragma unroll
        for (int j = 0; j < 4; ++j) acc[i][j] = (f32x4){0.f, 0.f, 0.f, 0.f};

    // chunk geometry (identical both phases): c -> row r=c>>2, quarter q=(c&3)^(r&3)
    int cA = tid;                // A chunk 0..511
    int rA = cA >> 2, qA = (cA & 3) ^ (rA & 3);
    int arow = m0 + rA; if (arow > M - 1) arow = M - 1;
    int cB0 = tid, cB1 = tid + 512;
    int rB0 = cB0 >> 2, qB0 = (cB0 & 3) ^ (rB0 & 3);
    int rB1 = cB1 >> 2, qB1 = (cB1 & 3) ^ (rB1 & 3);
    // byte sources
    size_t srcA8 = (size_t)arow * 256 + qA * 16;           // fp8 A row = 256 B
    size_t srcB08 = (size_t)rB0 * 256 + qB0 * 16;          // fp8 W row = 256 B
    size_t srcB18 = (size_t)rB1 * 256 + qB1 * 16;
    size_t srcAb = (size_t)arow * EMB + qA * 8;            // bf16 (ushort units)
    size_t srcB0b = (size_t)rB0 * EMB + qB0 * 8;
    size_t srcB1b = (size_t)rB1 * EMB + qB1 * 8;
    // LDS dests (bytes, phase-independent)
    int ldsoA = cA * 16;
    int ldsoB0 = AREG + cB0 * 16;
    int ldsoB1 = AREG + cB1 * 16;

    // fragment read byte-addresses (within a buffer)
    int raf8[4][2], rbf8[4][2], rafb[4], rbfb[4];
#pragma unroll
    for (int mf = 0; mf < 4; ++mf) {
        int r = wr * 64 + mf * 16 + (lane & 15);
        rafb[mf] = r * 64 + (((g) ^ (r & 3)) << 4);
#pragma unroll
        for (int ks = 0; ks < 2; ++ks) {
            int hi = ks * 2 + (g >> 1);
            raf8[mf][ks] = r * 64 + ((hi ^ (r & 3)) << 4) + ((g & 1) * 8);
        }
    }
#pragma unroll
    for (int nf = 0; nf < 4; ++nf) {
        int r = wc * 64 + nf * 16 + (lane & 15);
        rbfb[nf] = r * 64 + (((g) ^ (r & 3)) << 4);
#pragma unroll
        for (int ks = 0; ks < 2; ++ks) {
            int hi = ks * 2 + (g >> 1);
            rbf8[nf][ks] = r * 64 + ((hi ^ (r & 3)) << 4) + ((g & 1) * 8);
        }
    }

    // prologue: stage steps 0,1 (both fp8; window = s*64 bytes)
    {
        uchar* d0 = (uchar*)smem;
        uchar* d1 = (uchar*)smem + BUFSZ * 2;   // buffer 1 (ushort*2 bytes)
        GLOAD_LDS16(Am8 + srcA8 + 0, d0 + ldsoA);
        GLOAD_LDS16(Wl8 + srcB08 + 0, d0 + ldsoB0);
        GLOAD_LDS16(Wl8 + srcB18 + 0, d0 + ldsoB1);
        GLOAD_LDS16(Am8 + srcA8 + 64, d1 + ldsoA);
        GLOAD_LDS16(Wl8 + srcB08 + 64, d1 + ldsoB0);
        GLOAD_LDS16(Wl8 + srcB18 + 64, d1 + ldsoB1);
    }

    for (int s = 0; s < NSTEPS; ++s) {
        if (s < NSTEPS - 1) {
            asm volatile("s_waitcnt vmcnt(3)" ::: "memory");
        } else {
            asm volatile("s_waitcnt vmcnt(0)" ::: "memory");
        }
        __builtin_amdgcn_s_barrier();
        __builtin_amdgcn_sched_barrier(0);
        int nx = s + 2;
        if (nx < NSTEPS) {
            uchar* d = (uchar*)smem + (nx % 3) * BUFSZ * 2;
            if (nx < 4) {
                int k0 = nx * 64;
                GLOAD_LDS16(Am8 + srcA8 + k0, d + ldsoA);
                GLOAD_LDS16(Wl8 + srcB08 + k0, d + ldsoB0);
                GLOAD_LDS16(Wl8 + srcB18 + k0, d + ldsoB1);
            } else {
                int k0 = (nx - 4) * 32;   // ushort units
                GLOAD_LDS16(Ax + srcAb + k0, d + ldsoA);
                GLOAD_LDS16(Wr + srcB0b + k0, d + ldsoB0);
                GLOAD_LDS16(Wr + srcB1b + k0, d + ldsoB1);
            }
        }
        const char* Asb = (const char*)smem + (s % 3) * BUFSZ * 2;
        const char* Bsb = Asb + AREG;
        if (s < 4) {
            long af[4][2], bg[4][2];
#pragma unroll
            for (int mf = 0; mf < 4; ++mf) {
                af[mf][0] = *(const long*)(Asb + raf8[mf][0]);
                af[mf][1] = *(const long*)(Asb + raf8[mf][1]);
            }
#pragma unroll
            for (int nf = 0; nf < 4; ++nf) {
                bg[nf][0] = *(const long*)(Bsb + rbf8[nf][0]);
                bg[nf][1] = *(const long*)(Bsb + rbf8[nf][1]);
            }
#pragma unroll
            for (int mf = 0; mf < 4; ++mf)
#pragma unroll
                for (int nf = 0; nf < 4; ++nf) {
                    acc[mf][nf] = __builtin_amdgcn_mfma_f32_16x16x32_fp8_fp8(
                        af[mf][0], bg[nf][0], acc[mf][nf], 0, 0, 0);
                    acc[mf][nf] = __builtin_amdgcn_mfma_f32_16x16x32_fp8_fp8(
                        af[mf][1], bg[nf][1], acc[mf][nf], 0, 0, 0);
                }
        } else {
            s16x8 af[4], bg[4];
#pragma unroll
            for (int mf = 0; mf < 4; ++mf) af[mf] = *(const s16x8*)(Asb + rafb[mf]);
#pragma unroll
            for (int nf = 0; nf < 4; ++nf) bg[nf] = *(const s16x8*)(Bsb + rbfb[nf]);
#pragma unroll
            for (int mf = 0; mf < 4; ++mf)
#pragma unroll
                for (int nf = 0; nf < 4; ++nf)
                    acc[mf][nf] = __builtin_amdgcn_mfma_f32_16x16x32_bf16(
                        af[mf], bg[nf], acc[mf][nf], 0, 0, 0);
        }
    }
    __syncthreads();   // drain before C-slab reuse

    // ---- epilogue: two row-half passes through LDS, then linear stores ----
    ushort* Cs = smem;
#pragma unroll
    for (int p = 0; p < 2; ++p) {
        if (wr == p) {
#pragma unroll
            for (int nf = 0; nf < 4; ++nf) {
                int col = wc * 64 + nf * 16 + (lane & 15);
                float bv = bias[col];
#pragma unroll
                for (int mf = 0; mf < 4; ++mf) {
                    int rl = mf * 16 + ((lane >> 4) << 2);
#pragma unroll
                    for (int q = 0; q < 4; ++q) {
                        float v = acc[mf][nf][q] + bv;
                        if (do_relu) v = fmaxf(v, 0.f);
                        Cs[(rl + q) * BN + col] = f2bf(v);
                    }
                }
            }
        }
        __syncthreads();
#pragma unroll
        for (int i = 0; i < 4; ++i) {
            int idx = i * 512 + tid;
            int row = m0 + p * 64 + (idx >> 5);
            if (row < M) {
                uint4 v = ((const uint4*)Cs)[idx];
                *(uint4*)&out[(size_t)row * EMB + (idx & 31) * 8] = v;
                if (out8) {
                    const ushort* pu = (const ushort*)&v;
                    unsigned lo = f32x2_to_fp8(bf2f(pu[0]), bf2f(pu[1])) |
                                  (f32x2_to_fp8(bf2f(pu[2]), bf2f(pu[3])) << 16);
                    unsigned hi = f32x2_to_fp8(bf2f(pu[4]), bf2f(pu[5])) |
                                  (f32x2_to_fp8(bf2f(pu[6]), bf2f(pu[7])) << 16);
                    *(uint2*)&out8[(size_t)row * EMB + (idx & 31) * 8] =
                        make_uint2(lo, hi);
                }
            }
        }
        __syncthreads();
    }
}

// ------- supervision scores: wave per edge, both rows in one 16B/lane load -----

__global__ void score_kernel(const ushort* __restrict__ x, const int* __restrict__ sup,
                             float* __restrict__ out) {
    int w = threadIdx.x >> 6;
    int lane = threadIdx.x & 63;
    int half = lane >> 5;
    int sl = lane & 31;
    int e = blockIdx.x * 4 + w;
    if (e >= N_SUP) return;
    int s = clampi(sup[e], 0, N_NODES - 1);
    int d = clampi(sup[N_SUP + e], 0, N_NODES - 1);
    int row = half ? d : s;
    uint4 raw = *(const uint4*)&x[(unsigned)row * EMB + sl * 8];
    uint4 pr;
    pr.x = __shfl_xor(raw.x, 32, 64);
    pr.y = __shfl_xor(raw.y, 32, 64);
    pr.z = __shfl_xor(raw.z, 32, 64);
    pr.w = __shfl_xor(raw.w, 32, 64);
    float t = 0.f;
    unsigned a[4] = {raw.x, raw.y, raw.z, raw.w};
    unsigned b[4] = {pr.x, pr.y, pr.z, pr.w};
#pragma unroll
    for (int i = 0; i < 4; ++i) {
        t += bf2f((ushort)(a[i] & 0xffff)) * bf2f((ushort)(b[i] & 0xffff));
        t += bf2f((ushort)(a[i] >> 16)) * bf2f((ushort)(b[i] >> 16));
    }
#pragma unroll
    for (int off = 16; off > 0; off >>= 1) t += __shfl_xor(t, off, 64);
    if (lane == 0) out[e] = t;
}

// ---------------- launch ----------------

extern "C" void kernel_launch(void* const* d_in, const int* in_sizes, int n_in,
                              void* d_out, int out_size, void* d_ws, size_t ws_size,
                              hipStream_t stream) {
    const float* x0  = (const float*)d_in[0];
    const int*   mp  = (const int*)d_in[1];
    const int*   sup = (const int*)d_in[2];
    W6 wsrc;
    wsrc.p[0] = (const float*)d_in[3];   // Wl1
    wsrc.p[1] = (const float*)d_in[5];   // Wr1
    wsrc.p[2] = (const float*)d_in[6];   // Wl2
    wsrc.p[3] = (const float*)d_in[8];   // Wr2
    wsrc.p[4] = (const float*)d_in[9];   // Wl3
    wsrc.p[5] = (const float*)d_in[11];  // Wr3
    const float* bl1 = (const float*)d_in[4];
    const float* bl2 = (const float*)d_in[7];
    const float* bl3 = (const float*)d_in[10];
    float* scores = (float*)d_out;

    const int* mp_src = mp;
    const int* mp_dst = mp + N_MP;

    char* base = (char*)d_ws;
    size_t off = 0;
    auto alloc = [&](size_t bytes) {
        void* p = base + off;
        off = (off + bytes + 255) & ~(size_t)255;
        return p;
    };
    int* rp     = (int*)alloc((N_NODES + 1) * sizeof(int));
    int* gbfill = (int*)alloc(256 * sizeof(int));
    int* bbase  = (int*)alloc(256 * sizeof(int));
    int* srt    = (int*)alloc(N_MP * sizeof(int));
    unsigned* packed = (unsigned*)alloc((size_t)NBUCK * SCAP * sizeof(unsigned));
    ushort* x0b  = (ushort*)alloc((size_t)N_NODES * EMB * sizeof(ushort));
    ushort* bufA = (ushort*)alloc((size_t)N_NODES * EMB * sizeof(ushort));
    ushort* bufB = (ushort*)alloc((size_t)N_NODES * EMB * sizeof(ushort));
    uchar*  bufC8 = (uchar*)alloc((size_t)N_NODES * EMB);
    uchar*  x0f8 = (uchar*)alloc((size_t)N_NODES * EMB);
    uchar*  a8   = (uchar*)alloc((size_t)N_NODES * EMB);
    ushort* Wb   = (ushort*)alloc((size_t)6 * EMB * EMB * sizeof(ushort));
    uchar*  W8   = (uchar*)alloc((size_t)3 * EMB * EMB);
    (void)ws_size; (void)n_in; (void)in_sizes; (void)out_size;

    f2b8_kernel<<<(N_NODES * EMB / 8 + 255) / 256, 256, 0, stream>>>(
        x0, x0b, x0f8, N_NODES * EMB / 8);
    wcvt_kernel<<<192, 256, 0, stream>>>(wsrc, Wb, W8);

    binit_kernel<<<1, 256, 0, stream>>>(gbfill);
    bin_kernel<<<(N_MP + EPB_A - 1) / EPB_A, 1024, 0, stream>>>(
        mp_src, mp_dst, N_MP, gbfill, packed);
    bscan_kernel<<<1, 256, 0, stream>>>(gbfill, bbase, rp);
    debin_kernel<<<NBUCK, 1024, 0, stream>>>(packed, gbfill, bbase, srt, rp);

    dim3 gemm_grid((N_NODES + BM - 1) / BM, 1);
    int agg_blocks = (N_NODES + 3) / 4;

    ushort* Wr1 = Wb + 1 * EMB * EMB;
    ushort* Wr2 = Wb + 3 * EMB * EMB;
    ushort* Wr3 = Wb + 5 * EMB * EMB;
    uchar* Wl1_8 = W8 + 0 * EMB * EMB;
    uchar* Wl2_8 = W8 + 1 * EMB * EMB;
    uchar* Wl3_8 = W8 + 2 * EMB * EMB;

    agg_kernel<<<agg_blocks, 256, 0, stream>>>(x0f8, rp, srt, bufC8);
    gemm_kernel<<<gemm_grid, 512, 0, stream>>>(bufC8, x0b, Wl1_8, Wr1, bl1, bufA, a8, N_NODES, 1);

    agg_kernel<<<agg_blocks, 256, 0, stream>>>(a8, rp, srt, bufC8);
    gemm_kernel<<<gemm_grid, 512, 0, stream>>>(bufC8, bufA, Wl2_8, Wr2, bl2, bufB, a8, N_NODES, 1);

    agg_kernel<<<agg_blocks, 256, 0, stream>>>(a8, rp, srt, bufC8);
    gemm_kernel<<<gemm_grid, 512, 0, stream>>>(bufC8, bufB, Wl3_8, Wr3, bl3, bufA,
                                               (uchar*)nullptr, N_NODES, 0);

    score_kernel<<<(N_SUP + 3) / 4, 256, 0, stream>>>(bufA, sup, scores);
}